// Round 7
// baseline (328.812 us; speedup 1.0000x reference)
//
#include <hip/hip_runtime.h>
#include <hip/hip_bf16.h>
#include <math.h>

#define BSZ 2
#define LSEQ 2048
#define DMODEL 1024
#define DSTATE 16
#define DCONV 4
#define DINNER 2048
#define DTRANK 64
#define NPROJ (DTRANK + 2 * DSTATE) // 96
#define NC 32   // scan chunks
#define LC 64   // steps per chunk
#define KS 8    // proj split-K chunks
#define KCH (DINNER / KS) // 256

using short8 = __attribute__((ext_vector_type(8))) short;
using f32x4 = __attribute__((ext_vector_type(4))) float;
using u16x4 = __attribute__((ext_vector_type(4))) unsigned short;

__device__ __forceinline__ float silu_f(float v) {
    return v / (1.f + expf(-v));
}
__device__ __forceinline__ float softplus_f(float v) {
    return fmaxf(v, 0.f) + log1pf(expf(-fabsf(v)));
}
// fp32 -> bf16 bits, round-to-nearest-even
__device__ __forceinline__ unsigned short f2bf(float f) {
    unsigned u = __builtin_bit_cast(unsigned, f);
    u += 0x7fffu + ((u >> 16) & 1u);
    return (unsigned short)(u >> 16);
}
__device__ __forceinline__ float bf2f(unsigned short u) {
    unsigned x = ((unsigned)u) << 16;
    return __builtin_bit_cast(float, x);
}

__device__ __forceinline__ void gld_lds16(const unsigned short* g, unsigned short* l) {
    __builtin_amdgcn_global_load_lds(
        (const __attribute__((address_space(1))) unsigned int*)g,
        (__attribute__((address_space(3))) unsigned int*)l, 16, 0, 0);
}

// ---- prep: fp32 -> bf16 (same layout), n4 = n/4 ----
__global__ __launch_bounds__(256) void f32_to_bf16_kernel(
    const float* __restrict__ in, unsigned short* __restrict__ out, int n4) {
    int i = blockIdx.x * 256 + threadIdx.x;
    if (i >= n4) return;
    float4 v = reinterpret_cast<const float4*>(in)[i];
    u16x4 o = {f2bf(v.x), f2bf(v.y), f2bf(v.z), f2bf(v.w)};
    reinterpret_cast<u16x4*>(out)[i] = o;
}

// ---- prep: transpose fp32 [R][Cc] -> bf16 [Cc][R] ----
__global__ __launch_bounds__(256) void transpose_bf16_kernel(
    const float* __restrict__ in, unsigned short* __restrict__ out, int R, int Cc) {
    __shared__ float t[32][33];
    const int tx = threadIdx.x & 31, ty = threadIdx.x >> 5; // 32 x 8
    const int c0 = blockIdx.x * 32, r0 = blockIdx.y * 32;
    for (int i = ty; i < 32; i += 8)
        t[i][tx] = in[(size_t)(r0 + i) * Cc + c0 + tx];
    __syncthreads();
    for (int i = ty; i < 32; i += 8)
        out[(size_t)(c0 + i) * R + r0 + tx] = f2bf(t[tx][i]);
}

// ---- bf16 MFMA GEMM: C[M,N] = A[M,K] @ Bt[N,K]^T ----
// 128xBN tile (BN = 128 or 64), 4 waves (2x2), BK=32, double-buffered prefetch.
// LDS [row][32] row-major with chunk swizzle chunk' = chunk ^ ((row>>1)&3):
//   staging: lane-linear LDS dest, pre-swizzled global source (same row -> coalesced);
//   fragment read: kg ^ ((fr>>1)&3) -> 2-way bank aliasing (free).
// EPI 0: plain. EPI 1: n<DINNER -> C else silu -> C2 (ldc=DINNER). EPI 2: softplus+bias.
template <int EPI, int BN, typename CT>
__global__ __launch_bounds__(256) void gemm_mfma(
    const unsigned short* __restrict__ A, const unsigned short* __restrict__ Bt,
    CT* __restrict__ C, CT* __restrict__ C2, const float* __restrict__ bias,
    int M, int N, int K) {
    constexpr int NF = BN / 32;                 // per-wave n-frags (4 or 2)
    __shared__ __align__(16) unsigned short As[2][4096];
    __shared__ __align__(16) unsigned short Bs[2][BN * 32];
    const int tid = threadIdx.x;
    const int lane = tid & 63;
    const int wid = tid >> 6;
    const int wr = wid >> 1, wc = wid & 1;
    const int m0 = blockIdx.y * 128, n0 = blockIdx.x * BN;

    const int r0 = tid >> 2;              // rows 0..63
    const int r1 = r0 + 64;               // rows 64..127
    const int d0 = tid * 8;
    const int d1 = d0 + 2048;
    const int cs8 = (((tid & 3) ^ ((tid >> 3) & 3)) << 3); // swizzled src chunk

    f32x4 acc[4][NF];
#pragma unroll
    for (int m = 0; m < 4; m++)
#pragma unroll
        for (int n = 0; n < NF; n++) acc[m][n] = (f32x4){0.f, 0.f, 0.f, 0.f};

    const int fr = lane & 15;
    const int kg = lane >> 4;
    const int kswz = ((kg ^ ((fr >> 1) & 3)) << 3);
    const int nt = K / 32;

    // prologue: stage tile 0 into buffer 0
    gld_lds16(&A[(size_t)(m0 + r0) * K + cs8], &As[0][d0]);
    gld_lds16(&A[(size_t)(m0 + r1) * K + cs8], &As[0][d1]);
    gld_lds16(&Bt[(size_t)(n0 + r0) * K + cs8], &Bs[0][d0]);
    if constexpr (BN == 128)
        gld_lds16(&Bt[(size_t)(n0 + r1) * K + cs8], &Bs[0][d1]);
    __syncthreads();

    int cur = 0;
    for (int t = 0; t < nt; t++) {
        if (t + 1 < nt) { // issue next-tile prefetch BEFORE compute
            const int k0 = (t + 1) * 32;
            gld_lds16(&A[(size_t)(m0 + r0) * K + k0 + cs8], &As[cur ^ 1][d0]);
            gld_lds16(&A[(size_t)(m0 + r1) * K + k0 + cs8], &As[cur ^ 1][d1]);
            gld_lds16(&Bt[(size_t)(n0 + r0) * K + k0 + cs8], &Bs[cur ^ 1][d0]);
            if constexpr (BN == 128)
                gld_lds16(&Bt[(size_t)(n0 + r1) * K + k0 + cs8], &Bs[cur ^ 1][d1]);
        }
        short8 a[4], b[NF];
#pragma unroll
        for (int m = 0; m < 4; m++)
            a[m] = *reinterpret_cast<const short8*>(
                &As[cur][(wr * 64 + m * 16 + fr) * 32 + kswz]);
#pragma unroll
        for (int n = 0; n < NF; n++)
            b[n] = *reinterpret_cast<const short8*>(
                &Bs[cur][(wc * (BN / 2) + n * 16 + fr) * 32 + kswz]);
#pragma unroll
        for (int m = 0; m < 4; m++)
#pragma unroll
            for (int n = 0; n < NF; n++)
                acc[m][n] = __builtin_amdgcn_mfma_f32_16x16x32_bf16(
                    a[m], b[n], acc[m][n], 0, 0, 0);
        __syncthreads(); // drains vmcnt (prefetch landed) + all reads of cur done
        cur ^= 1;
    }

    const int g4 = (lane >> 4) * 4;
#pragma unroll
    for (int m = 0; m < 4; m++)
#pragma unroll
        for (int n = 0; n < NF; n++)
#pragma unroll
            for (int j = 0; j < 4; j++) {
                int mm = m0 + wr * 64 + m * 16 + g4 + j;
                int nn = n0 + wc * (BN / 2) + n * 16 + fr;
                float v = acc[m][n][j];
                if (EPI == 2) v = softplus_f(v + bias[nn]);
                if (EPI == 1) {
                    if (nn < DINNER) {
                        if constexpr (sizeof(CT) == 2)
                            C[(size_t)mm * DINNER + nn] = f2bf(v);
                        else
                            C[(size_t)mm * DINNER + nn] = v;
                    } else {
                        float sv = silu_f(v);
                        if constexpr (sizeof(CT) == 2)
                            C2[(size_t)mm * DINNER + (nn - DINNER)] = f2bf(sv);
                        else
                            C2[(size_t)mm * DINNER + (nn - DINNER)] = sv;
                    }
                } else {
                    if constexpr (sizeof(CT) == 2)
                        C[(size_t)mm * N + nn] = f2bf(v);
                    else
                        C[(size_t)mm * N + nn] = v;
                }
            }
}

// ---- proj split-K MFMA: pp[kc][M][96] partial of xb_bf @ WxT^T ----
__global__ __launch_bounds__(256) void proj_splitk(
    const unsigned short* __restrict__ Abf,   // [M][DINNER] bf16
    const unsigned short* __restrict__ WxT,   // [NPROJ][DINNER] bf16
    float* __restrict__ pp) {
    const int lane = threadIdx.x & 63;
    const int wid = threadIdx.x >> 6;
    const int mt = wid >> 1;
    const int nh = wid & 1;
    const int m0 = blockIdx.x * 32;
    const int kc = blockIdx.y;
    const int fr = lane & 15;
    const int kg = lane >> 4;

    const size_t abase = (size_t)(m0 + mt * 16 + fr) * DINNER + kc * KCH + kg * 8;

    f32x4 acc[3];
#pragma unroll
    for (int i = 0; i < 3; i++) acc[i] = (f32x4){0.f, 0.f, 0.f, 0.f};

    for (int step = 0; step < KCH / 32; step++) {
        short8 a = *reinterpret_cast<const short8*>(&Abf[abase + step * 32]);
#pragma unroll
        for (int nt = 0; nt < 3; nt++) {
            int nrow = nh * 48 + nt * 16 + fr;
            short8 b = *reinterpret_cast<const short8*>(
                &WxT[(size_t)nrow * DINNER + kc * KCH + step * 32 + kg * 8]);
            acc[nt] = __builtin_amdgcn_mfma_f32_16x16x32_bf16(a, b, acc[nt], 0, 0, 0);
        }
    }
    const int g4 = (lane >> 4) * 4;
#pragma unroll
    for (int nt = 0; nt < 3; nt++)
#pragma unroll
        for (int j = 0; j < 4; j++) {
            int m = m0 + mt * 16 + g4 + j;
            int n = nh * 48 + nt * 16 + fr;
            pp[((size_t)kc * (BSZ * LSEQ) + m) * NPROJ + n] = acc[nt][j];
        }
}

// reduce split-K partials; emit fp32 proj + bf16 dt_in (cols < DTRANK)
__global__ __launch_bounds__(256) void proj_reduce(
    const float* __restrict__ pp, float* __restrict__ proj,
    unsigned short* __restrict__ dtin) {
    int i = blockIdx.x * 256 + threadIdx.x;
    if (i >= BSZ * LSEQ * NPROJ) return;
    float s = 0.f;
#pragma unroll
    for (int kc = 0; kc < KS; kc++)
        s += pp[(size_t)kc * BSZ * LSEQ * NPROJ + i];
    proj[i] = s;
    int m = i / NPROJ;
    int n = i - m * NPROJ;
    if (n < DTRANK) dtin[(size_t)m * DTRANK + n] = f2bf(s);
}

// causal depthwise conv (k=4) + bias + silu; bf16 in/out, 8 d per thread
__global__ __launch_bounds__(256) void conv_silu_kernel(
    const unsigned short* __restrict__ xin, const float* __restrict__ w,
    const float* __restrict__ bconv, unsigned short* __restrict__ xout) {
    int i = blockIdx.x * 256 + threadIdx.x;        // (b*LSEQ+t) * 256 + d/8
    const int d0 = (i & (DINNER / 8 - 1)) * 8;
    const int bt = i >> 8;
    const int t = bt & (LSEQ - 1);
    const size_t base = (size_t)bt * DINNER + d0;

    float acc[8];
#pragma unroll
    for (int q = 0; q < 8; q++) acc[q] = bconv[d0 + q];

#pragma unroll
    for (int k = 0; k < 4; k++) {
        int tt = t + k - 3;
        if (tt >= 0) {
            short8 xv = *reinterpret_cast<const short8*>(&xin[base + (size_t)(k - 3) * DINNER]);
#pragma unroll
            for (int q = 0; q < 8; q++)
                acc[q] = fmaf(bf2f((unsigned short)xv[q]), w[(d0 + q) * 4 + k], acc[q]);
        }
    }
    short8 o;
#pragma unroll
    for (int q = 0; q < 8; q++) o[q] = (short)f2bf(silu_f(acc[q]));
    *reinterpret_cast<short8*>(&xout[base]) = o;
}

// ---- chunked selective scan (bf16 operands, fp32 state) ----
__global__ __launch_bounds__(256) void scan_pass1(
    const unsigned short* __restrict__ xb, const unsigned short* __restrict__ dt,
    const float* __restrict__ proj, const float* __restrict__ A_log,
    float* __restrict__ aprod, float* __restrict__ hend) {
    __shared__ float Bs[LC][DSTATE];
    const int tg = blockIdx.x * 256 + threadIdx.x;
    const int d = tg & (DINNER - 1);
    const int bc = tg >> 11;
    const int c = bc & (NC - 1);
    const int b = bc >> 5;

    for (int idx = threadIdx.x; idx < LC * DSTATE; idx += 256) {
        int ti = idx >> 4, j = idx & 15;
        Bs[ti][j] = proj[(size_t)(b * LSEQ + c * LC + ti) * NPROJ + DTRANK + j];
    }
    __syncthreads();

    float Av[DSTATE], h[DSTATE], ap[DSTATE];
#pragma unroll
    for (int s = 0; s < DSTATE; s++) {
        Av[s] = -expf(A_log[d * DSTATE + s]);
        h[s] = 0.f;
        ap[s] = 1.f;
    }

    for (int i = 0; i < LC; i++) {
        size_t base = (size_t)(b * LSEQ + c * LC + i) * DINNER + d;
        float dtv = bf2f(dt[base]);
        float xv = bf2f(xb[base]);
        float dx = dtv * xv;
#pragma unroll
        for (int s = 0; s < DSTATE; s++) {
            float dA = __expf(dtv * Av[s]);
            ap[s] *= dA;
            h[s] = fmaf(dA, h[s], dx * Bs[i][s]);
        }
    }

    size_t o = ((size_t)bc * DINNER + d) * DSTATE;
#pragma unroll
    for (int q = 0; q < 4; q++) {
        *reinterpret_cast<float4*>(&aprod[o + q * 4]) =
            make_float4(ap[4 * q], ap[4 * q + 1], ap[4 * q + 2], ap[4 * q + 3]);
        *reinterpret_cast<float4*>(&hend[o + q * 4]) =
            make_float4(h[4 * q], h[4 * q + 1], h[4 * q + 2], h[4 * q + 3]);
    }
}

__global__ __launch_bounds__(256) void scan_pass2(
    float* __restrict__ aprod, const float* __restrict__ hend) {
    const int tg = blockIdx.x * 256 + threadIdx.x;
    const int s = tg & (DSTATE - 1);
    const int d = (tg >> 4) & (DINNER - 1);
    const int b = tg >> 15;
    float h = 0.f;
    for (int c = 0; c < NC; c++) {
        size_t o = ((size_t)((b * NC + c) * DINNER) + d) * DSTATE + s;
        float a = aprod[o];
        float e = hend[o];
        aprod[o] = h;
        h = fmaf(a, h, e);
    }
}

__global__ __launch_bounds__(256) void scan_pass3(
    const unsigned short* __restrict__ xb, const unsigned short* __restrict__ dt,
    const float* __restrict__ proj, const float* __restrict__ hstart,
    const float* __restrict__ A_log, const float* __restrict__ Dp,
    const unsigned short* __restrict__ sz, unsigned short* __restrict__ ybf) {
    __shared__ float Bs[LC][DSTATE];
    __shared__ float Cs[LC][DSTATE];
    const int tg = blockIdx.x * 256 + threadIdx.x;
    const int d = tg & (DINNER - 1);
    const int bc = tg >> 11;
    const int c = bc & (NC - 1);
    const int b = bc >> 5;

    for (int idx = threadIdx.x; idx < LC * 2 * DSTATE; idx += 256) {
        int ti = idx >> 5, j = idx & 31;
        float v = proj[(size_t)(b * LSEQ + c * LC + ti) * NPROJ + DTRANK + j];
        if (j < DSTATE) Bs[ti][j] = v;
        else            Cs[ti][j - DSTATE] = v;
    }
    __syncthreads();

    float Av[DSTATE], h[DSTATE];
    size_t o = ((size_t)bc * DINNER + d) * DSTATE;
#pragma unroll
    for (int q = 0; q < 4; q++) {
        float4 hv = *reinterpret_cast<const float4*>(&hstart[o + q * 4]);
        h[4 * q] = hv.x; h[4 * q + 1] = hv.y; h[4 * q + 2] = hv.z; h[4 * q + 3] = hv.w;
    }
#pragma unroll
    for (int s = 0; s < DSTATE; s++)
        Av[s] = -expf(A_log[d * DSTATE + s]);
    const float Dd = Dp[d];

    for (int i = 0; i < LC; i++) {
        size_t base = (size_t)(b * LSEQ + c * LC + i) * DINNER + d;
        float dtv = bf2f(dt[base]);
        float xv = bf2f(xb[base]);
        float szv = bf2f(sz[base]);
        float dx = dtv * xv;
        float p = 0.f;
#pragma unroll
        for (int s = 0; s < DSTATE; s++) {
            float dA = __expf(dtv * Av[s]);
            h[s] = fmaf(dA, h[s], dx * Bs[i][s]);
            p = fmaf(h[s], Cs[i][s], p);
        }
        ybf[base] = f2bf((p + Dd * xv) * szv);
    }
}

extern "C" void kernel_launch(void* const* d_in, const int* in_sizes, int n_in,
                              void* d_out, int out_size, void* d_ws,
                              size_t ws_size, hipStream_t stream) {
    const float* x = (const float*)d_in[0];
    const float* W_in = (const float*)d_in[1];
    const float* conv_w = (const float*)d_in[2];
    const float* conv_b = (const float*)d_in[3];
    const float* W_xproj = (const float*)d_in[4];
    const float* W_dt = (const float*)d_in[5];
    const float* b_dt = (const float*)d_in[6];
    const float* A_log = (const float*)d_in[7];
    const float* Dp = (const float*)d_in[8];
    const float* W_out = (const float*)d_in[9];
    float* out = (float*)d_out;

    char* ws = (char*)d_ws;
    const size_t MB = 1u << 20;
    // [0,16M): pp (12.6M) -> later aprod(8M)+hend(8M)
    float* pp    = (float*)(ws);
    float* aprod = (float*)(ws);
    float* hend  = (float*)(ws + 8 * MB);
    unsigned short* xbpre_bf = (unsigned short*)(ws + 16 * MB);  // 16 MB
    unsigned short* sz_bf    = (unsigned short*)(ws + 32 * MB);  // 16 MB
    unsigned short* xb_bf    = (unsigned short*)(ws + 48 * MB);  // 16 MB
    unsigned short* dt_bf    = (unsigned short*)(ws + 64 * MB);  // 16 MB
    unsigned short* ybf      = (unsigned short*)(ws + 80 * MB);  // 8 MB
    float* projbuf           = (float*)(ws + 88 * MB);           // 1.5 MB
    unsigned short* dtin_bf  = (unsigned short*)(ws + 90 * MB);  // 0.5 MB
    unsigned short* xbf      = (unsigned short*)(ws + 91 * MB);  // 8 MB
    unsigned short* WinT     = (unsigned short*)(ws + 99 * MB);  // 8 MB
    unsigned short* WoutT    = (unsigned short*)(ws + 107 * MB); // 4 MB
    unsigned short* WxT      = (unsigned short*)(ws + 111 * MB); // 384 KB
    unsigned short* WdtT     = (unsigned short*)(ws + 112 * MB); // 256 KB

    const int M = BSZ * LSEQ; // 4096
    dim3 blk(256);

    // prep: bf16 conversions / weight transposes
    f32_to_bf16_kernel<<<dim3((M * DMODEL / 4 + 255) / 256), blk, 0, stream>>>(
        x, xbf, M * DMODEL / 4);
    transpose_bf16_kernel<<<dim3(2 * DINNER / 32, DMODEL / 32), blk, 0, stream>>>(
        W_in, WinT, DMODEL, 2 * DINNER);
    transpose_bf16_kernel<<<dim3(DMODEL / 32, DINNER / 32), blk, 0, stream>>>(
        W_out, WoutT, DINNER, DMODEL);
    transpose_bf16_kernel<<<dim3(NPROJ / 32, DINNER / 32), blk, 0, stream>>>(
        W_xproj, WxT, DINNER, NPROJ);
    transpose_bf16_kernel<<<dim3(DINNER / 32, DTRANK / 32), blk, 0, stream>>>(
        W_dt, WdtT, DTRANK, DINNER);

    // 1. xz = x @ W_in (bf16 MFMA, split: xbpre_bf | silu -> sz_bf)
    gemm_mfma<1, 128, unsigned short><<<dim3((2 * DINNER) / 128, M / 128), blk, 0, stream>>>(
        xbf, WinT, xbpre_bf, sz_bf, nullptr, M, 2 * DINNER, DMODEL);

    // 2. conv + silu (bf16 -> bf16, 8 d/thread)
    conv_silu_kernel<<<dim3((M * DINNER / 8) / 256), blk, 0, stream>>>(
        xbpre_bf, conv_w, conv_b, xb_bf);

    // 3. proj = xb @ W_xproj via split-K MFMA + reduce (emits fp32 proj + bf16 dt_in)
    proj_splitk<<<dim3(M / 32, KS), blk, 0, stream>>>(xb_bf, WxT, pp);
    proj_reduce<<<dim3((M * NPROJ) / 256), blk, 0, stream>>>(pp, projbuf, dtin_bf);

    // 4. dt = softplus(dt_in @ W_dt + b_dt) (bf16 MFMA, K=64, BN=64)
    gemm_mfma<2, 64, unsigned short><<<dim3(DINNER / 64, M / 128), blk, 0, stream>>>(
        dtin_bf, WdtT, dt_bf, nullptr, b_dt, M, DINNER, DTRANK);

    // 5. chunked selective scan
    const int nthreads1 = BSZ * NC * DINNER;
    scan_pass1<<<dim3(nthreads1 / 256), blk, 0, stream>>>(
        xb_bf, dt_bf, projbuf, A_log, aprod, hend);
    const int nthreads2 = BSZ * DINNER * DSTATE;
    scan_pass2<<<dim3(nthreads2 / 256), blk, 0, stream>>>(aprod, hend);
    scan_pass3<<<dim3(nthreads1 / 256), blk, 0, stream>>>(
        xb_bf, dt_bf, projbuf, aprod, A_log, Dp, sz_bf, ybf);

    // 6. out = y @ W_out (bf16 MFMA, BN=64 -> 512 blocks, fp32 store)
    gemm_mfma<0, 64, float><<<dim3(DMODEL / 64, M / 128), blk, 0, stream>>>(
        ybf, WoutT, out, nullptr, nullptr, M, DMODEL, DINNER);
}

// Round 8
// 327.288 us; speedup vs baseline: 1.0047x; 1.0047x over previous
//
#include <hip/hip_runtime.h>
#include <hip/hip_bf16.h>
#include <math.h>

#define BSZ 2
#define LSEQ 2048
#define DMODEL 1024
#define DSTATE 16
#define DCONV 4
#define DINNER 2048
#define DTRANK 64
#define NPROJ (DTRANK + 2 * DSTATE) // 96
#define NC 32   // scan chunks
#define LC 64   // steps per chunk
#define KS 8    // proj split-K chunks
#define KCH (DINNER / KS) // 256

using short8 = __attribute__((ext_vector_type(8))) short;
using f32x4 = __attribute__((ext_vector_type(4))) float;
using u16x4 = __attribute__((ext_vector_type(4))) unsigned short;

__device__ __forceinline__ float silu_f(float v) {
    return v / (1.f + expf(-v));
}
__device__ __forceinline__ float softplus_f(float v) {
    return fmaxf(v, 0.f) + log1pf(expf(-fabsf(v)));
}
// fp32 -> bf16 bits, round-to-nearest-even
__device__ __forceinline__ unsigned short f2bf(float f) {
    unsigned u = __builtin_bit_cast(unsigned, f);
    u += 0x7fffu + ((u >> 16) & 1u);
    return (unsigned short)(u >> 16);
}
__device__ __forceinline__ float bf2f(unsigned short u) {
    unsigned x = ((unsigned)u) << 16;
    return __builtin_bit_cast(float, x);
}

__device__ __forceinline__ void gld_lds16(const unsigned short* g, unsigned short* l) {
    __builtin_amdgcn_global_load_lds(
        (const __attribute__((address_space(1))) unsigned int*)g,
        (__attribute__((address_space(3))) unsigned int*)l, 16, 0, 0);
}

// ---- fused prep: x->bf16 + 4 weight transposes (fp32 [R][Cc] -> bf16 [Cc][R]) ----
__global__ __launch_bounds__(256) void prep_kernel(
    const float* __restrict__ x, const float* __restrict__ W_in,
    const float* __restrict__ W_out, const float* __restrict__ W_xproj,
    const float* __restrict__ W_dt,
    unsigned short* __restrict__ xbf, unsigned short* __restrict__ WinT,
    unsigned short* __restrict__ WoutT, unsigned short* __restrict__ WxT,
    unsigned short* __restrict__ WdtT) {
    int bid = blockIdx.x;
    if (bid < 4096) { // x -> bf16 (4096*1024 floats, float4 per thread)
        int i = bid * 256 + threadIdx.x;
        float4 v = reinterpret_cast<const float4*>(x)[i];
        u16x4 o = {f2bf(v.x), f2bf(v.y), f2bf(v.z), f2bf(v.w)};
        reinterpret_cast<u16x4*>(xbf)[i] = o;
        return;
    }
    bid -= 4096;
    const float* in;
    unsigned short* outp;
    int R, Cc, gx;
    if (bid < 4096) { in = W_in; outp = WinT; R = 1024; Cc = 4096; gx = 128; }
    else if ((bid -= 4096) < 2048) { in = W_out; outp = WoutT; R = 2048; Cc = 1024; gx = 32; }
    else if ((bid -= 2048) < 192) { in = W_xproj; outp = WxT; R = 2048; Cc = 96; gx = 3; }
    else { bid -= 192; in = W_dt; outp = WdtT; R = 64; Cc = 2048; gx = 64; }
    const int bx = bid % gx, by = bid / gx;
    __shared__ float t[32][33];
    const int tx = threadIdx.x & 31, ty = threadIdx.x >> 5; // 32 x 8
    const int c0 = bx * 32, r0 = by * 32;
    for (int i = ty; i < 32; i += 8)
        t[i][tx] = in[(size_t)(r0 + i) * Cc + c0 + tx];
    __syncthreads();
    for (int i = ty; i < 32; i += 8)
        outp[(size_t)(c0 + i) * R + r0 + tx] = f2bf(t[tx][i]);
}

// ---- bf16 MFMA GEMM: C[M,N] = A[M,K] @ Bt[N,K]^T ----
// 128xBN tile, 4 waves (2x2), BK=32, double-buffered with COUNTED vmcnt:
//   iter: barrier | stage next tile (4 loads) | vmcnt(4) (prev tile landed,
//   new 4 stay in flight across MFMA phase) | barrier | ds_read+MFMA.
// LDS [row][32] row-major, chunk swizzle chunk' = chunk ^ ((row>>1)&3)
// (pre-swizzled global source + swizzled fragment read; 2-way bank = free).
// EPI 0: plain. EPI 1: n<DINNER -> C else silu -> C2 (ldc=DINNER). EPI 2: softplus+bias.
template <int EPI, int BN, typename CT>
__global__ __launch_bounds__(256) void gemm_mfma(
    const unsigned short* __restrict__ A, const unsigned short* __restrict__ Bt,
    CT* __restrict__ C, CT* __restrict__ C2, const float* __restrict__ bias,
    int M, int N, int K) {
    constexpr int NF = BN / 32;                 // per-wave n-frags
    __shared__ __align__(16) unsigned short As[2][4096];
    __shared__ __align__(16) unsigned short Bs[2][BN * 32];
    const int tid = threadIdx.x;
    const int lane = tid & 63;
    const int wid = tid >> 6;
    const int wr = wid >> 1, wc = wid & 1;
    const int m0 = blockIdx.y * 128, n0 = blockIdx.x * BN;

    const int r0 = tid >> 2;              // rows 0..63
    const int r1 = r0 + 64;               // rows 64..127
    const int d0 = tid * 8;
    const int d1 = d0 + 2048;
    const int cs8 = (((tid & 3) ^ ((tid >> 3) & 3)) << 3); // swizzled src chunk

    f32x4 acc[4][NF];
#pragma unroll
    for (int m = 0; m < 4; m++)
#pragma unroll
        for (int n = 0; n < NF; n++) acc[m][n] = (f32x4){0.f, 0.f, 0.f, 0.f};

    const int fr = lane & 15;
    const int kg = lane >> 4;
    const int kswz = ((kg ^ ((fr >> 1) & 3)) << 3);
    const int nt = K / 32;

    // prologue: stage tile 0 into buffer 0 (4 loads in flight)
    gld_lds16(&A[(size_t)(m0 + r0) * K + cs8], &As[0][d0]);
    gld_lds16(&A[(size_t)(m0 + r1) * K + cs8], &As[0][d1]);
    gld_lds16(&Bt[(size_t)(n0 + r0) * K + cs8], &Bs[0][d0]);
    if constexpr (BN == 128)
        gld_lds16(&Bt[(size_t)(n0 + r1) * K + cs8], &Bs[0][d1]);

    int cur = 0;
    for (int t = 0; t < nt; t++) {
        // all waves finished reading buf[cur^1] (iter t-1) -> safe to overwrite
        __builtin_amdgcn_s_barrier();
        if (t + 1 < nt) {
            const int k0 = (t + 1) * 32;
            gld_lds16(&A[(size_t)(m0 + r0) * K + k0 + cs8], &As[cur ^ 1][d0]);
            gld_lds16(&A[(size_t)(m0 + r1) * K + k0 + cs8], &As[cur ^ 1][d1]);
            gld_lds16(&Bt[(size_t)(n0 + r0) * K + k0 + cs8], &Bs[cur ^ 1][d0]);
            if constexpr (BN == 128) {
                gld_lds16(&Bt[(size_t)(n0 + r1) * K + k0 + cs8], &Bs[cur ^ 1][d1]);
                asm volatile("s_waitcnt vmcnt(4)" ::: "memory");
            } else {
                asm volatile("s_waitcnt vmcnt(3)" ::: "memory");
            }
        } else {
            asm volatile("s_waitcnt vmcnt(0)" ::: "memory");
        }
        // buf[cur] loads landed on every wave
        __builtin_amdgcn_s_barrier();

        short8 a[4], b[NF];
#pragma unroll
        for (int m = 0; m < 4; m++)
            a[m] = *reinterpret_cast<const short8*>(
                &As[cur][(wr * 64 + m * 16 + fr) * 32 + kswz]);
#pragma unroll
        for (int n = 0; n < NF; n++)
            b[n] = *reinterpret_cast<const short8*>(
                &Bs[cur][(wc * (BN / 2) + n * 16 + fr) * 32 + kswz]);
#pragma unroll
        for (int m = 0; m < 4; m++)
#pragma unroll
            for (int n = 0; n < NF; n++)
                acc[m][n] = __builtin_amdgcn_mfma_f32_16x16x32_bf16(
                    a[m], b[n], acc[m][n], 0, 0, 0);
        cur ^= 1;
    }

    const int g4 = (lane >> 4) * 4;
#pragma unroll
    for (int m = 0; m < 4; m++)
#pragma unroll
        for (int n = 0; n < NF; n++)
#pragma unroll
            for (int j = 0; j < 4; j++) {
                int mm = m0 + wr * 64 + m * 16 + g4 + j;
                int nn = n0 + wc * (BN / 2) + n * 16 + fr;
                float v = acc[m][n][j];
                if (EPI == 2) v = softplus_f(v + bias[nn]);
                if (EPI == 1) {
                    if (nn < DINNER) {
                        if constexpr (sizeof(CT) == 2)
                            C[(size_t)mm * DINNER + nn] = f2bf(v);
                        else
                            C[(size_t)mm * DINNER + nn] = v;
                    } else {
                        float sv = silu_f(v);
                        if constexpr (sizeof(CT) == 2)
                            C2[(size_t)mm * DINNER + (nn - DINNER)] = f2bf(sv);
                        else
                            C2[(size_t)mm * DINNER + (nn - DINNER)] = sv;
                    }
                } else {
                    if constexpr (sizeof(CT) == 2)
                        C[(size_t)mm * N + nn] = f2bf(v);
                    else
                        C[(size_t)mm * N + nn] = v;
                }
            }
}

// ---- proj split-K MFMA: pp[kc][M][96] partial of xb_bf @ WxT^T ----
__global__ __launch_bounds__(256) void proj_splitk(
    const unsigned short* __restrict__ Abf,   // [M][DINNER] bf16
    const unsigned short* __restrict__ WxT,   // [NPROJ][DINNER] bf16
    float* __restrict__ pp) {
    const int lane = threadIdx.x & 63;
    const int wid = threadIdx.x >> 6;
    const int mt = wid >> 1;
    const int nh = wid & 1;
    const int m0 = blockIdx.x * 32;
    const int kc = blockIdx.y;
    const int fr = lane & 15;
    const int kg = lane >> 4;

    const size_t abase = (size_t)(m0 + mt * 16 + fr) * DINNER + kc * KCH + kg * 8;

    f32x4 acc[3];
#pragma unroll
    for (int i = 0; i < 3; i++) acc[i] = (f32x4){0.f, 0.f, 0.f, 0.f};

    for (int step = 0; step < KCH / 32; step++) {
        short8 a = *reinterpret_cast<const short8*>(&Abf[abase + step * 32]);
#pragma unroll
        for (int nt = 0; nt < 3; nt++) {
            int nrow = nh * 48 + nt * 16 + fr;
            short8 b = *reinterpret_cast<const short8*>(
                &WxT[(size_t)nrow * DINNER + kc * KCH + step * 32 + kg * 8]);
            acc[nt] = __builtin_amdgcn_mfma_f32_16x16x32_bf16(a, b, acc[nt], 0, 0, 0);
        }
    }
    const int g4 = (lane >> 4) * 4;
#pragma unroll
    for (int nt = 0; nt < 3; nt++)
#pragma unroll
        for (int j = 0; j < 4; j++) {
            int m = m0 + mt * 16 + g4 + j;
            int n = nh * 48 + nt * 16 + fr;
            pp[((size_t)kc * (BSZ * LSEQ) + m) * NPROJ + n] = acc[nt][j];
        }
}

// reduce split-K partials; emit fp32 proj + bf16 dt_in (cols < DTRANK)
__global__ __launch_bounds__(256) void proj_reduce(
    const float* __restrict__ pp, float* __restrict__ proj,
    unsigned short* __restrict__ dtin) {
    int i = blockIdx.x * 256 + threadIdx.x;
    if (i >= BSZ * LSEQ * NPROJ) return;
    float s = 0.f;
#pragma unroll
    for (int kc = 0; kc < KS; kc++)
        s += pp[(size_t)kc * BSZ * LSEQ * NPROJ + i];
    proj[i] = s;
    int m = i / NPROJ;
    int n = i - m * NPROJ;
    if (n < DTRANK) dtin[(size_t)m * DTRANK + n] = f2bf(s);
}

// causal depthwise conv (k=4) + bias + silu; bf16 in/out, 8 d per thread
__global__ __launch_bounds__(256) void conv_silu_kernel(
    const unsigned short* __restrict__ xin, const float* __restrict__ w,
    const float* __restrict__ bconv, unsigned short* __restrict__ xout) {
    int i = blockIdx.x * 256 + threadIdx.x;        // (b*LSEQ+t) * 256 + d/8
    const int d0 = (i & (DINNER / 8 - 1)) * 8;
    const int bt = i >> 8;
    const int t = bt & (LSEQ - 1);
    const size_t base = (size_t)bt * DINNER + d0;

    float acc[8];
#pragma unroll
    for (int q = 0; q < 8; q++) acc[q] = bconv[d0 + q];

#pragma unroll
    for (int k = 0; k < 4; k++) {
        int tt = t + k - 3;
        if (tt >= 0) {
            short8 xv = *reinterpret_cast<const short8*>(&xin[base + (size_t)(k - 3) * DINNER]);
#pragma unroll
            for (int q = 0; q < 8; q++)
                acc[q] = fmaf(bf2f((unsigned short)xv[q]), w[(d0 + q) * 4 + k], acc[q]);
        }
    }
    short8 o;
#pragma unroll
    for (int q = 0; q < 8; q++) o[q] = (short)f2bf(silu_f(acc[q]));
    *reinterpret_cast<short8*>(&xout[base]) = o;
}

// ---- chunked selective scan (bf16 operands, fp32 state) ----
__global__ __launch_bounds__(256) void scan_pass1(
    const unsigned short* __restrict__ xb, const unsigned short* __restrict__ dt,
    const float* __restrict__ proj, const float* __restrict__ A_log,
    float* __restrict__ aprod, float* __restrict__ hend) {
    __shared__ float Bs[LC][DSTATE];
    const int tg = blockIdx.x * 256 + threadIdx.x;
    const int d = tg & (DINNER - 1);
    const int bc = tg >> 11;
    const int c = bc & (NC - 1);
    const int b = bc >> 5;

    for (int idx = threadIdx.x; idx < LC * DSTATE; idx += 256) {
        int ti = idx >> 4, j = idx & 15;
        Bs[ti][j] = proj[(size_t)(b * LSEQ + c * LC + ti) * NPROJ + DTRANK + j];
    }
    __syncthreads();

    float Av[DSTATE], h[DSTATE], ap[DSTATE];
#pragma unroll
    for (int s = 0; s < DSTATE; s++) {
        Av[s] = -expf(A_log[d * DSTATE + s]);
        h[s] = 0.f;
        ap[s] = 1.f;
    }

    for (int i = 0; i < LC; i++) {
        size_t base = (size_t)(b * LSEQ + c * LC + i) * DINNER + d;
        float dtv = bf2f(dt[base]);
        float xv = bf2f(xb[base]);
        float dx = dtv * xv;
#pragma unroll
        for (int s = 0; s < DSTATE; s++) {
            float dA = __expf(dtv * Av[s]);
            ap[s] *= dA;
            h[s] = fmaf(dA, h[s], dx * Bs[i][s]);
        }
    }

    size_t o = ((size_t)bc * DINNER + d) * DSTATE;
#pragma unroll
    for (int q = 0; q < 4; q++) {
        *reinterpret_cast<float4*>(&aprod[o + q * 4]) =
            make_float4(ap[4 * q], ap[4 * q + 1], ap[4 * q + 2], ap[4 * q + 3]);
        *reinterpret_cast<float4*>(&hend[o + q * 4]) =
            make_float4(h[4 * q], h[4 * q + 1], h[4 * q + 2], h[4 * q + 3]);
    }
}

__global__ __launch_bounds__(256) void scan_pass2(
    float* __restrict__ aprod, const float* __restrict__ hend) {
    const int tg = blockIdx.x * 256 + threadIdx.x;
    const int s = tg & (DSTATE - 1);
    const int d = (tg >> 4) & (DINNER - 1);
    const int b = tg >> 15;
    float h = 0.f;
    for (int c = 0; c < NC; c++) {
        size_t o = ((size_t)((b * NC + c) * DINNER) + d) * DSTATE + s;
        float a = aprod[o];
        float e = hend[o];
        aprod[o] = h;
        h = fmaf(a, h, e);
    }
}

__global__ __launch_bounds__(256) void scan_pass3(
    const unsigned short* __restrict__ xb, const unsigned short* __restrict__ dt,
    const float* __restrict__ proj, const float* __restrict__ hstart,
    const float* __restrict__ A_log, const float* __restrict__ Dp,
    const unsigned short* __restrict__ sz, unsigned short* __restrict__ ybf) {
    __shared__ float Bs[LC][DSTATE];
    __shared__ float Cs[LC][DSTATE];
    const int tg = blockIdx.x * 256 + threadIdx.x;
    const int d = tg & (DINNER - 1);
    const int bc = tg >> 11;
    const int c = bc & (NC - 1);
    const int b = bc >> 5;

    for (int idx = threadIdx.x; idx < LC * 2 * DSTATE; idx += 256) {
        int ti = idx >> 5, j = idx & 31;
        float v = proj[(size_t)(b * LSEQ + c * LC + ti) * NPROJ + DTRANK + j];
        if (j < DSTATE) Bs[ti][j] = v;
        else            Cs[ti][j - DSTATE] = v;
    }
    __syncthreads();

    float Av[DSTATE], h[DSTATE];
    size_t o = ((size_t)bc * DINNER + d) * DSTATE;
#pragma unroll
    for (int q = 0; q < 4; q++) {
        float4 hv = *reinterpret_cast<const float4*>(&hstart[o + q * 4]);
        h[4 * q] = hv.x; h[4 * q + 1] = hv.y; h[4 * q + 2] = hv.z; h[4 * q + 3] = hv.w;
    }
#pragma unroll
    for (int s = 0; s < DSTATE; s++)
        Av[s] = -expf(A_log[d * DSTATE + s]);
    const float Dd = Dp[d];

    for (int i = 0; i < LC; i++) {
        size_t base = (size_t)(b * LSEQ + c * LC + i) * DINNER + d;
        float dtv = bf2f(dt[base]);
        float xv = bf2f(xb[base]);
        float szv = bf2f(sz[base]);
        float dx = dtv * xv;
        float p = 0.f;
#pragma unroll
        for (int s = 0; s < DSTATE; s++) {
            float dA = __expf(dtv * Av[s]);
            h[s] = fmaf(dA, h[s], dx * Bs[i][s]);
            p = fmaf(h[s], Cs[i][s], p);
        }
        ybf[base] = f2bf((p + Dd * xv) * szv);
    }
}

extern "C" void kernel_launch(void* const* d_in, const int* in_sizes, int n_in,
                              void* d_out, int out_size, void* d_ws,
                              size_t ws_size, hipStream_t stream) {
    const float* x = (const float*)d_in[0];
    const float* W_in = (const float*)d_in[1];
    const float* conv_w = (const float*)d_in[2];
    const float* conv_b = (const float*)d_in[3];
    const float* W_xproj = (const float*)d_in[4];
    const float* W_dt = (const float*)d_in[5];
    const float* b_dt = (const float*)d_in[6];
    const float* A_log = (const float*)d_in[7];
    const float* Dp = (const float*)d_in[8];
    const float* W_out = (const float*)d_in[9];
    float* out = (float*)d_out;

    char* ws = (char*)d_ws;
    const size_t MB = 1u << 20;
    // [0,16M): pp (12.6M) -> later aprod(8M)+hend(8M)
    float* pp    = (float*)(ws);
    float* aprod = (float*)(ws);
    float* hend  = (float*)(ws + 8 * MB);
    unsigned short* xbpre_bf = (unsigned short*)(ws + 16 * MB);  // 16 MB
    unsigned short* sz_bf    = (unsigned short*)(ws + 32 * MB);  // 16 MB
    unsigned short* xb_bf    = (unsigned short*)(ws + 48 * MB);  // 16 MB
    unsigned short* dt_bf    = (unsigned short*)(ws + 64 * MB);  // 16 MB
    unsigned short* ybf      = (unsigned short*)(ws + 80 * MB);  // 8 MB
    float* projbuf           = (float*)(ws + 88 * MB);           // 1.5 MB
    unsigned short* dtin_bf  = (unsigned short*)(ws + 90 * MB);  // 0.5 MB
    unsigned short* xbf      = (unsigned short*)(ws + 91 * MB);  // 8 MB
    unsigned short* WinT     = (unsigned short*)(ws + 99 * MB);  // 8 MB
    unsigned short* WoutT    = (unsigned short*)(ws + 107 * MB); // 4 MB
    unsigned short* WxT      = (unsigned short*)(ws + 111 * MB); // 384 KB
    unsigned short* WdtT     = (unsigned short*)(ws + 112 * MB); // 256 KB

    const int M = BSZ * LSEQ; // 4096
    dim3 blk(256);

    // 0. fused prep: x->bf16 + 4 transposes (1 launch)
    prep_kernel<<<dim3(4096 + 4096 + 2048 + 192 + 128), blk, 0, stream>>>(
        x, W_in, W_out, W_xproj, W_dt, xbf, WinT, WoutT, WxT, WdtT);

    // 1. xz = x @ W_in (bf16 MFMA, split: xbpre_bf | silu -> sz_bf)
    gemm_mfma<1, 128, unsigned short><<<dim3((2 * DINNER) / 128, M / 128), blk, 0, stream>>>(
        xbf, WinT, xbpre_bf, sz_bf, nullptr, M, 2 * DINNER, DMODEL);

    // 2. conv + silu (bf16 -> bf16, 8 d/thread)
    conv_silu_kernel<<<dim3((M * DINNER / 8) / 256), blk, 0, stream>>>(
        xbpre_bf, conv_w, conv_b, xb_bf);

    // 3. proj = xb @ W_xproj via split-K MFMA + reduce (emits fp32 proj + bf16 dt_in)
    proj_splitk<<<dim3(M / 32, KS), blk, 0, stream>>>(xb_bf, WxT, pp);
    proj_reduce<<<dim3((M * NPROJ) / 256), blk, 0, stream>>>(pp, projbuf, dtin_bf);

    // 4. dt = softplus(dt_in @ W_dt + b_dt) (bf16 MFMA, K=64, BN=128)
    gemm_mfma<2, 128, unsigned short><<<dim3(DINNER / 128, M / 128), blk, 0, stream>>>(
        dtin_bf, WdtT, dt_bf, nullptr, b_dt, M, DINNER, DTRANK);

    // 5. chunked selective scan
    const int nthreads1 = BSZ * NC * DINNER;
    scan_pass1<<<dim3(nthreads1 / 256), blk, 0, stream>>>(
        xb_bf, dt_bf, projbuf, A_log, aprod, hend);
    const int nthreads2 = BSZ * DINNER * DSTATE;
    scan_pass2<<<dim3(nthreads2 / 256), blk, 0, stream>>>(aprod, hend);
    scan_pass3<<<dim3(nthreads1 / 256), blk, 0, stream>>>(
        xb_bf, dt_bf, projbuf, aprod, A_log, Dp, sz_bf, ybf);

    // 6. out = y @ W_out (bf16 MFMA, BN=128, fp32 store)
    gemm_mfma<0, 128, float><<<dim3(DMODEL / 128, M / 128), blk, 0, stream>>>(
        ybf, WoutT, out, nullptr, nullptr, M, DMODEL, DINNER);
}

// Round 9
// 324.800 us; speedup vs baseline: 1.0124x; 1.0077x over previous
//
#include <hip/hip_runtime.h>
#include <hip/hip_bf16.h>
#include <math.h>

#define BSZ 2
#define LSEQ 2048
#define DMODEL 1024
#define DSTATE 16
#define DCONV 4
#define DINNER 2048
#define DTRANK 64
#define NPROJ (DTRANK + 2 * DSTATE) // 96
#define NC 32   // scan chunks
#define LC 64   // steps per chunk
#define KS 8    // proj split-K chunks
#define KCH (DINNER / KS) // 256

using short8 = __attribute__((ext_vector_type(8))) short;
using f32x4 = __attribute__((ext_vector_type(4))) float;
using u16x4 = __attribute__((ext_vector_type(4))) unsigned short;

__device__ __forceinline__ float silu_f(float v) {
    return v / (1.f + expf(-v));
}
__device__ __forceinline__ float softplus_f(float v) {
    return fmaxf(v, 0.f) + log1pf(expf(-fabsf(v)));
}
// fp32 -> bf16 bits, round-to-nearest-even
__device__ __forceinline__ unsigned short f2bf(float f) {
    unsigned u = __builtin_bit_cast(unsigned, f);
    u += 0x7fffu + ((u >> 16) & 1u);
    return (unsigned short)(u >> 16);
}
__device__ __forceinline__ float bf2f(unsigned short u) {
    unsigned x = ((unsigned)u) << 16;
    return __builtin_bit_cast(float, x);
}

__device__ __forceinline__ void gld_lds16(const unsigned short* g, unsigned short* l) {
    __builtin_amdgcn_global_load_lds(
        (const __attribute__((address_space(1))) unsigned int*)g,
        (__attribute__((address_space(3))) unsigned int*)l, 16, 0, 0);
}

// ---- prep: fp32 -> bf16 (same layout), n4 = n/4 ----
__global__ __launch_bounds__(256) void f32_to_bf16_kernel(
    const float* __restrict__ in, unsigned short* __restrict__ out, int n4) {
    int i = blockIdx.x * 256 + threadIdx.x;
    if (i >= n4) return;
    float4 v = reinterpret_cast<const float4*>(in)[i];
    u16x4 o = {f2bf(v.x), f2bf(v.y), f2bf(v.z), f2bf(v.w)};
    reinterpret_cast<u16x4*>(out)[i] = o;
}

// ---- prep: transpose fp32 [R][Cc] -> bf16 [Cc][R] ----
__global__ __launch_bounds__(256) void transpose_bf16_kernel(
    const float* __restrict__ in, unsigned short* __restrict__ out, int R, int Cc) {
    __shared__ float t[32][33];
    const int tx = threadIdx.x & 31, ty = threadIdx.x >> 5; // 32 x 8
    const int c0 = blockIdx.x * 32, r0 = blockIdx.y * 32;
    for (int i = ty; i < 32; i += 8)
        t[i][tx] = in[(size_t)(r0 + i) * Cc + c0 + tx];
    __syncthreads();
    for (int i = ty; i < 32; i += 8)
        out[(size_t)(c0 + i) * R + r0 + tx] = f2bf(t[tx][i]);
}

// ===== 256x256 8-wave phase-interleaved MFMA GEMM (xz) =====
// 512 thr = 8 waves (2m x 4n); per-wave C = 128x64 (8x4 frags of 16x16).
// BK=32, triple-buffered LDS (96 KB dynamic), counted vmcnt(4) once per K-tile.
// Per phase: ds_read frags | 2x global_load_lds (tile t+2) | barrier |
//            lgkmcnt(0)+sched_barrier | setprio(1) 16 MFMA setprio(0) | barrier.
// LDS [256][32] rows, chunk swizzle chunk' = chunk ^ ((row>>1)&3) (2-way = free).
// EPI 1: n<DINNER -> C, else silu -> C2 (both bf16, ldc=DINNER).
template <int EPI, typename CT>
__global__ __launch_bounds__(512) void gemm256(
    const unsigned short* __restrict__ A, const unsigned short* __restrict__ Bt,
    CT* __restrict__ C, CT* __restrict__ C2, int M, int N, int K) {
    extern __shared__ __align__(16) unsigned short lds[];
    unsigned short* As = lds;            // [3][8192]
    unsigned short* Bs = lds + 3 * 8192; // [3][8192]
    const int tid = threadIdx.x;
    const int lane = tid & 63;
    const int w = tid >> 6;
    const int wm = w >> 2, wn = w & 3;
    const int m0 = blockIdx.y * 256, n0 = blockIdx.x * 256;
    const int fr = lane & 15, kg = lane >> 4;
    const int kswz = ((kg ^ ((fr >> 1) & 3)) << 3);
    const int srow = tid >> 2;           // staging row within 128-half
    const int cs8 = (((tid & 3) ^ ((tid >> 3) & 3)) << 3);
    const int dst = tid * 8;             // lane-linear LDS elem offset
    const int nt = K / 32;

    f32x4 acc[8][4];
#pragma unroll
    for (int m = 0; m < 8; m++)
#pragma unroll
        for (int n = 0; n < 4; n++) acc[m][n] = (f32x4){0.f, 0.f, 0.f, 0.f};

#define STAGE_A(t)                                                               \
    {                                                                            \
        const int _b = (t) % 3, _k = (t) * 32;                                   \
        gld_lds16(&A[(size_t)(m0 + srow) * K + _k + cs8], &As[_b * 8192 + dst]); \
        gld_lds16(&A[(size_t)(m0 + 128 + srow) * K + _k + cs8],                  \
                  &As[_b * 8192 + dst + 4096]);                                  \
    }
#define STAGE_B(t)                                                               \
    {                                                                            \
        const int _b = (t) % 3, _k = (t) * 32;                                   \
        gld_lds16(&Bt[(size_t)(n0 + srow) * K + _k + cs8], &Bs[_b * 8192 + dst]);\
        gld_lds16(&Bt[(size_t)(n0 + 128 + srow) * K + _k + cs8],                 \
                  &Bs[_b * 8192 + dst + 4096]);                                  \
    }

    // prologue: tiles 0 and 1 in flight; wait tile 0 only
    STAGE_A(0); STAGE_B(0); STAGE_A(1); STAGE_B(1);
    asm volatile("s_waitcnt vmcnt(4)" ::: "memory");
    __builtin_amdgcn_s_barrier();

    short8 bfr[4];
    for (int t = 0; t < nt; t++) {
        const int buf = t % 3;
        // ---- phase 0: m-frags 0..3 ----
        short8 afr[4];
#pragma unroll
        for (int q = 0; q < 4; q++)
            afr[q] = *reinterpret_cast<const short8*>(
                &As[buf * 8192 + (wm * 128 + q * 16 + fr) * 32 + kswz]);
#pragma unroll
        for (int q = 0; q < 4; q++)
            bfr[q] = *reinterpret_cast<const short8*>(
                &Bs[buf * 8192 + (wn * 64 + q * 16 + fr) * 32 + kswz]);
        if (t + 2 < nt) STAGE_A(t + 2);
        __builtin_amdgcn_s_barrier();
        asm volatile("s_waitcnt lgkmcnt(0)" ::: "memory");
        __builtin_amdgcn_sched_barrier(0);
        __builtin_amdgcn_s_setprio(1);
#pragma unroll
        for (int m = 0; m < 4; m++)
#pragma unroll
            for (int n = 0; n < 4; n++)
                acc[m][n] = __builtin_amdgcn_mfma_f32_16x16x32_bf16(
                    afr[m], bfr[n], acc[m][n], 0, 0, 0);
        __builtin_amdgcn_s_setprio(0);
        __builtin_amdgcn_s_barrier();
        // ---- phase 1: m-frags 4..7 (reuse bfr) ----
#pragma unroll
        for (int q = 0; q < 4; q++)
            afr[q] = *reinterpret_cast<const short8*>(
                &As[buf * 8192 + (wm * 128 + 64 + q * 16 + fr) * 32 + kswz]);
        if (t + 2 < nt) STAGE_B(t + 2);
        if (t + 1 < nt) { // guarantee tile t+1 landed before its phase-0 reads
            if (t + 2 < nt)
                asm volatile("s_waitcnt vmcnt(4)" ::: "memory");
            else
                asm volatile("s_waitcnt vmcnt(0)" ::: "memory");
        }
        __builtin_amdgcn_s_barrier();
        asm volatile("s_waitcnt lgkmcnt(0)" ::: "memory");
        __builtin_amdgcn_sched_barrier(0);
        __builtin_amdgcn_s_setprio(1);
#pragma unroll
        for (int m = 0; m < 4; m++)
#pragma unroll
            for (int n = 0; n < 4; n++)
                acc[4 + m][n] = __builtin_amdgcn_mfma_f32_16x16x32_bf16(
                    afr[m], bfr[n], acc[4 + m][n], 0, 0, 0);
        __builtin_amdgcn_s_setprio(0);
        __builtin_amdgcn_s_barrier();
    }
#undef STAGE_A
#undef STAGE_B

    const int g4 = kg * 4;
#pragma unroll
    for (int m = 0; m < 8; m++)
#pragma unroll
        for (int n = 0; n < 4; n++)
#pragma unroll
            for (int j = 0; j < 4; j++) {
                int mm = m0 + wm * 128 + m * 16 + g4 + j;
                int nn = n0 + wn * 64 + n * 16 + fr;
                float v = acc[m][n][j];
                if (EPI == 1) {
                    if (nn < DINNER)
                        C[(size_t)mm * DINNER + nn] = f2bf(v);
                    else
                        C2[(size_t)mm * DINNER + (nn - DINNER)] = f2bf(silu_f(v));
                } else {
                    if constexpr (sizeof(CT) == 2)
                        C[(size_t)mm * N + nn] = f2bf(v);
                    else
                        C[(size_t)mm * N + nn] = v;
                }
            }
}

// ---- 128xBN 2-phase MFMA GEMM (dt, out) — r6-proven __syncthreads loop ----
template <int EPI, int BN, typename CT>
__global__ __launch_bounds__(256) void gemm_mfma(
    const unsigned short* __restrict__ A, const unsigned short* __restrict__ Bt,
    CT* __restrict__ C, CT* __restrict__ C2, const float* __restrict__ bias,
    int M, int N, int K) {
    constexpr int NF = BN / 32;
    __shared__ __align__(16) unsigned short As[2][4096];
    __shared__ __align__(16) unsigned short Bs[2][BN * 32];
    const int tid = threadIdx.x;
    const int lane = tid & 63;
    const int wid = tid >> 6;
    const int wr = wid >> 1, wc = wid & 1;
    const int m0 = blockIdx.y * 128, n0 = blockIdx.x * BN;

    const int r0 = tid >> 2;
    const int r1 = r0 + 64;
    const int d0 = tid * 8;
    const int d1 = d0 + 2048;
    const int cs8 = (((tid & 3) ^ ((tid >> 3) & 3)) << 3);

    f32x4 acc[4][NF];
#pragma unroll
    for (int m = 0; m < 4; m++)
#pragma unroll
        for (int n = 0; n < NF; n++) acc[m][n] = (f32x4){0.f, 0.f, 0.f, 0.f};

    const int fr = lane & 15;
    const int kg = lane >> 4;
    const int kswz = ((kg ^ ((fr >> 1) & 3)) << 3);
    const int nt = K / 32;

    gld_lds16(&A[(size_t)(m0 + r0) * K + cs8], &As[0][d0]);
    gld_lds16(&A[(size_t)(m0 + r1) * K + cs8], &As[0][d1]);
    gld_lds16(&Bt[(size_t)(n0 + r0) * K + cs8], &Bs[0][d0]);
    if constexpr (BN == 128)
        gld_lds16(&Bt[(size_t)(n0 + r1) * K + cs8], &Bs[0][d1]);
    __syncthreads();

    int cur = 0;
    for (int t = 0; t < nt; t++) {
        if (t + 1 < nt) {
            const int k0 = (t + 1) * 32;
            gld_lds16(&A[(size_t)(m0 + r0) * K + k0 + cs8], &As[cur ^ 1][d0]);
            gld_lds16(&A[(size_t)(m0 + r1) * K + k0 + cs8], &As[cur ^ 1][d1]);
            gld_lds16(&Bt[(size_t)(n0 + r0) * K + k0 + cs8], &Bs[cur ^ 1][d0]);
            if constexpr (BN == 128)
                gld_lds16(&Bt[(size_t)(n0 + r1) * K + k0 + cs8], &Bs[cur ^ 1][d1]);
        }
        short8 a[4], b[NF];
#pragma unroll
        for (int m = 0; m < 4; m++)
            a[m] = *reinterpret_cast<const short8*>(
                &As[cur][(wr * 64 + m * 16 + fr) * 32 + kswz]);
#pragma unroll
        for (int n = 0; n < NF; n++)
            b[n] = *reinterpret_cast<const short8*>(
                &Bs[cur][(wc * (BN / 2) + n * 16 + fr) * 32 + kswz]);
#pragma unroll
        for (int m = 0; m < 4; m++)
#pragma unroll
            for (int n = 0; n < NF; n++)
                acc[m][n] = __builtin_amdgcn_mfma_f32_16x16x32_bf16(
                    a[m], b[n], acc[m][n], 0, 0, 0);
        __syncthreads();
        cur ^= 1;
    }

    const int g4 = (lane >> 4) * 4;
#pragma unroll
    for (int m = 0; m < 4; m++)
#pragma unroll
        for (int n = 0; n < NF; n++)
#pragma unroll
            for (int j = 0; j < 4; j++) {
                int mm = m0 + wr * 64 + m * 16 + g4 + j;
                int nn = n0 + wc * (BN / 2) + n * 16 + fr;
                float v = acc[m][n][j];
                if (EPI == 2) v = softplus_f(v + bias[nn]);
                if constexpr (sizeof(CT) == 2)
                    C[(size_t)mm * N + nn] = f2bf(v);
                else
                    C[(size_t)mm * N + nn] = v;
            }
}

// ---- proj split-K MFMA: pp[kc][M][96] partial of xb_bf @ WxT^T ----
__global__ __launch_bounds__(256) void proj_splitk(
    const unsigned short* __restrict__ Abf,
    const unsigned short* __restrict__ WxT,
    float* __restrict__ pp) {
    const int lane = threadIdx.x & 63;
    const int wid = threadIdx.x >> 6;
    const int mt = wid >> 1;
    const int nh = wid & 1;
    const int m0 = blockIdx.x * 32;
    const int kc = blockIdx.y;
    const int fr = lane & 15;
    const int kg = lane >> 4;

    const size_t abase = (size_t)(m0 + mt * 16 + fr) * DINNER + kc * KCH + kg * 8;

    f32x4 acc[3];
#pragma unroll
    for (int i = 0; i < 3; i++) acc[i] = (f32x4){0.f, 0.f, 0.f, 0.f};

    for (int step = 0; step < KCH / 32; step++) {
        short8 a = *reinterpret_cast<const short8*>(&Abf[abase + step * 32]);
#pragma unroll
        for (int nt = 0; nt < 3; nt++) {
            int nrow = nh * 48 + nt * 16 + fr;
            short8 b = *reinterpret_cast<const short8*>(
                &WxT[(size_t)nrow * DINNER + kc * KCH + step * 32 + kg * 8]);
            acc[nt] = __builtin_amdgcn_mfma_f32_16x16x32_bf16(a, b, acc[nt], 0, 0, 0);
        }
    }
    const int g4 = (lane >> 4) * 4;
#pragma unroll
    for (int nt = 0; nt < 3; nt++)
#pragma unroll
        for (int j = 0; j < 4; j++) {
            int m = m0 + mt * 16 + g4 + j;
            int n = nh * 48 + nt * 16 + fr;
            pp[((size_t)kc * (BSZ * LSEQ) + m) * NPROJ + n] = acc[nt][j];
        }
}

// reduce split-K partials; emit fp32 proj + bf16 dt_in (cols < DTRANK)
__global__ __launch_bounds__(256) void proj_reduce(
    const float* __restrict__ pp, float* __restrict__ proj,
    unsigned short* __restrict__ dtin) {
    int i = blockIdx.x * 256 + threadIdx.x;
    if (i >= BSZ * LSEQ * NPROJ) return;
    float s = 0.f;
#pragma unroll
    for (int kc = 0; kc < KS; kc++)
        s += pp[(size_t)kc * BSZ * LSEQ * NPROJ + i];
    proj[i] = s;
    int m = i / NPROJ;
    int n = i - m * NPROJ;
    if (n < DTRANK) dtin[(size_t)m * DTRANK + n] = f2bf(s);
}

// causal depthwise conv (k=4) + bias + silu; bf16 in/out, 8 d per thread
__global__ __launch_bounds__(256) void conv_silu_kernel(
    const unsigned short* __restrict__ xin, const float* __restrict__ w,
    const float* __restrict__ bconv, unsigned short* __restrict__ xout) {
    int i = blockIdx.x * 256 + threadIdx.x;
    const int d0 = (i & (DINNER / 8 - 1)) * 8;
    const int bt = i >> 8;
    const int t = bt & (LSEQ - 1);
    const size_t base = (size_t)bt * DINNER + d0;

    float acc[8];
#pragma unroll
    for (int q = 0; q < 8; q++) acc[q] = bconv[d0 + q];

#pragma unroll
    for (int k = 0; k < 4; k++) {
        int tt = t + k - 3;
        if (tt >= 0) {
            short8 xv = *reinterpret_cast<const short8*>(&xin[base + (size_t)(k - 3) * DINNER]);
#pragma unroll
            for (int q = 0; q < 8; q++)
                acc[q] = fmaf(bf2f((unsigned short)xv[q]), w[(d0 + q) * 4 + k], acc[q]);
        }
    }
    short8 o;
#pragma unroll
    for (int q = 0; q < 8; q++) o[q] = (short)f2bf(silu_f(acc[q]));
    *reinterpret_cast<short8*>(&xout[base]) = o;
}

// ---- chunked selective scan (bf16 operands, fp32 state) ----
__global__ __launch_bounds__(256) void scan_pass1(
    const unsigned short* __restrict__ xb, const unsigned short* __restrict__ dt,
    const float* __restrict__ proj, const float* __restrict__ A_log,
    float* __restrict__ aprod, float* __restrict__ hend) {
    __shared__ float Bs[LC][DSTATE];
    const int tg = blockIdx.x * 256 + threadIdx.x;
    const int d = tg & (DINNER - 1);
    const int bc = tg >> 11;
    const int c = bc & (NC - 1);
    const int b = bc >> 5;

    for (int idx = threadIdx.x; idx < LC * DSTATE; idx += 256) {
        int ti = idx >> 4, j = idx & 15;
        Bs[ti][j] = proj[(size_t)(b * LSEQ + c * LC + ti) * NPROJ + DTRANK + j];
    }
    __syncthreads();

    float Av[DSTATE], h[DSTATE], ap[DSTATE];
#pragma unroll
    for (int s = 0; s < DSTATE; s++) {
        Av[s] = -expf(A_log[d * DSTATE + s]);
        h[s] = 0.f;
        ap[s] = 1.f;
    }

    for (int i = 0; i < LC; i++) {
        size_t base = (size_t)(b * LSEQ + c * LC + i) * DINNER + d;
        float dtv = bf2f(dt[base]);
        float xv = bf2f(xb[base]);
        float dx = dtv * xv;
#pragma unroll
        for (int s = 0; s < DSTATE; s++) {
            float dA = __expf(dtv * Av[s]);
            ap[s] *= dA;
            h[s] = fmaf(dA, h[s], dx * Bs[i][s]);
        }
    }

    size_t o = ((size_t)bc * DINNER + d) * DSTATE;
#pragma unroll
    for (int q = 0; q < 4; q++) {
        *reinterpret_cast<float4*>(&aprod[o + q * 4]) =
            make_float4(ap[4 * q], ap[4 * q + 1], ap[4 * q + 2], ap[4 * q + 3]);
        *reinterpret_cast<float4*>(&hend[o + q * 4]) =
            make_float4(h[4 * q], h[4 * q + 1], h[4 * q + 2], h[4 * q + 3]);
    }
}

__global__ __launch_bounds__(256) void scan_pass2(
    float* __restrict__ aprod, const float* __restrict__ hend) {
    const int tg = blockIdx.x * 256 + threadIdx.x;
    const int s = tg & (DSTATE - 1);
    const int d = (tg >> 4) & (DINNER - 1);
    const int b = tg >> 15;
    float h = 0.f;
    for (int c = 0; c < NC; c++) {
        size_t o = ((size_t)((b * NC + c) * DINNER) + d) * DSTATE + s;
        float a = aprod[o];
        float e = hend[o];
        aprod[o] = h;
        h = fmaf(a, h, e);
    }
}

__global__ __launch_bounds__(256) void scan_pass3(
    const unsigned short* __restrict__ xb, const unsigned short* __restrict__ dt,
    const float* __restrict__ proj, const float* __restrict__ hstart,
    const float* __restrict__ A_log, const float* __restrict__ Dp,
    const unsigned short* __restrict__ sz, unsigned short* __restrict__ ybf) {
    __shared__ float Bs[LC][DSTATE];
    __shared__ float Cs[LC][DSTATE];
    const int tg = blockIdx.x * 256 + threadIdx.x;
    const int d = tg & (DINNER - 1);
    const int bc = tg >> 11;
    const int c = bc & (NC - 1);
    const int b = bc >> 5;

    for (int idx = threadIdx.x; idx < LC * 2 * DSTATE; idx += 256) {
        int ti = idx >> 5, j = idx & 31;
        float v = proj[(size_t)(b * LSEQ + c * LC + ti) * NPROJ + DTRANK + j];
        if (j < DSTATE) Bs[ti][j] = v;
        else            Cs[ti][j - DSTATE] = v;
    }
    __syncthreads();

    float Av[DSTATE], h[DSTATE];
    size_t o = ((size_t)bc * DINNER + d) * DSTATE;
#pragma unroll
    for (int q = 0; q < 4; q++) {
        float4 hv = *reinterpret_cast<const float4*>(&hstart[o + q * 4]);
        h[4 * q] = hv.x; h[4 * q + 1] = hv.y; h[4 * q + 2] = hv.z; h[4 * q + 3] = hv.w;
    }
#pragma unroll
    for (int s = 0; s < DSTATE; s++)
        Av[s] = -expf(A_log[d * DSTATE + s]);
    const float Dd = Dp[d];

    for (int i = 0; i < LC; i++) {
        size_t base = (size_t)(b * LSEQ + c * LC + i) * DINNER + d;
        float dtv = bf2f(dt[base]);
        float xv = bf2f(xb[base]);
        float szv = bf2f(sz[base]);
        float dx = dtv * xv;
        float p = 0.f;
#pragma unroll
        for (int s = 0; s < DSTATE; s++) {
            float dA = __expf(dtv * Av[s]);
            h[s] = fmaf(dA, h[s], dx * Bs[i][s]);
            p = fmaf(h[s], Cs[i][s], p);
        }
        ybf[base] = f2bf((p + Dd * xv) * szv);
    }
}

extern "C" void kernel_launch(void* const* d_in, const int* in_sizes, int n_in,
                              void* d_out, int out_size, void* d_ws,
                              size_t ws_size, hipStream_t stream) {
    const float* x = (const float*)d_in[0];
    const float* W_in = (const float*)d_in[1];
    const float* conv_w = (const float*)d_in[2];
    const float* conv_b = (const float*)d_in[3];
    const float* W_xproj = (const float*)d_in[4];
    const float* W_dt = (const float*)d_in[5];
    const float* b_dt = (const float*)d_in[6];
    const float* A_log = (const float*)d_in[7];
    const float* Dp = (const float*)d_in[8];
    const float* W_out = (const float*)d_in[9];
    float* out = (float*)d_out;

    char* ws = (char*)d_ws;
    const size_t MB = 1u << 20;
    float* pp    = (float*)(ws);
    float* aprod = (float*)(ws);
    float* hend  = (float*)(ws + 8 * MB);
    unsigned short* xbpre_bf = (unsigned short*)(ws + 16 * MB);  // 16 MB
    unsigned short* sz_bf    = (unsigned short*)(ws + 32 * MB);  // 16 MB
    unsigned short* xb_bf    = (unsigned short*)(ws + 48 * MB);  // 16 MB
    unsigned short* dt_bf    = (unsigned short*)(ws + 64 * MB);  // 16 MB
    unsigned short* ybf      = (unsigned short*)(ws + 80 * MB);  // 8 MB
    float* projbuf           = (float*)(ws + 88 * MB);           // 1.5 MB
    unsigned short* dtin_bf  = (unsigned short*)(ws + 90 * MB);  // 0.5 MB
    unsigned short* xbf      = (unsigned short*)(ws + 91 * MB);  // 8 MB
    unsigned short* WinT     = (unsigned short*)(ws + 99 * MB);  // 8 MB
    unsigned short* WoutT    = (unsigned short*)(ws + 107 * MB); // 4 MB
    unsigned short* WxT      = (unsigned short*)(ws + 111 * MB); // 384 KB
    unsigned short* WdtT     = (unsigned short*)(ws + 112 * MB); // 256 KB

    const int M = BSZ * LSEQ; // 4096
    dim3 blk(256);

    // prep
    f32_to_bf16_kernel<<<dim3((M * DMODEL / 4 + 255) / 256), blk, 0, stream>>>(
        x, xbf, M * DMODEL / 4);
    transpose_bf16_kernel<<<dim3(2 * DINNER / 32, DMODEL / 32), blk, 0, stream>>>(
        W_in, WinT, DMODEL, 2 * DINNER);
    transpose_bf16_kernel<<<dim3(DMODEL / 32, DINNER / 32), blk, 0, stream>>>(
        W_out, WoutT, DINNER, DMODEL);
    transpose_bf16_kernel<<<dim3(NPROJ / 32, DINNER / 32), blk, 0, stream>>>(
        W_xproj, WxT, DINNER, NPROJ);
    transpose_bf16_kernel<<<dim3(DINNER / 32, DTRANK / 32), blk, 0, stream>>>(
        W_dt, WdtT, DTRANK, DINNER);

    // 1. xz = x @ W_in — 256x256 8-wave phase-interleaved kernel (96 KB dyn LDS)
    gemm256<1, unsigned short><<<dim3((2 * DINNER) / 256, M / 256), dim3(512),
                                 98304, stream>>>(
        xbf, WinT, xbpre_bf, sz_bf, M, 2 * DINNER, DMODEL);

    // 2. conv + silu
    conv_silu_kernel<<<dim3((M * DINNER / 8) / 256), blk, 0, stream>>>(
        xbpre_bf, conv_w, conv_b, xb_bf);

    // 3. proj
    proj_splitk<<<dim3(M / 32, KS), blk, 0, stream>>>(xb_bf, WxT, pp);
    proj_reduce<<<dim3((M * NPROJ) / 256), blk, 0, stream>>>(pp, projbuf, dtin_bf);

    // 4. dt (2-phase, BN=128)
    gemm_mfma<2, 128, unsigned short><<<dim3(DINNER / 128, M / 128), blk, 0, stream>>>(
        dtin_bf, WdtT, dt_bf, nullptr, b_dt, M, DINNER, DTRANK);

    // 5. scan
    const int nthreads1 = BSZ * NC * DINNER;
    scan_pass1<<<dim3(nthreads1 / 256), blk, 0, stream>>>(
        xb_bf, dt_bf, projbuf, A_log, aprod, hend);
    const int nthreads2 = BSZ * DINNER * DSTATE;
    scan_pass2<<<dim3(nthreads2 / 256), blk, 0, stream>>>(aprod, hend);
    scan_pass3<<<dim3(nthreads1 / 256), blk, 0, stream>>>(
        xb_bf, dt_bf, projbuf, aprod, A_log, Dp, sz_bf, ybf);

    // 6. out (2-phase, BN=128)
    gemm_mfma<0, 128, float><<<dim3(DMODEL / 128, M / 128), blk, 0, stream>>>(
        ybf, WoutT, out, nullptr, nullptr, M, DMODEL, DINNER);
}

// Round 10
// 274.553 us; speedup vs baseline: 1.1976x; 1.1830x over previous
//
#include <hip/hip_runtime.h>
#include <hip/hip_bf16.h>
#include <math.h>

#define BSZ 2
#define LSEQ 2048
#define DMODEL 1024
#define DSTATE 16
#define DCONV 4
#define DINNER 2048
#define DTRANK 64
#define NPROJ (DTRANK + 2 * DSTATE) // 96
#define NC 32   // scan chunks
#define LC 64   // steps per chunk
#define KS 4    // proj split-K chunks
#define KCH (DINNER / KS) // 512
#define TT 8    // conv timesteps per thread

using short8 = __attribute__((ext_vector_type(8))) short;
using f32x4 = __attribute__((ext_vector_type(4))) float;
using u16x4 = __attribute__((ext_vector_type(4))) unsigned short;

__device__ __forceinline__ float silu_f(float v) {
    return v / (1.f + expf(-v));
}
__device__ __forceinline__ float softplus_f(float v) {
    return fmaxf(v, 0.f) + log1pf(expf(-fabsf(v)));
}
// fp32 -> bf16 bits, round-to-nearest-even
__device__ __forceinline__ unsigned short f2bf(float f) {
    unsigned u = __builtin_bit_cast(unsigned, f);
    u += 0x7fffu + ((u >> 16) & 1u);
    return (unsigned short)(u >> 16);
}
__device__ __forceinline__ float bf2f(unsigned short u) {
    unsigned x = ((unsigned)u) << 16;
    return __builtin_bit_cast(float, x);
}

__device__ __forceinline__ void gld_lds16(const unsigned short* g, unsigned short* l) {
    __builtin_amdgcn_global_load_lds(
        (const __attribute__((address_space(1))) unsigned int*)g,
        (__attribute__((address_space(3))) unsigned int*)l, 16, 0, 0);
}

// ---- prep: fp32 -> bf16 (same layout), n4 = n/4 ----
__global__ __launch_bounds__(256) void f32_to_bf16_kernel(
    const float* __restrict__ in, unsigned short* __restrict__ out, int n4) {
    int i = blockIdx.x * 256 + threadIdx.x;
    if (i >= n4) return;
    float4 v = reinterpret_cast<const float4*>(in)[i];
    u16x4 o = {f2bf(v.x), f2bf(v.y), f2bf(v.z), f2bf(v.w)};
    reinterpret_cast<u16x4*>(out)[i] = o;
}

// ---- prep: transpose fp32 [R][Cc] -> bf16 [Cc][R] ----
__global__ __launch_bounds__(256) void transpose_bf16_kernel(
    const float* __restrict__ in, unsigned short* __restrict__ out, int R, int Cc) {
    __shared__ float t[32][33];
    const int tx = threadIdx.x & 31, ty = threadIdx.x >> 5; // 32 x 8
    const int c0 = blockIdx.x * 32, r0 = blockIdx.y * 32;
    for (int i = ty; i < 32; i += 8)
        t[i][tx] = in[(size_t)(r0 + i) * Cc + c0 + tx];
    __syncthreads();
    for (int i = ty; i < 32; i += 8)
        out[(size_t)(c0 + i) * R + r0 + tx] = f2bf(t[tx][i]);
}

// ===== 256x256 8-wave phase-interleaved MFMA GEMM (xz) =====
// (r9-proven; see comments there)
template <int EPI, typename CT>
__global__ __launch_bounds__(512) void gemm256(
    const unsigned short* __restrict__ A, const unsigned short* __restrict__ Bt,
    CT* __restrict__ C, CT* __restrict__ C2, int M, int N, int K) {
    extern __shared__ __align__(16) unsigned short lds[];
    unsigned short* As = lds;            // [3][8192]
    unsigned short* Bs = lds + 3 * 8192; // [3][8192]
    const int tid = threadIdx.x;
    const int lane = tid & 63;
    const int w = tid >> 6;
    const int wm = w >> 2, wn = w & 3;
    const int m0 = blockIdx.y * 256, n0 = blockIdx.x * 256;
    const int fr = lane & 15, kg = lane >> 4;
    const int kswz = ((kg ^ ((fr >> 1) & 3)) << 3);
    const int srow = tid >> 2;
    const int cs8 = (((tid & 3) ^ ((tid >> 3) & 3)) << 3);
    const int dst = tid * 8;
    const int nt = K / 32;

    f32x4 acc[8][4];
#pragma unroll
    for (int m = 0; m < 8; m++)
#pragma unroll
        for (int n = 0; n < 4; n++) acc[m][n] = (f32x4){0.f, 0.f, 0.f, 0.f};

#define STAGE_A(t)                                                               \
    {                                                                            \
        const int _b = (t) % 3, _k = (t) * 32;                                   \
        gld_lds16(&A[(size_t)(m0 + srow) * K + _k + cs8], &As[_b * 8192 + dst]); \
        gld_lds16(&A[(size_t)(m0 + 128 + srow) * K + _k + cs8],                  \
                  &As[_b * 8192 + dst + 4096]);                                  \
    }
#define STAGE_B(t)                                                               \
    {                                                                            \
        const int _b = (t) % 3, _k = (t) * 32;                                   \
        gld_lds16(&Bt[(size_t)(n0 + srow) * K + _k + cs8], &Bs[_b * 8192 + dst]);\
        gld_lds16(&Bt[(size_t)(n0 + 128 + srow) * K + _k + cs8],                 \
                  &Bs[_b * 8192 + dst + 4096]);                                  \
    }

    STAGE_A(0); STAGE_B(0); STAGE_A(1); STAGE_B(1);
    asm volatile("s_waitcnt vmcnt(4)" ::: "memory");
    __builtin_amdgcn_s_barrier();

    short8 bfr[4];
    for (int t = 0; t < nt; t++) {
        const int buf = t % 3;
        // phase 0: m-frags 0..3
        short8 afr[4];
#pragma unroll
        for (int q = 0; q < 4; q++)
            afr[q] = *reinterpret_cast<const short8*>(
                &As[buf * 8192 + (wm * 128 + q * 16 + fr) * 32 + kswz]);
#pragma unroll
        for (int q = 0; q < 4; q++)
            bfr[q] = *reinterpret_cast<const short8*>(
                &Bs[buf * 8192 + (wn * 64 + q * 16 + fr) * 32 + kswz]);
        if (t + 2 < nt) STAGE_A(t + 2);
        __builtin_amdgcn_s_barrier();
        asm volatile("s_waitcnt lgkmcnt(0)" ::: "memory");
        __builtin_amdgcn_sched_barrier(0);
        __builtin_amdgcn_s_setprio(1);
#pragma unroll
        for (int m = 0; m < 4; m++)
#pragma unroll
            for (int n = 0; n < 4; n++)
                acc[m][n] = __builtin_amdgcn_mfma_f32_16x16x32_bf16(
                    afr[m], bfr[n], acc[m][n], 0, 0, 0);
        __builtin_amdgcn_s_setprio(0);
        __builtin_amdgcn_s_barrier();
        // phase 1: m-frags 4..7 (reuse bfr)
#pragma unroll
        for (int q = 0; q < 4; q++)
            afr[q] = *reinterpret_cast<const short8*>(
                &As[buf * 8192 + (wm * 128 + 64 + q * 16 + fr) * 32 + kswz]);
        if (t + 2 < nt) STAGE_B(t + 2);
        if (t + 1 < nt) {
            if (t + 2 < nt)
                asm volatile("s_waitcnt vmcnt(4)" ::: "memory");
            else
                asm volatile("s_waitcnt vmcnt(0)" ::: "memory");
        }
        __builtin_amdgcn_s_barrier();
        asm volatile("s_waitcnt lgkmcnt(0)" ::: "memory");
        __builtin_amdgcn_sched_barrier(0);
        __builtin_amdgcn_s_setprio(1);
#pragma unroll
        for (int m = 0; m < 4; m++)
#pragma unroll
            for (int n = 0; n < 4; n++)
                acc[4 + m][n] = __builtin_amdgcn_mfma_f32_16x16x32_bf16(
                    afr[m], bfr[n], acc[4 + m][n], 0, 0, 0);
        __builtin_amdgcn_s_setprio(0);
        __builtin_amdgcn_s_barrier();
    }
#undef STAGE_A
#undef STAGE_B

    const int g4 = kg * 4;
#pragma unroll
    for (int m = 0; m < 8; m++)
#pragma unroll
        for (int n = 0; n < 4; n++)
#pragma unroll
            for (int j = 0; j < 4; j++) {
                int mm = m0 + wm * 128 + m * 16 + g4 + j;
                int nn = n0 + wn * 64 + n * 16 + fr;
                float v = acc[m][n][j];
                if (EPI == 1) {
                    if (nn < DINNER)
                        C[(size_t)mm * DINNER + nn] = f2bf(v);
                    else
                        C2[(size_t)mm * DINNER + (nn - DINNER)] = f2bf(silu_f(v));
                } else {
                    if constexpr (sizeof(CT) == 2)
                        C[(size_t)mm * N + nn] = f2bf(v);
                    else
                        C[(size_t)mm * N + nn] = v;
                }
            }
}

// ---- 128xBN 2-phase MFMA GEMM (dt, out) ----
template <int EPI, int BN, typename CT>
__global__ __launch_bounds__(256) void gemm_mfma(
    const unsigned short* __restrict__ A, const unsigned short* __restrict__ Bt,
    CT* __restrict__ C, CT* __restrict__ C2, const float* __restrict__ bias,
    int M, int N, int K) {
    constexpr int NF = BN / 32;
    __shared__ __align__(16) unsigned short As[2][4096];
    __shared__ __align__(16) unsigned short Bs[2][BN * 32];
    const int tid = threadIdx.x;
    const int lane = tid & 63;
    const int wid = tid >> 6;
    const int wr = wid >> 1, wc = wid & 1;
    const int m0 = blockIdx.y * 128, n0 = blockIdx.x * BN;

    const int r0 = tid >> 2;
    const int r1 = r0 + 64;
    const int d0 = tid * 8;
    const int d1 = d0 + 2048;
    const int cs8 = (((tid & 3) ^ ((tid >> 3) & 3)) << 3);

    f32x4 acc[4][NF];
#pragma unroll
    for (int m = 0; m < 4; m++)
#pragma unroll
        for (int n = 0; n < NF; n++) acc[m][n] = (f32x4){0.f, 0.f, 0.f, 0.f};

    const int fr = lane & 15;
    const int kg = lane >> 4;
    const int kswz = ((kg ^ ((fr >> 1) & 3)) << 3);
    const int nt = K / 32;

    gld_lds16(&A[(size_t)(m0 + r0) * K + cs8], &As[0][d0]);
    gld_lds16(&A[(size_t)(m0 + r1) * K + cs8], &As[0][d1]);
    gld_lds16(&Bt[(size_t)(n0 + r0) * K + cs8], &Bs[0][d0]);
    if constexpr (BN == 128)
        gld_lds16(&Bt[(size_t)(n0 + r1) * K + cs8], &Bs[0][d1]);
    __syncthreads();

    int cur = 0;
    for (int t = 0; t < nt; t++) {
        if (t + 1 < nt) {
            const int k0 = (t + 1) * 32;
            gld_lds16(&A[(size_t)(m0 + r0) * K + k0 + cs8], &As[cur ^ 1][d0]);
            gld_lds16(&A[(size_t)(m0 + r1) * K + k0 + cs8], &As[cur ^ 1][d1]);
            gld_lds16(&Bt[(size_t)(n0 + r0) * K + k0 + cs8], &Bs[cur ^ 1][d0]);
            if constexpr (BN == 128)
                gld_lds16(&Bt[(size_t)(n0 + r1) * K + k0 + cs8], &Bs[cur ^ 1][d1]);
        }
        short8 a[4], b[NF];
#pragma unroll
        for (int m = 0; m < 4; m++)
            a[m] = *reinterpret_cast<const short8*>(
                &As[cur][(wr * 64 + m * 16 + fr) * 32 + kswz]);
#pragma unroll
        for (int n = 0; n < NF; n++)
            b[n] = *reinterpret_cast<const short8*>(
                &Bs[cur][(wc * (BN / 2) + n * 16 + fr) * 32 + kswz]);
#pragma unroll
        for (int m = 0; m < 4; m++)
#pragma unroll
            for (int n = 0; n < NF; n++)
                acc[m][n] = __builtin_amdgcn_mfma_f32_16x16x32_bf16(
                    a[m], b[n], acc[m][n], 0, 0, 0);
        __syncthreads();
        cur ^= 1;
    }

    const int g4 = (lane >> 4) * 4;
#pragma unroll
    for (int m = 0; m < 4; m++)
#pragma unroll
        for (int n = 0; n < NF; n++)
#pragma unroll
            for (int j = 0; j < 4; j++) {
                int mm = m0 + wr * 64 + m * 16 + g4 + j;
                int nn = n0 + wc * (BN / 2) + n * 16 + fr;
                float v = acc[m][n][j];
                if (EPI == 2) v = softplus_f(v + bias[nn]);
                if constexpr (sizeof(CT) == 2)
                    C[(size_t)mm * N + nn] = f2bf(v);
                else
                    C[(size_t)mm * N + nn] = v;
            }
}

// ---- proj split-K MFMA: pp[kc][M][96] partial of xb_bf @ WxT^T ----
__global__ __launch_bounds__(256) void proj_splitk(
    const unsigned short* __restrict__ Abf,
    const unsigned short* __restrict__ WxT,
    float* __restrict__ pp) {
    const int lane = threadIdx.x & 63;
    const int wid = threadIdx.x >> 6;
    const int mt = wid >> 1;
    const int nh = wid & 1;
    const int m0 = blockIdx.x * 32;
    const int kc = blockIdx.y;
    const int fr = lane & 15;
    const int kg = lane >> 4;

    const size_t abase = (size_t)(m0 + mt * 16 + fr) * DINNER + kc * KCH + kg * 8;

    f32x4 acc[3];
#pragma unroll
    for (int i = 0; i < 3; i++) acc[i] = (f32x4){0.f, 0.f, 0.f, 0.f};

    for (int step = 0; step < KCH / 32; step++) {
        short8 a = *reinterpret_cast<const short8*>(&Abf[abase + step * 32]);
#pragma unroll
        for (int nt = 0; nt < 3; nt++) {
            int nrow = nh * 48 + nt * 16 + fr;
            short8 b = *reinterpret_cast<const short8*>(
                &WxT[(size_t)nrow * DINNER + kc * KCH + step * 32 + kg * 8]);
            acc[nt] = __builtin_amdgcn_mfma_f32_16x16x32_bf16(a, b, acc[nt], 0, 0, 0);
        }
    }
    const int g4 = (lane >> 4) * 4;
#pragma unroll
    for (int nt = 0; nt < 3; nt++)
#pragma unroll
        for (int j = 0; j < 4; j++) {
            int m = m0 + mt * 16 + g4 + j;
            int n = nh * 48 + nt * 16 + fr;
            pp[((size_t)kc * (BSZ * LSEQ) + m) * NPROJ + n] = acc[nt][j];
        }
}

// reduce split-K partials; emit fp32 proj + bf16 dt_in (cols < DTRANK)
__global__ __launch_bounds__(256) void proj_reduce(
    const float* __restrict__ pp, float* __restrict__ proj,
    unsigned short* __restrict__ dtin) {
    int i = blockIdx.x * 256 + threadIdx.x;
    if (i >= BSZ * LSEQ * NPROJ) return;
    float s = 0.f;
#pragma unroll
    for (int kc = 0; kc < KS; kc++)
        s += pp[(size_t)kc * BSZ * LSEQ * NPROJ + i];
    proj[i] = s;
    int m = i / NPROJ;
    int n = i - m * NPROJ;
    if (n < DTRANK) dtin[(size_t)m * DTRANK + n] = f2bf(s);
}

// ---- causal depthwise conv (k=4) + bias + silu — sliding window ----
// thread = 8 consecutive d; loops TT timesteps; weights loaded once,
// each x row loaded once (window kept in registers). grid = BSZ*LSEQ/TT.
__global__ __launch_bounds__(256) void conv_silu_kernel(
    const unsigned short* __restrict__ xin, const float* __restrict__ w,
    const float* __restrict__ bconv, unsigned short* __restrict__ xout) {
    const int tid = threadIdx.x;
    const int d0 = tid * 8;
    const int bt0 = blockIdx.x * TT;
    const int tloc = bt0 & (LSEQ - 1);

    float wk0[8], wk1[8], wk2[8], wk3[8], bb[8];
#pragma unroll
    for (int q = 0; q < 8; q++) {
        float4 wv = *reinterpret_cast<const float4*>(&w[(d0 + q) * 4]);
        wk0[q] = wv.x; wk1[q] = wv.y; wk2[q] = wv.z; wk3[q] = wv.w;
    }
    {
        float4 b0 = *reinterpret_cast<const float4*>(&bconv[d0]);
        float4 b1 = *reinterpret_cast<const float4*>(&bconv[d0 + 4]);
        bb[0] = b0.x; bb[1] = b0.y; bb[2] = b0.z; bb[3] = b0.w;
        bb[4] = b1.x; bb[5] = b1.y; bb[6] = b1.z; bb[7] = b1.w;
    }

    float xm3[8], xm2[8], xm1[8];
    if (tloc >= 3) {
        short8 v3 = *reinterpret_cast<const short8*>(&xin[(size_t)(bt0 - 3) * DINNER + d0]);
        short8 v2 = *reinterpret_cast<const short8*>(&xin[(size_t)(bt0 - 2) * DINNER + d0]);
        short8 v1 = *reinterpret_cast<const short8*>(&xin[(size_t)(bt0 - 1) * DINNER + d0]);
#pragma unroll
        for (int q = 0; q < 8; q++) {
            xm3[q] = bf2f((unsigned short)v3[q]);
            xm2[q] = bf2f((unsigned short)v2[q]);
            xm1[q] = bf2f((unsigned short)v1[q]);
        }
    } else { // batch start (tloc == 0 since TT | LSEQ)
#pragma unroll
        for (int q = 0; q < 8; q++) { xm3[q] = 0.f; xm2[q] = 0.f; xm1[q] = 0.f; }
    }

#pragma unroll
    for (int i = 0; i < TT; i++) {
        short8 vc = *reinterpret_cast<const short8*>(&xin[(size_t)(bt0 + i) * DINNER + d0]);
        float xc[8];
        short8 o;
#pragma unroll
        for (int q = 0; q < 8; q++) {
            xc[q] = bf2f((unsigned short)vc[q]);
            float a = bb[q];
            a = fmaf(wk0[q], xm3[q], a);
            a = fmaf(wk1[q], xm2[q], a);
            a = fmaf(wk2[q], xm1[q], a);
            a = fmaf(wk3[q], xc[q], a);
            o[q] = (short)f2bf(silu_f(a));
        }
        *reinterpret_cast<short8*>(&xout[(size_t)(bt0 + i) * DINNER + d0]) = o;
#pragma unroll
        for (int q = 0; q < 8; q++) { xm3[q] = xm2[q]; xm2[q] = xm1[q]; xm1[q] = xc[q]; }
    }
}

// ---- chunked selective scan (bf16 operands, fp32 state) ----
__global__ __launch_bounds__(256) void scan_pass1(
    const unsigned short* __restrict__ xb, const unsigned short* __restrict__ dt,
    const float* __restrict__ proj, const float* __restrict__ A_log,
    float* __restrict__ aprod, float* __restrict__ hend) {
    __shared__ float Bs[LC][DSTATE];
    const int tg = blockIdx.x * 256 + threadIdx.x;
    const int d = tg & (DINNER - 1);
    const int bc = tg >> 11;
    const int c = bc & (NC - 1);
    const int b = bc >> 5;

    for (int idx = threadIdx.x; idx < LC * DSTATE; idx += 256) {
        int ti = idx >> 4, j = idx & 15;
        Bs[ti][j] = proj[(size_t)(b * LSEQ + c * LC + ti) * NPROJ + DTRANK + j];
    }
    __syncthreads();

    float Av[DSTATE], h[DSTATE], ap[DSTATE];
#pragma unroll
    for (int s = 0; s < DSTATE; s++) {
        Av[s] = -expf(A_log[d * DSTATE + s]);
        h[s] = 0.f;
        ap[s] = 1.f;
    }

    for (int i = 0; i < LC; i++) {
        size_t base = (size_t)(b * LSEQ + c * LC + i) * DINNER + d;
        float dtv = bf2f(dt[base]);
        float xv = bf2f(xb[base]);
        float dx = dtv * xv;
#pragma unroll
        for (int s = 0; s < DSTATE; s++) {
            float dA = __expf(dtv * Av[s]);
            ap[s] *= dA;
            h[s] = fmaf(dA, h[s], dx * Bs[i][s]);
        }
    }

    size_t o = ((size_t)bc * DINNER + d) * DSTATE;
#pragma unroll
    for (int q = 0; q < 4; q++) {
        *reinterpret_cast<float4*>(&aprod[o + q * 4]) =
            make_float4(ap[4 * q], ap[4 * q + 1], ap[4 * q + 2], ap[4 * q + 3]);
        *reinterpret_cast<float4*>(&hend[o + q * 4]) =
            make_float4(h[4 * q], h[4 * q + 1], h[4 * q + 2], h[4 * q + 3]);
    }
}

__global__ __launch_bounds__(256) void scan_pass2(
    float* __restrict__ aprod, const float* __restrict__ hend) {
    const int tg = blockIdx.x * 256 + threadIdx.x;
    const int s = tg & (DSTATE - 1);
    const int d = (tg >> 4) & (DINNER - 1);
    const int b = tg >> 15;
    float h = 0.f;
    for (int c = 0; c < NC; c++) {
        size_t o = ((size_t)((b * NC + c) * DINNER) + d) * DSTATE + s;
        float a = aprod[o];
        float e = hend[o];
        aprod[o] = h;
        h = fmaf(a, h, e);
    }
}

__global__ __launch_bounds__(256) void scan_pass3(
    const unsigned short* __restrict__ xb, const unsigned short* __restrict__ dt,
    const float* __restrict__ proj, const float* __restrict__ hstart,
    const float* __restrict__ A_log, const float* __restrict__ Dp,
    const unsigned short* __restrict__ sz, unsigned short* __restrict__ ybf) {
    __shared__ float Bs[LC][DSTATE];
    __shared__ float Cs[LC][DSTATE];
    const int tg = blockIdx.x * 256 + threadIdx.x;
    const int d = tg & (DINNER - 1);
    const int bc = tg >> 11;
    const int c = bc & (NC - 1);
    const int b = bc >> 5;

    for (int idx = threadIdx.x; idx < LC * 2 * DSTATE; idx += 256) {
        int ti = idx >> 5, j = idx & 31;
        float v = proj[(size_t)(b * LSEQ + c * LC + ti) * NPROJ + DTRANK + j];
        if (j < DSTATE) Bs[ti][j] = v;
        else            Cs[ti][j - DSTATE] = v;
    }
    __syncthreads();

    float Av[DSTATE], h[DSTATE];
    size_t o = ((size_t)bc * DINNER + d) * DSTATE;
#pragma unroll
    for (int q = 0; q < 4; q++) {
        float4 hv = *reinterpret_cast<const float4*>(&hstart[o + q * 4]);
        h[4 * q] = hv.x; h[4 * q + 1] = hv.y; h[4 * q + 2] = hv.z; h[4 * q + 3] = hv.w;
    }
#pragma unroll
    for (int s = 0; s < DSTATE; s++)
        Av[s] = -expf(A_log[d * DSTATE + s]);
    const float Dd = Dp[d];

    for (int i = 0; i < LC; i++) {
        size_t base = (size_t)(b * LSEQ + c * LC + i) * DINNER + d;
        float dtv = bf2f(dt[base]);
        float xv = bf2f(xb[base]);
        float szv = bf2f(sz[base]);
        float dx = dtv * xv;
        float p = 0.f;
#pragma unroll
        for (int s = 0; s < DSTATE; s++) {
            float dA = __expf(dtv * Av[s]);
            h[s] = fmaf(dA, h[s], dx * Bs[i][s]);
            p = fmaf(h[s], Cs[i][s], p);
        }
        ybf[base] = f2bf((p + Dd * xv) * szv);
    }
}

extern "C" void kernel_launch(void* const* d_in, const int* in_sizes, int n_in,
                              void* d_out, int out_size, void* d_ws,
                              size_t ws_size, hipStream_t stream) {
    const float* x = (const float*)d_in[0];
    const float* W_in = (const float*)d_in[1];
    const float* conv_w = (const float*)d_in[2];
    const float* conv_b = (const float*)d_in[3];
    const float* W_xproj = (const float*)d_in[4];
    const float* W_dt = (const float*)d_in[5];
    const float* b_dt = (const float*)d_in[6];
    const float* A_log = (const float*)d_in[7];
    const float* Dp = (const float*)d_in[8];
    const float* W_out = (const float*)d_in[9];
    float* out = (float*)d_out;

    char* ws = (char*)d_ws;
    const size_t MB = 1u << 20;
    float* pp    = (float*)(ws);
    float* aprod = (float*)(ws);
    float* hend  = (float*)(ws + 8 * MB);
    unsigned short* xbpre_bf = (unsigned short*)(ws + 16 * MB);  // 16 MB
    unsigned short* sz_bf    = (unsigned short*)(ws + 32 * MB);  // 16 MB
    unsigned short* xb_bf    = (unsigned short*)(ws + 48 * MB);  // 16 MB
    unsigned short* dt_bf    = (unsigned short*)(ws + 64 * MB);  // 16 MB
    unsigned short* ybf      = (unsigned short*)(ws + 80 * MB);  // 8 MB
    float* projbuf           = (float*)(ws + 88 * MB);           // 1.5 MB
    unsigned short* dtin_bf  = (unsigned short*)(ws + 90 * MB);  // 0.5 MB
    unsigned short* xbf      = (unsigned short*)(ws + 91 * MB);  // 8 MB
    unsigned short* WinT     = (unsigned short*)(ws + 99 * MB);  // 8 MB
    unsigned short* WoutT    = (unsigned short*)(ws + 107 * MB); // 4 MB
    unsigned short* WxT      = (unsigned short*)(ws + 111 * MB); // 384 KB
    unsigned short* WdtT     = (unsigned short*)(ws + 112 * MB); // 256 KB

    const int M = BSZ * LSEQ; // 4096
    dim3 blk(256);

    // prep
    f32_to_bf16_kernel<<<dim3((M * DMODEL / 4 + 255) / 256), blk, 0, stream>>>(
        x, xbf, M * DMODEL / 4);
    transpose_bf16_kernel<<<dim3(2 * DINNER / 32, DMODEL / 32), blk, 0, stream>>>(
        W_in, WinT, DMODEL, 2 * DINNER);
    transpose_bf16_kernel<<<dim3(DMODEL / 32, DINNER / 32), blk, 0, stream>>>(
        W_out, WoutT, DINNER, DMODEL);
    transpose_bf16_kernel<<<dim3(NPROJ / 32, DINNER / 32), blk, 0, stream>>>(
        W_xproj, WxT, DINNER, NPROJ);
    transpose_bf16_kernel<<<dim3(DINNER / 32, DTRANK / 32), blk, 0, stream>>>(
        W_dt, WdtT, DTRANK, DINNER);

    // 1. xz = x @ W_in — 256x256 8-wave phase-interleaved (96 KB dyn LDS)
    gemm256<1, unsigned short><<<dim3((2 * DINNER) / 256, M / 256), dim3(512),
                                 98304, stream>>>(
        xbf, WinT, xbpre_bf, sz_bf, M, 2 * DINNER, DMODEL);

    // 2. conv + silu (sliding window, TT=8)
    conv_silu_kernel<<<dim3(M / TT), blk, 0, stream>>>(
        xbpre_bf, conv_w, conv_b, xb_bf);

    // 3. proj (split-K = 4)
    proj_splitk<<<dim3(M / 32, KS), blk, 0, stream>>>(xb_bf, WxT, pp);
    proj_reduce<<<dim3((M * NPROJ) / 256), blk, 0, stream>>>(pp, projbuf, dtin_bf);

    // 4. dt (2-phase, BN=128)
    gemm_mfma<2, 128, unsigned short><<<dim3(DINNER / 128, M / 128), blk, 0, stream>>>(
        dtin_bf, WdtT, dt_bf, nullptr, b_dt, M, DINNER, DTRANK);

    // 5. scan
    const int nthreads1 = BSZ * NC * DINNER;
    scan_pass1<<<dim3(nthreads1 / 256), blk, 0, stream>>>(
        xb_bf, dt_bf, projbuf, A_log, aprod, hend);
    const int nthreads2 = BSZ * DINNER * DSTATE;
    scan_pass2<<<dim3(nthreads2 / 256), blk, 0, stream>>>(aprod, hend);
    scan_pass3<<<dim3(nthreads1 / 256), blk, 0, stream>>>(
        xb_bf, dt_bf, projbuf, aprod, A_log, Dp, sz_bf, ybf);

    // 6. out (2-phase, BN=128)
    gemm_mfma<0, 128, float><<<dim3(DMODEL / 128, M / 128), blk, 0, stream>>>(
        ybf, WoutT, out, nullptr, nullptr, M, DMODEL, DINNER);
}

// Round 11
// 270.111 us; speedup vs baseline: 1.2173x; 1.0164x over previous
//
#include <hip/hip_runtime.h>
#include <hip/hip_bf16.h>
#include <math.h>

#define BSZ 2
#define LSEQ 2048
#define DMODEL 1024
#define DSTATE 16
#define DCONV 4
#define DINNER 2048
#define DTRANK 64
#define NPROJ (DTRANK + 2 * DSTATE) // 96
#define NC 32   // scan chunks
#define LC 64   // steps per chunk
#define KS 4    // proj split-K chunks
#define KCH (DINNER / KS) // 512
#define TT 8    // conv timesteps per thread

using short8 = __attribute__((ext_vector_type(8))) short;
using f32x4 = __attribute__((ext_vector_type(4))) float;
using u16x4 = __attribute__((ext_vector_type(4))) unsigned short;

__device__ __forceinline__ float silu_f(float v) {
    return v / (1.f + expf(-v));
}
__device__ __forceinline__ float softplus_f(float v) {
    return fmaxf(v, 0.f) + log1pf(expf(-fabsf(v)));
}
// fp32 -> bf16 bits, round-to-nearest-even
__device__ __forceinline__ unsigned short f2bf(float f) {
    unsigned u = __builtin_bit_cast(unsigned, f);
    u += 0x7fffu + ((u >> 16) & 1u);
    return (unsigned short)(u >> 16);
}
__device__ __forceinline__ float bf2f(unsigned short u) {
    unsigned x = ((unsigned)u) << 16;
    return __builtin_bit_cast(float, x);
}

__device__ __forceinline__ void gld_lds16(const unsigned short* g, unsigned short* l) {
    __builtin_amdgcn_global_load_lds(
        (const __attribute__((address_space(1))) unsigned int*)g,
        (__attribute__((address_space(3))) unsigned int*)l, 16, 0, 0);
}

// bijective XCD swizzle (requires nwg % 8 == 0)
__device__ __forceinline__ int xcd_swz(int wg, int nwg) {
    return (wg & 7) * (nwg >> 3) + (wg >> 3);
}

// ---- prep: fp32 -> bf16 (same layout), n4 = n/4 ----
__global__ __launch_bounds__(256) void f32_to_bf16_kernel(
    const float* __restrict__ in, unsigned short* __restrict__ out, int n4) {
    int i = blockIdx.x * 256 + threadIdx.x;
    if (i >= n4) return;
    float4 v = reinterpret_cast<const float4*>(in)[i];
    u16x4 o = {f2bf(v.x), f2bf(v.y), f2bf(v.z), f2bf(v.w)};
    reinterpret_cast<u16x4*>(out)[i] = o;
}

// ---- prep: transpose fp32 [R][Cc] -> bf16 [Cc][R] ----
__global__ __launch_bounds__(256) void transpose_bf16_kernel(
    const float* __restrict__ in, unsigned short* __restrict__ out, int R, int Cc) {
    __shared__ float t[32][33];
    const int tx = threadIdx.x & 31, ty = threadIdx.x >> 5; // 32 x 8
    const int c0 = blockIdx.x * 32, r0 = blockIdx.y * 32;
    for (int i = ty; i < 32; i += 8)
        t[i][tx] = in[(size_t)(r0 + i) * Cc + c0 + tx];
    __syncthreads();
    for (int i = ty; i < 32; i += 8)
        out[(size_t)(c0 + i) * R + r0 + tx] = f2bf(t[tx][i]);
}

// ===== 256x256 8-wave phase-interleaved MFMA GEMM (xz) — r9-proven =====
template <int EPI, typename CT>
__global__ __launch_bounds__(512) void gemm256(
    const unsigned short* __restrict__ A, const unsigned short* __restrict__ Bt,
    CT* __restrict__ C, CT* __restrict__ C2, int M, int N, int K) {
    extern __shared__ __align__(16) unsigned short lds[];
    unsigned short* As = lds;            // [3][8192]
    unsigned short* Bs = lds + 3 * 8192; // [3][8192]
    const int tid = threadIdx.x;
    const int lane = tid & 63;
    const int w = tid >> 6;
    const int wm = w >> 2, wn = w & 3;
    // XCD-aware block swizzle (nwg = gridDim.x*gridDim.y, multiple of 8)
    const int nwg = gridDim.x * gridDim.y;
    const int wg = xcd_swz(blockIdx.y * gridDim.x + blockIdx.x, nwg);
    const int m0 = (wg / gridDim.x) * 256, n0 = (wg % gridDim.x) * 256;
    const int fr = lane & 15, kg = lane >> 4;
    const int kswz = ((kg ^ ((fr >> 1) & 3)) << 3);
    const int srow = tid >> 2;
    const int cs8 = (((tid & 3) ^ ((tid >> 3) & 3)) << 3);
    const int dst = tid * 8;
    const int nt = K / 32;

    f32x4 acc[8][4];
#pragma unroll
    for (int m = 0; m < 8; m++)
#pragma unroll
        for (int n = 0; n < 4; n++) acc[m][n] = (f32x4){0.f, 0.f, 0.f, 0.f};

#define STAGE_A(t)                                                               \
    {                                                                            \
        const int _b = (t) % 3, _k = (t) * 32;                                   \
        gld_lds16(&A[(size_t)(m0 + srow) * K + _k + cs8], &As[_b * 8192 + dst]); \
        gld_lds16(&A[(size_t)(m0 + 128 + srow) * K + _k + cs8],                  \
                  &As[_b * 8192 + dst + 4096]);                                  \
    }
#define STAGE_B(t)                                                               \
    {                                                                            \
        const int _b = (t) % 3, _k = (t) * 32;                                   \
        gld_lds16(&Bt[(size_t)(n0 + srow) * K + _k + cs8], &Bs[_b * 8192 + dst]);\
        gld_lds16(&Bt[(size_t)(n0 + 128 + srow) * K + _k + cs8],                 \
                  &Bs[_b * 8192 + dst + 4096]);                                  \
    }

    STAGE_A(0); STAGE_B(0); STAGE_A(1); STAGE_B(1);
    asm volatile("s_waitcnt vmcnt(4)" ::: "memory");
    __builtin_amdgcn_s_barrier();

    short8 bfr[4];
    for (int t = 0; t < nt; t++) {
        const int buf = t % 3;
        // phase 0: m-frags 0..3
        short8 afr[4];
#pragma unroll
        for (int q = 0; q < 4; q++)
            afr[q] = *reinterpret_cast<const short8*>(
                &As[buf * 8192 + (wm * 128 + q * 16 + fr) * 32 + kswz]);
#pragma unroll
        for (int q = 0; q < 4; q++)
            bfr[q] = *reinterpret_cast<const short8*>(
                &Bs[buf * 8192 + (wn * 64 + q * 16 + fr) * 32 + kswz]);
        if (t + 2 < nt) STAGE_A(t + 2);
        __builtin_amdgcn_s_barrier();
        asm volatile("s_waitcnt lgkmcnt(0)" ::: "memory");
        __builtin_amdgcn_sched_barrier(0);
        __builtin_amdgcn_s_setprio(1);
#pragma unroll
        for (int m = 0; m < 4; m++)
#pragma unroll
            for (int n = 0; n < 4; n++)
                acc[m][n] = __builtin_amdgcn_mfma_f32_16x16x32_bf16(
                    afr[m], bfr[n], acc[m][n], 0, 0, 0);
        __builtin_amdgcn_s_setprio(0);
        __builtin_amdgcn_s_barrier();
        // phase 1: m-frags 4..7 (reuse bfr)
#pragma unroll
        for (int q = 0; q < 4; q++)
            afr[q] = *reinterpret_cast<const short8*>(
                &As[buf * 8192 + (wm * 128 + 64 + q * 16 + fr) * 32 + kswz]);
        if (t + 2 < nt) STAGE_B(t + 2);
        if (t + 1 < nt) {
            if (t + 2 < nt)
                asm volatile("s_waitcnt vmcnt(4)" ::: "memory");
            else
                asm volatile("s_waitcnt vmcnt(0)" ::: "memory");
        }
        __builtin_amdgcn_s_barrier();
        asm volatile("s_waitcnt lgkmcnt(0)" ::: "memory");
        __builtin_amdgcn_sched_barrier(0);
        __builtin_amdgcn_s_setprio(1);
#pragma unroll
        for (int m = 0; m < 4; m++)
#pragma unroll
            for (int n = 0; n < 4; n++)
                acc[4 + m][n] = __builtin_amdgcn_mfma_f32_16x16x32_bf16(
                    afr[m], bfr[n], acc[4 + m][n], 0, 0, 0);
        __builtin_amdgcn_s_setprio(0);
        __builtin_amdgcn_s_barrier();
    }
#undef STAGE_A
#undef STAGE_B

    const int g4 = kg * 4;
#pragma unroll
    for (int m = 0; m < 8; m++)
#pragma unroll
        for (int n = 0; n < 4; n++)
#pragma unroll
            for (int j = 0; j < 4; j++) {
                int mm = m0 + wm * 128 + m * 16 + g4 + j;
                int nn = n0 + wn * 64 + n * 16 + fr;
                float v = acc[m][n][j];
                if (EPI == 1) {
                    if (nn < DINNER)
                        C[(size_t)mm * DINNER + nn] = f2bf(v);
                    else
                        C2[(size_t)mm * DINNER + (nn - DINNER)] = f2bf(silu_f(v));
                } else {
                    if constexpr (sizeof(CT) == 2)
                        C[(size_t)mm * N + nn] = f2bf(v);
                    else
                        C[(size_t)mm * N + nn] = v;
                }
            }
}

// ---- 128x128 2-phase MFMA GEMM (out) ----
template <int EPI, typename CT>
__global__ __launch_bounds__(256) void gemm_mfma(
    const unsigned short* __restrict__ A, const unsigned short* __restrict__ Bt,
    CT* __restrict__ C, int M, int N, int K) {
    __shared__ __align__(16) unsigned short As[2][4096];
    __shared__ __align__(16) unsigned short Bs[2][4096];
    const int tid = threadIdx.x;
    const int lane = tid & 63;
    const int wid = tid >> 6;
    const int wr = wid >> 1, wc = wid & 1;
    const int nwg = gridDim.x * gridDim.y;
    const int wg = xcd_swz(blockIdx.y * gridDim.x + blockIdx.x, nwg);
    const int m0 = (wg / gridDim.x) * 128, n0 = (wg % gridDim.x) * 128;

    const int r0 = tid >> 2;
    const int r1 = r0 + 64;
    const int d0 = tid * 8;
    const int d1 = d0 + 2048;
    const int cs8 = (((tid & 3) ^ ((tid >> 3) & 3)) << 3);

    f32x4 acc[4][4];
#pragma unroll
    for (int m = 0; m < 4; m++)
#pragma unroll
        for (int n = 0; n < 4; n++) acc[m][n] = (f32x4){0.f, 0.f, 0.f, 0.f};

    const int fr = lane & 15;
    const int kg = lane >> 4;
    const int kswz = ((kg ^ ((fr >> 1) & 3)) << 3);
    const int nt = K / 32;

    gld_lds16(&A[(size_t)(m0 + r0) * K + cs8], &As[0][d0]);
    gld_lds16(&A[(size_t)(m0 + r1) * K + cs8], &As[0][d1]);
    gld_lds16(&Bt[(size_t)(n0 + r0) * K + cs8], &Bs[0][d0]);
    gld_lds16(&Bt[(size_t)(n0 + r1) * K + cs8], &Bs[0][d1]);
    __syncthreads();

    int cur = 0;
    for (int t = 0; t < nt; t++) {
        if (t + 1 < nt) {
            const int k0 = (t + 1) * 32;
            gld_lds16(&A[(size_t)(m0 + r0) * K + k0 + cs8], &As[cur ^ 1][d0]);
            gld_lds16(&A[(size_t)(m0 + r1) * K + k0 + cs8], &As[cur ^ 1][d1]);
            gld_lds16(&Bt[(size_t)(n0 + r0) * K + k0 + cs8], &Bs[cur ^ 1][d0]);
            gld_lds16(&Bt[(size_t)(n0 + r1) * K + k0 + cs8], &Bs[cur ^ 1][d1]);
        }
        short8 a[4], b[4];
#pragma unroll
        for (int m = 0; m < 4; m++)
            a[m] = *reinterpret_cast<const short8*>(
                &As[cur][(wr * 64 + m * 16 + fr) * 32 + kswz]);
#pragma unroll
        for (int n = 0; n < 4; n++)
            b[n] = *reinterpret_cast<const short8*>(
                &Bs[cur][(wc * 64 + n * 16 + fr) * 32 + kswz]);
#pragma unroll
        for (int m = 0; m < 4; m++)
#pragma unroll
            for (int n = 0; n < 4; n++)
                acc[m][n] = __builtin_amdgcn_mfma_f32_16x16x32_bf16(
                    a[m], b[n], acc[m][n], 0, 0, 0);
        __syncthreads();
        cur ^= 1;
    }

    const int g4 = (lane >> 4) * 4;
#pragma unroll
    for (int m = 0; m < 4; m++)
#pragma unroll
        for (int n = 0; n < 4; n++)
#pragma unroll
            for (int j = 0; j < 4; j++) {
                int mm = m0 + wr * 64 + m * 16 + g4 + j;
                int nn = n0 + wc * 64 + n * 16 + fr;
                float v = acc[m][n][j];
                if constexpr (sizeof(CT) == 2)
                    C[(size_t)mm * N + nn] = f2bf(v);
                else
                    C[(size_t)mm * N + nn] = v;
            }
}

// ---- dt: LDS-free direct MFMA, K=64 (dtin, WdtT both L2-resident) ----
// grid (M/32, DINNER/128); 4 waves: mt = wid>>1, nh = wid&1; softplus+bias, bf16 out
__global__ __launch_bounds__(256) void dt_gemm(
    const unsigned short* __restrict__ dtin,  // [M][64]
    const unsigned short* __restrict__ WdtT,  // [DINNER][64]
    const float* __restrict__ bias,
    unsigned short* __restrict__ dtout) {     // [M][DINNER]
    const int lane = threadIdx.x & 63;
    const int wid = threadIdx.x >> 6;
    const int mt = wid >> 1, nh = wid & 1;
    const int m0 = blockIdx.x * 32;
    const int n0 = blockIdx.y * 128 + nh * 64;
    const int fr = lane & 15, kg = lane >> 4;

    f32x4 acc[4];
#pragma unroll
    for (int i = 0; i < 4; i++) acc[i] = (f32x4){0.f, 0.f, 0.f, 0.f};

#pragma unroll
    for (int step = 0; step < 2; step++) {
        short8 a = *reinterpret_cast<const short8*>(
            &dtin[(size_t)(m0 + mt * 16 + fr) * DTRANK + step * 32 + kg * 8]);
#pragma unroll
        for (int nt = 0; nt < 4; nt++) {
            short8 b = *reinterpret_cast<const short8*>(
                &WdtT[(size_t)(n0 + nt * 16 + fr) * DTRANK + step * 32 + kg * 8]);
            acc[nt] = __builtin_amdgcn_mfma_f32_16x16x32_bf16(a, b, acc[nt], 0, 0, 0);
        }
    }
    const int g4 = kg * 4;
#pragma unroll
    for (int nt = 0; nt < 4; nt++)
#pragma unroll
        for (int j = 0; j < 4; j++) {
            int m = m0 + mt * 16 + g4 + j;
            int n = n0 + nt * 16 + fr;
            dtout[(size_t)m * DINNER + n] = f2bf(softplus_f(acc[nt][j] + bias[n]));
        }
}

// ---- proj split-K MFMA: pp[kc][M][96] partial of xb_bf @ WxT^T ----
__global__ __launch_bounds__(256) void proj_splitk(
    const unsigned short* __restrict__ Abf,
    const unsigned short* __restrict__ WxT,
    float* __restrict__ pp) {
    const int lane = threadIdx.x & 63;
    const int wid = threadIdx.x >> 6;
    const int mt = wid >> 1;
    const int nh = wid & 1;
    const int m0 = blockIdx.x * 32;
    const int kc = blockIdx.y;
    const int fr = lane & 15;
    const int kg = lane >> 4;

    const size_t abase = (size_t)(m0 + mt * 16 + fr) * DINNER + kc * KCH + kg * 8;

    f32x4 acc[3];
#pragma unroll
    for (int i = 0; i < 3; i++) acc[i] = (f32x4){0.f, 0.f, 0.f, 0.f};

    for (int step = 0; step < KCH / 32; step++) {
        short8 a = *reinterpret_cast<const short8*>(&Abf[abase + step * 32]);
#pragma unroll
        for (int nt = 0; nt < 3; nt++) {
            int nrow = nh * 48 + nt * 16 + fr;
            short8 b = *reinterpret_cast<const short8*>(
                &WxT[(size_t)nrow * DINNER + kc * KCH + step * 32 + kg * 8]);
            acc[nt] = __builtin_amdgcn_mfma_f32_16x16x32_bf16(a, b, acc[nt], 0, 0, 0);
        }
    }
    const int g4 = (lane >> 4) * 4;
#pragma unroll
    for (int nt = 0; nt < 3; nt++)
#pragma unroll
        for (int j = 0; j < 4; j++) {
            int m = m0 + mt * 16 + g4 + j;
            int n = nh * 48 + nt * 16 + fr;
            pp[((size_t)kc * (BSZ * LSEQ) + m) * NPROJ + n] = acc[nt][j];
        }
}

// reduce split-K partials; emit fp32 proj + bf16 dt_in (cols < DTRANK)
__global__ __launch_bounds__(256) void proj_reduce(
    const float* __restrict__ pp, float* __restrict__ proj,
    unsigned short* __restrict__ dtin) {
    int i = blockIdx.x * 256 + threadIdx.x;
    if (i >= BSZ * LSEQ * NPROJ) return;
    float s = 0.f;
#pragma unroll
    for (int kc = 0; kc < KS; kc++)
        s += pp[(size_t)kc * BSZ * LSEQ * NPROJ + i];
    proj[i] = s;
    int m = i / NPROJ;
    int n = i - m * NPROJ;
    if (n < DTRANK) dtin[(size_t)m * DTRANK + n] = f2bf(s);
}

// ---- causal depthwise conv (k=4) + bias + silu — sliding window (r10-proven) ----
__global__ __launch_bounds__(256) void conv_silu_kernel(
    const unsigned short* __restrict__ xin, const float* __restrict__ w,
    const float* __restrict__ bconv, unsigned short* __restrict__ xout) {
    const int tid = threadIdx.x;
    const int d0 = tid * 8;
    const int bt0 = blockIdx.x * TT;
    const int tloc = bt0 & (LSEQ - 1);

    float wk0[8], wk1[8], wk2[8], wk3[8], bb[8];
#pragma unroll
    for (int q = 0; q < 8; q++) {
        float4 wv = *reinterpret_cast<const float4*>(&w[(d0 + q) * 4]);
        wk0[q] = wv.x; wk1[q] = wv.y; wk2[q] = wv.z; wk3[q] = wv.w;
    }
    {
        float4 b0 = *reinterpret_cast<const float4*>(&bconv[d0]);
        float4 b1 = *reinterpret_cast<const float4*>(&bconv[d0 + 4]);
        bb[0] = b0.x; bb[1] = b0.y; bb[2] = b0.z; bb[3] = b0.w;
        bb[4] = b1.x; bb[5] = b1.y; bb[6] = b1.z; bb[7] = b1.w;
    }

    float xm3[8], xm2[8], xm1[8];
    if (tloc >= 3) {
        short8 v3 = *reinterpret_cast<const short8*>(&xin[(size_t)(bt0 - 3) * DINNER + d0]);
        short8 v2 = *reinterpret_cast<const short8*>(&xin[(size_t)(bt0 - 2) * DINNER + d0]);
        short8 v1 = *reinterpret_cast<const short8*>(&xin[(size_t)(bt0 - 1) * DINNER + d0]);
#pragma unroll
        for (int q = 0; q < 8; q++) {
            xm3[q] = bf2f((unsigned short)v3[q]);
            xm2[q] = bf2f((unsigned short)v2[q]);
            xm1[q] = bf2f((unsigned short)v1[q]);
        }
    } else {
#pragma unroll
        for (int q = 0; q < 8; q++) { xm3[q] = 0.f; xm2[q] = 0.f; xm1[q] = 0.f; }
    }

#pragma unroll
    for (int i = 0; i < TT; i++) {
        short8 vc = *reinterpret_cast<const short8*>(&xin[(size_t)(bt0 + i) * DINNER + d0]);
        float xc[8];
        short8 o;
#pragma unroll
        for (int q = 0; q < 8; q++) {
            xc[q] = bf2f((unsigned short)vc[q]);
            float a = bb[q];
            a = fmaf(wk0[q], xm3[q], a);
            a = fmaf(wk1[q], xm2[q], a);
            a = fmaf(wk2[q], xm1[q], a);
            a = fmaf(wk3[q], xc[q], a);
            o[q] = (short)f2bf(silu_f(a));
        }
        *reinterpret_cast<short8*>(&xout[(size_t)(bt0 + i) * DINNER + d0]) = o;
#pragma unroll
        for (int q = 0; q < 8; q++) { xm3[q] = xm2[q]; xm2[q] = xm1[q]; xm1[q] = xc[q]; }
    }
}

// ---- chunked selective scan (bf16 operands, fp32 state) ----
__global__ __launch_bounds__(256) void scan_pass1(
    const unsigned short* __restrict__ xb, const unsigned short* __restrict__ dt,
    const float* __restrict__ proj, const float* __restrict__ A_log,
    float* __restrict__ aprod, float* __restrict__ hend) {
    __shared__ float Bs[LC][DSTATE];
    const int tg = blockIdx.x * 256 + threadIdx.x;
    const int d = tg & (DINNER - 1);
    const int bc = tg >> 11;
    const int c = bc & (NC - 1);
    const int b = bc >> 5;

    for (int idx = threadIdx.x; idx < LC * DSTATE; idx += 256) {
        int ti = idx >> 4, j = idx & 15;
        Bs[ti][j] = proj[(size_t)(b * LSEQ + c * LC + ti) * NPROJ + DTRANK + j];
    }
    __syncthreads();

    float Av[DSTATE], h[DSTATE], ap[DSTATE];
#pragma unroll
    for (int s = 0; s < DSTATE; s++) {
        Av[s] = -expf(A_log[d * DSTATE + s]);
        h[s] = 0.f;
        ap[s] = 1.f;
    }

    for (int i = 0; i < LC; i++) {
        size_t base = (size_t)(b * LSEQ + c * LC + i) * DINNER + d;
        float dtv = bf2f(dt[base]);
        float xv = bf2f(xb[base]);
        float dx = dtv * xv;
#pragma unroll
        for (int s = 0; s < DSTATE; s++) {
            float dA = __expf(dtv * Av[s]);
            ap[s] *= dA;
            h[s] = fmaf(dA, h[s], dx * Bs[i][s]);
        }
    }

    size_t o = ((size_t)bc * DINNER + d) * DSTATE;
#pragma unroll
    for (int q = 0; q < 4; q++) {
        *reinterpret_cast<float4*>(&aprod[o + q * 4]) =
            make_float4(ap[4 * q], ap[4 * q + 1], ap[4 * q + 2], ap[4 * q + 3]);
        *reinterpret_cast<float4*>(&hend[o + q * 4]) =
            make_float4(h[4 * q], h[4 * q + 1], h[4 * q + 2], h[4 * q + 3]);
    }
}

__global__ __launch_bounds__(256) void scan_pass2(
    float* __restrict__ aprod, const float* __restrict__ hend) {
    const int tg = blockIdx.x * 256 + threadIdx.x;
    const int s = tg & (DSTATE - 1);
    const int d = (tg >> 4) & (DINNER - 1);
    const int b = tg >> 15;
    float h = 0.f;
    for (int c = 0; c < NC; c++) {
        size_t o = ((size_t)((b * NC + c) * DINNER) + d) * DSTATE + s;
        float a = aprod[o];
        float e = hend[o];
        aprod[o] = h;
        h = fmaf(a, h, e);
    }
}

__global__ __launch_bounds__(256) void scan_pass3(
    const unsigned short* __restrict__ xb, const unsigned short* __restrict__ dt,
    const float* __restrict__ proj, const float* __restrict__ hstart,
    const float* __restrict__ A_log, const float* __restrict__ Dp,
    const unsigned short* __restrict__ sz, unsigned short* __restrict__ ybf) {
    __shared__ float Bs[LC][DSTATE];
    __shared__ float Cs[LC][DSTATE];
    const int tg = blockIdx.x * 256 + threadIdx.x;
    const int d = tg & (DINNER - 1);
    const int bc = tg >> 11;
    const int c = bc & (NC - 1);
    const int b = bc >> 5;

    for (int idx = threadIdx.x; idx < LC * 2 * DSTATE; idx += 256) {
        int ti = idx >> 5, j = idx & 31;
        float v = proj[(size_t)(b * LSEQ + c * LC + ti) * NPROJ + DTRANK + j];
        if (j < DSTATE) Bs[ti][j] = v;
        else            Cs[ti][j - DSTATE] = v;
    }
    __syncthreads();

    float Av[DSTATE], h[DSTATE];
    size_t o = ((size_t)bc * DINNER + d) * DSTATE;
#pragma unroll
    for (int q = 0; q < 4; q++) {
        float4 hv = *reinterpret_cast<const float4*>(&hstart[o + q * 4]);
        h[4 * q] = hv.x; h[4 * q + 1] = hv.y; h[4 * q + 2] = hv.z; h[4 * q + 3] = hv.w;
    }
#pragma unroll
    for (int s = 0; s < DSTATE; s++)
        Av[s] = -expf(A_log[d * DSTATE + s]);
    const float Dd = Dp[d];

    for (int i = 0; i < LC; i++) {
        size_t base = (size_t)(b * LSEQ + c * LC + i) * DINNER + d;
        float dtv = bf2f(dt[base]);
        float xv = bf2f(xb[base]);
        float szv = bf2f(sz[base]);
        float dx = dtv * xv;
        float p = 0.f;
#pragma unroll
        for (int s = 0; s < DSTATE; s++) {
            float dA = __expf(dtv * Av[s]);
            h[s] = fmaf(dA, h[s], dx * Bs[i][s]);
            p = fmaf(h[s], Cs[i][s], p);
        }
        ybf[base] = f2bf((p + Dd * xv) * szv);
    }
}

extern "C" void kernel_launch(void* const* d_in, const int* in_sizes, int n_in,
                              void* d_out, int out_size, void* d_ws,
                              size_t ws_size, hipStream_t stream) {
    const float* x = (const float*)d_in[0];
    const float* W_in = (const float*)d_in[1];
    const float* conv_w = (const float*)d_in[2];
    const float* conv_b = (const float*)d_in[3];
    const float* W_xproj = (const float*)d_in[4];
    const float* W_dt = (const float*)d_in[5];
    const float* b_dt = (const float*)d_in[6];
    const float* A_log = (const float*)d_in[7];
    const float* Dp = (const float*)d_in[8];
    const float* W_out = (const float*)d_in[9];
    float* out = (float*)d_out;

    char* ws = (char*)d_ws;
    const size_t MB = 1u << 20;
    // [0,16M): pp (6.3M, KS=4) -> later aprod(8M)+hend(8M)
    float* pp    = (float*)(ws);
    float* aprod = (float*)(ws);
    float* hend  = (float*)(ws + 8 * MB);
    // [16,32M): xbpre_bf (dead after conv) -> ybf (16 MB) for scan_pass3/out-GEMM
    unsigned short* xbpre_bf = (unsigned short*)(ws + 16 * MB);  // 16 MB
    unsigned short* ybf      = (unsigned short*)(ws + 16 * MB);  // 16 MB (after conv)
    unsigned short* sz_bf    = (unsigned short*)(ws + 32 * MB);  // 16 MB
    unsigned short* xb_bf    = (unsigned short*)(ws + 48 * MB);  // 16 MB
    unsigned short* dt_bf    = (unsigned short*)(ws + 64 * MB);  // 16 MB
    float* projbuf           = (float*)(ws + 88 * MB);           // 1.5 MB
    unsigned short* dtin_bf  = (unsigned short*)(ws + 90 * MB);  // 0.5 MB
    unsigned short* xbf      = (unsigned short*)(ws + 91 * MB);  // 8 MB
    unsigned short* WinT     = (unsigned short*)(ws + 99 * MB);  // 8 MB
    unsigned short* WoutT    = (unsigned short*)(ws + 107 * MB); // 4 MB
    unsigned short* WxT      = (unsigned short*)(ws + 111 * MB); // 384 KB
    unsigned short* WdtT     = (unsigned short*)(ws + 112 * MB); // 256 KB

    const int M = BSZ * LSEQ; // 4096
    dim3 blk(256);

    // prep
    f32_to_bf16_kernel<<<dim3((M * DMODEL / 4 + 255) / 256), blk, 0, stream>>>(
        x, xbf, M * DMODEL / 4);
    transpose_bf16_kernel<<<dim3(2 * DINNER / 32, DMODEL / 32), blk, 0, stream>>>(
        W_in, WinT, DMODEL, 2 * DINNER);
    transpose_bf16_kernel<<<dim3(DMODEL / 32, DINNER / 32), blk, 0, stream>>>(
        W_out, WoutT, DINNER, DMODEL);
    transpose_bf16_kernel<<<dim3(NPROJ / 32, DINNER / 32), blk, 0, stream>>>(
        W_xproj, WxT, DINNER, NPROJ);
    transpose_bf16_kernel<<<dim3(DINNER / 32, DTRANK / 32), blk, 0, stream>>>(
        W_dt, WdtT, DTRANK, DINNER);

    // 1. xz = x @ W_in — 256x256 8-wave phase-interleaved (96 KB dyn LDS)
    gemm256<1, unsigned short><<<dim3((2 * DINNER) / 256, M / 256), dim3(512),
                                 98304, stream>>>(
        xbf, WinT, xbpre_bf, sz_bf, M, 2 * DINNER, DMODEL);

    // 2. conv + silu (sliding window, TT=8); xbpre dead after this
    conv_silu_kernel<<<dim3(M / TT), blk, 0, stream>>>(
        xbpre_bf, conv_w, conv_b, xb_bf);

    // 3. proj (split-K = 4)
    proj_splitk<<<dim3(M / 32, KS), blk, 0, stream>>>(xb_bf, WxT, pp);
    proj_reduce<<<dim3((M * NPROJ) / 256), blk, 0, stream>>>(pp, projbuf, dtin_bf);

    // 4. dt = softplus(dt_in @ W_dt + b_dt) — LDS-free direct MFMA
    dt_gemm<<<dim3(M / 32, DINNER / 128), blk, 0, stream>>>(
        dtin_bf, WdtT, b_dt, dt_bf);

    // 5. scan
    const int nthreads1 = BSZ * NC * DINNER;
    scan_pass1<<<dim3(nthreads1 / 256), blk, 0, stream>>>(
        xb_bf, dt_bf, projbuf, A_log, aprod, hend);
    const int nthreads2 = BSZ * DINNER * DSTATE;
    scan_pass2<<<dim3(nthreads2 / 256), blk, 0, stream>>>(aprod, hend);
    scan_pass3<<<dim3(nthreads1 / 256), blk, 0, stream>>>(
        xb_bf, dt_bf, projbuf, aprod, A_log, Dp, sz_bf, ybf);

    // 6. out = y @ W_out (2-phase 128x128, XCD swizzle)
    gemm_mfma<0, float><<<dim3(DMODEL / 128, M / 128), blk, 0, stream>>>(
        ybf, WoutT, out, M, DMODEL, DINNER);
}

// Round 12
// 261.155 us; speedup vs baseline: 1.2591x; 1.0343x over previous
//
#include <hip/hip_runtime.h>
#include <hip/hip_bf16.h>
#include <math.h>

#define BSZ 2
#define LSEQ 2048
#define DMODEL 1024
#define DSTATE 16
#define DCONV 4
#define DINNER 2048
#define DTRANK 64
#define NPROJ (DTRANK + 2 * DSTATE) // 96
#define NC 32   // scan chunks
#define LC 64   // steps per chunk
#define KS 4    // proj split-K chunks
#define KCH (DINNER / KS) // 512
#define TT 8    // conv timesteps per thread

using short8 = __attribute__((ext_vector_type(8))) short;
using f32x4 = __attribute__((ext_vector_type(4))) float;
using u16x4 = __attribute__((ext_vector_type(4))) unsigned short;

__device__ __forceinline__ float silu_f(float v) {
    return v / (1.f + expf(-v));
}
__device__ __forceinline__ float softplus_f(float v) {
    return fmaxf(v, 0.f) + log1pf(expf(-fabsf(v)));
}
// fp32 -> bf16 bits, round-to-nearest-even
__device__ __forceinline__ unsigned short f2bf(float f) {
    unsigned u = __builtin_bit_cast(unsigned, f);
    u += 0x7fffu + ((u >> 16) & 1u);
    return (unsigned short)(u >> 16);
}
__device__ __forceinline__ float bf2f(unsigned short u) {
    unsigned x = ((unsigned)u) << 16;
    return __builtin_bit_cast(float, x);
}

__device__ __forceinline__ void gld_lds16(const unsigned short* g, unsigned short* l) {
    __builtin_amdgcn_global_load_lds(
        (const __attribute__((address_space(1))) unsigned int*)g,
        (__attribute__((address_space(3))) unsigned int*)l, 16, 0, 0);
}

// bijective XCD swizzle (requires nwg % 8 == 0)
__device__ __forceinline__ int xcd_swz(int wg, int nwg) {
    return (wg & 7) * (nwg >> 3) + (wg >> 3);
}

// ---- fused prep: x->bf16 + 4 weight transposes (fp32 [R][Cc] -> bf16 [Cc][R]) ----
__global__ __launch_bounds__(256) void prep_kernel(
    const float* __restrict__ x, const float* __restrict__ W_in,
    const float* __restrict__ W_out, const float* __restrict__ W_xproj,
    const float* __restrict__ W_dt,
    unsigned short* __restrict__ xbf, unsigned short* __restrict__ WinT,
    unsigned short* __restrict__ WoutT, unsigned short* __restrict__ WxT,
    unsigned short* __restrict__ WdtT) {
    int bid = blockIdx.x;
    if (bid < 4096) { // x -> bf16 (4096*1024 floats, float4 per thread)
        int i = bid * 256 + threadIdx.x;
        float4 v = reinterpret_cast<const float4*>(x)[i];
        u16x4 o = {f2bf(v.x), f2bf(v.y), f2bf(v.z), f2bf(v.w)};
        reinterpret_cast<u16x4*>(xbf)[i] = o;
        return;
    }
    bid -= 4096;
    const float* in;
    unsigned short* outp;
    int R, Cc, gx;
    if (bid < 4096) { in = W_in; outp = WinT; R = 1024; Cc = 4096; gx = 128; }
    else if ((bid -= 4096) < 2048) { in = W_out; outp = WoutT; R = 2048; Cc = 1024; gx = 32; }
    else if ((bid -= 2048) < 192) { in = W_xproj; outp = WxT; R = 2048; Cc = 96; gx = 3; }
    else { bid -= 192; in = W_dt; outp = WdtT; R = 64; Cc = 2048; gx = 64; }
    const int bx = bid % gx, by = bid / gx;
    __shared__ float t[32][33];
    const int tx = threadIdx.x & 31, ty = threadIdx.x >> 5; // 32 x 8
    const int c0 = bx * 32, r0 = by * 32;
    for (int i = ty; i < 32; i += 8)
        t[i][tx] = in[(size_t)(r0 + i) * Cc + c0 + tx];
    __syncthreads();
    for (int i = ty; i < 32; i += 8)
        outp[(size_t)(c0 + i) * R + r0 + tx] = f2bf(t[tx][i]);
}

// ===== 256x256 m201-style 4-phase BK=64 MFMA GEMM (xz) =====
// 512 thr = 8 waves; INTERLEAVED ownership: A-rows q*32+wm*16, B-cols p*64+wn*16
// so phase quadrant (qh,ph) touches exactly one A-half / one B-half.
// LDS 128 KB = 2 buf x (A 32KB + B 32KB). Staging order per tile (for t+1):
// P0:A-H0 P1:B-H0 P2:B-H1 P3:A-H1; counted vmcnt(4) after P0/P1/P3 MFMAs
// (FIFO: each wait releases exactly the half-tile the next phase reads;
// >=4 loads stay in flight). Swizzle: 8 chunks/row, slot = chunk ^ (row&7),
// both sides; 2-way bank aliasing (free).
// EPI 1: nn<DINNER -> C, else silu -> C2 (both bf16, ldc=DINNER).
template <int EPI, typename CT>
__global__ __launch_bounds__(512, 2) void gemm256(
    const unsigned short* __restrict__ A, const unsigned short* __restrict__ Bt,
    CT* __restrict__ C, CT* __restrict__ C2, int M, int N, int K) {
    extern __shared__ __align__(16) unsigned short lds[];
    unsigned short* As = lds;           // [2][16384]
    unsigned short* Bs = lds + 32768;   // [2][16384]
    const int tid = threadIdx.x;
    const int lane = tid & 63;
    const int w8 = tid >> 6;
    const int wm = w8 >> 2, wn = w8 & 3;
    const int nwg = gridDim.x * gridDim.y;
    const int wg = xcd_swz(blockIdx.y * gridDim.x + blockIdx.x, nwg);
    const int m0 = (wg / gridDim.x) * 256, n0 = (wg % gridDim.x) * 256;
    const int fr = lane & 15, kg = lane >> 4;
    const int s0 = ((kg ^ (fr & 7)) << 3);        // k-half 0 slot (elems)
    const int s1 = (((4 + kg) ^ (fr & 7)) << 3);  // k-half 1 slot
    const int cs8 = (((tid & 7) ^ ((tid >> 3) & 7)) << 3); // staging src chunk
    const int srow = tid >> 3;                    // 0..63
    const int nt = K / 64;

    f32x4 acc[8][4];
#pragma unroll
    for (int q = 0; q < 8; q++)
#pragma unroll
        for (int p = 0; p < 4; p++) acc[q][p] = (f32x4){0.f, 0.f, 0.f, 0.f};

// stage half h (rows h*128..h*128+127) of tile tt (2 gld, 16 KB)
#define SA(tt, h)                                                                \
    {                                                                            \
        const int _b = ((tt) & 1) * 16384, _k = (tt) * 64;                       \
        gld_lds16(&A[(size_t)(m0 + (h) * 128 + srow) * K + _k + cs8],            \
                  &As[_b + (((h) * 2) * 512 + tid) * 8]);                        \
        gld_lds16(&A[(size_t)(m0 + (h) * 128 + 64 + srow) * K + _k + cs8],       \
                  &As[_b + (((h) * 2 + 1) * 512 + tid) * 8]);                    \
    }
#define SB(tt, h)                                                                \
    {                                                                            \
        const int _b = ((tt) & 1) * 16384, _k = (tt) * 64;                       \
        gld_lds16(&Bt[(size_t)(n0 + (h) * 128 + srow) * K + _k + cs8],           \
                  &Bs[_b + (((h) * 2) * 512 + tid) * 8]);                        \
        gld_lds16(&Bt[(size_t)(n0 + (h) * 128 + 64 + srow) * K + _k + cs8],      \
                  &Bs[_b + (((h) * 2 + 1) * 512 + tid) * 8]);                    \
    }

    // prologue: tile 0 fully staged, drained once
    SA(0, 0); SB(0, 0); SB(0, 1); SA(0, 1);
    asm volatile("s_waitcnt vmcnt(0)" ::: "memory");
    __builtin_amdgcn_s_barrier();

    short8 a[4][2], b[4][2];
    for (int t = 0; t < nt; t++) {
        const int bufo = (t & 1) * 16384;
        const bool pre = (t + 1 < nt);
        // ---- P0: quadrant (q0-3, p0-1); reads A-H0, B-H0 ----
#pragma unroll
        for (int i = 0; i < 4; i++) {
            const int row = i * 32 + wm * 16 + fr;
            a[i][0] = *reinterpret_cast<const short8*>(&As[bufo + row * 64 + s0]);
            a[i][1] = *reinterpret_cast<const short8*>(&As[bufo + row * 64 + s1]);
        }
#pragma unroll
        for (int p = 0; p < 2; p++) {
            const int row = p * 64 + wn * 16 + fr;
            b[p][0] = *reinterpret_cast<const short8*>(&Bs[bufo + row * 64 + s0]);
            b[p][1] = *reinterpret_cast<const short8*>(&Bs[bufo + row * 64 + s1]);
        }
        if (pre) SA(t + 1, 0);
        __builtin_amdgcn_s_barrier();
        asm volatile("s_waitcnt lgkmcnt(0)" ::: "memory");
        __builtin_amdgcn_sched_barrier(0);
        __builtin_amdgcn_s_setprio(1);
#pragma unroll
        for (int i = 0; i < 4; i++)
#pragma unroll
            for (int p = 0; p < 2; p++) {
                acc[i][p] = __builtin_amdgcn_mfma_f32_16x16x32_bf16(
                    a[i][0], b[p][0], acc[i][p], 0, 0, 0);
                acc[i][p] = __builtin_amdgcn_mfma_f32_16x16x32_bf16(
                    a[i][1], b[p][1], acc[i][p], 0, 0, 0);
            }
        __builtin_amdgcn_s_setprio(0);
        asm volatile("s_waitcnt vmcnt(4)" ::: "memory");
        __builtin_amdgcn_s_barrier();
        // ---- P1: quadrant (q0-3, p2-3); reads B-H1 ----
#pragma unroll
        for (int p = 2; p < 4; p++) {
            const int row = p * 64 + wn * 16 + fr;
            b[p][0] = *reinterpret_cast<const short8*>(&Bs[bufo + row * 64 + s0]);
            b[p][1] = *reinterpret_cast<const short8*>(&Bs[bufo + row * 64 + s1]);
        }
        if (pre) SB(t + 1, 0);
        __builtin_amdgcn_s_barrier();
        asm volatile("s_waitcnt lgkmcnt(0)" ::: "memory");
        __builtin_amdgcn_sched_barrier(0);
        __builtin_amdgcn_s_setprio(1);
#pragma unroll
        for (int i = 0; i < 4; i++)
#pragma unroll
            for (int p = 2; p < 4; p++) {
                acc[i][p] = __builtin_amdgcn_mfma_f32_16x16x32_bf16(
                    a[i][0], b[p][0], acc[i][p], 0, 0, 0);
                acc[i][p] = __builtin_amdgcn_mfma_f32_16x16x32_bf16(
                    a[i][1], b[p][1], acc[i][p], 0, 0, 0);
            }
        __builtin_amdgcn_s_setprio(0);
        asm volatile("s_waitcnt vmcnt(4)" ::: "memory");
        __builtin_amdgcn_s_barrier();
        // ---- P2: quadrant (q4-7, p0-1); reads A-H1 ----
#pragma unroll
        for (int i = 0; i < 4; i++) {
            const int row = (4 + i) * 32 + wm * 16 + fr;
            a[i][0] = *reinterpret_cast<const short8*>(&As[bufo + row * 64 + s0]);
            a[i][1] = *reinterpret_cast<const short8*>(&As[bufo + row * 64 + s1]);
        }
        if (pre) SB(t + 1, 1);
        __builtin_amdgcn_s_barrier();
        asm volatile("s_waitcnt lgkmcnt(0)" ::: "memory");
        __builtin_amdgcn_sched_barrier(0);
        __builtin_amdgcn_s_setprio(1);
#pragma unroll
        for (int i = 0; i < 4; i++)
#pragma unroll
            for (int p = 0; p < 2; p++) {
                acc[4 + i][p] = __builtin_amdgcn_mfma_f32_16x16x32_bf16(
                    a[i][0], b[p][0], acc[4 + i][p], 0, 0, 0);
                acc[4 + i][p] = __builtin_amdgcn_mfma_f32_16x16x32_bf16(
                    a[i][1], b[p][1], acc[4 + i][p], 0, 0, 0);
            }
        __builtin_amdgcn_s_setprio(0);
        __builtin_amdgcn_s_barrier();
        // ---- P3: quadrant (q4-7, p2-3); no ds_reads (regs live) ----
        if (pre) SA(t + 1, 1);
        __builtin_amdgcn_s_barrier();
        __builtin_amdgcn_s_setprio(1);
#pragma unroll
        for (int i = 0; i < 4; i++)
#pragma unroll
            for (int p = 2; p < 4; p++) {
                acc[4 + i][p] = __builtin_amdgcn_mfma_f32_16x16x32_bf16(
                    a[i][0], b[p][0], acc[4 + i][p], 0, 0, 0);
                acc[4 + i][p] = __builtin_amdgcn_mfma_f32_16x16x32_bf16(
                    a[i][1], b[p][1], acc[4 + i][p], 0, 0, 0);
            }
        __builtin_amdgcn_s_setprio(0);
        asm volatile("s_waitcnt vmcnt(4)" ::: "memory");
        __builtin_amdgcn_s_barrier();
    }
#undef SA
#undef SB

    const int g4 = kg * 4;
#pragma unroll
    for (int q = 0; q < 8; q++)
#pragma unroll
        for (int p = 0; p < 4; p++)
#pragma unroll
            for (int j = 0; j < 4; j++) {
                int mm = m0 + q * 32 + wm * 16 + g4 + j;
                int nn = n0 + p * 64 + wn * 16 + fr;
                float v = acc[q][p][j];
                if (EPI == 1) {
                    if (nn < DINNER)
                        C[(size_t)mm * DINNER + nn] = f2bf(v);
                    else
                        C2[(size_t)mm * DINNER + (nn - DINNER)] = f2bf(silu_f(v));
                } else {
                    if constexpr (sizeof(CT) == 2)
                        C[(size_t)mm * N + nn] = f2bf(v);
                    else
                        C[(size_t)mm * N + nn] = v;
                }
            }
}

// ---- 128x128 2-phase MFMA GEMM (out) ----
template <int EPI, typename CT>
__global__ __launch_bounds__(256) void gemm_mfma(
    const unsigned short* __restrict__ A, const unsigned short* __restrict__ Bt,
    CT* __restrict__ C, int M, int N, int K) {
    __shared__ __align__(16) unsigned short As[2][4096];
    __shared__ __align__(16) unsigned short Bs[2][4096];
    const int tid = threadIdx.x;
    const int lane = tid & 63;
    const int wid = tid >> 6;
    const int wr = wid >> 1, wc = wid & 1;
    const int nwg = gridDim.x * gridDim.y;
    const int wg = xcd_swz(blockIdx.y * gridDim.x + blockIdx.x, nwg);
    const int m0 = (wg / gridDim.x) * 128, n0 = (wg % gridDim.x) * 128;

    const int r0 = tid >> 2;
    const int r1 = r0 + 64;
    const int d0 = tid * 8;
    const int d1 = d0 + 2048;
    const int cs8 = (((tid & 3) ^ ((tid >> 3) & 3)) << 3);

    f32x4 acc[4][4];
#pragma unroll
    for (int m = 0; m < 4; m++)
#pragma unroll
        for (int n = 0; n < 4; n++) acc[m][n] = (f32x4){0.f, 0.f, 0.f, 0.f};

    const int fr = lane & 15;
    const int kg = lane >> 4;
    const int kswz = ((kg ^ ((fr >> 1) & 3)) << 3);
    const int nt = K / 32;

    gld_lds16(&A[(size_t)(m0 + r0) * K + cs8], &As[0][d0]);
    gld_lds16(&A[(size_t)(m0 + r1) * K + cs8], &As[0][d1]);
    gld_lds16(&Bt[(size_t)(n0 + r0) * K + cs8], &Bs[0][d0]);
    gld_lds16(&Bt[(size_t)(n0 + r1) * K + cs8], &Bs[0][d1]);
    __syncthreads();

    int cur = 0;
    for (int t = 0; t < nt; t++) {
        if (t + 1 < nt) {
            const int k0 = (t + 1) * 32;
            gld_lds16(&A[(size_t)(m0 + r0) * K + k0 + cs8], &As[cur ^ 1][d0]);
            gld_lds16(&A[(size_t)(m0 + r1) * K + k0 + cs8], &As[cur ^ 1][d1]);
            gld_lds16(&Bt[(size_t)(n0 + r0) * K + k0 + cs8], &Bs[cur ^ 1][d0]);
            gld_lds16(&Bt[(size_t)(n0 + r1) * K + k0 + cs8], &Bs[cur ^ 1][d1]);
        }
        short8 a[4], b[4];
#pragma unroll
        for (int m = 0; m < 4; m++)
            a[m] = *reinterpret_cast<const short8*>(
                &As[cur][(wr * 64 + m * 16 + fr) * 32 + kswz]);
#pragma unroll
        for (int n = 0; n < 4; n++)
            b[n] = *reinterpret_cast<const short8*>(
                &Bs[cur][(wc * 64 + n * 16 + fr) * 32 + kswz]);
#pragma unroll
        for (int m = 0; m < 4; m++)
#pragma unroll
            for (int n = 0; n < 4; n++)
                acc[m][n] = __builtin_amdgcn_mfma_f32_16x16x32_bf16(
                    a[m], b[n], acc[m][n], 0, 0, 0);
        __syncthreads();
        cur ^= 1;
    }

    const int g4 = (lane >> 4) * 4;
#pragma unroll
    for (int m = 0; m < 4; m++)
#pragma unroll
        for (int n = 0; n < 4; n++)
#pragma unroll
            for (int j = 0; j < 4; j++) {
                int mm = m0 + wr * 64 + m * 16 + g4 + j;
                int nn = n0 + wc * 64 + n * 16 + fr;
                float v = acc[m][n][j];
                if constexpr (sizeof(CT) == 2)
                    C[(size_t)mm * N + nn] = f2bf(v);
                else
                    C[(size_t)mm * N + nn] = v;
            }
}

// ---- dt: LDS-free direct MFMA, K=64 ----
__global__ __launch_bounds__(256) void dt_gemm(
    const unsigned short* __restrict__ dtin,  // [M][64]
    const unsigned short* __restrict__ WdtT,  // [DINNER][64]
    const float* __restrict__ bias,
    unsigned short* __restrict__ dtout) {     // [M][DINNER]
    const int lane = threadIdx.x & 63;
    const int wid = threadIdx.x >> 6;
    const int mt = wid >> 1, nh = wid & 1;
    const int m0 = blockIdx.x * 32;
    const int n0 = blockIdx.y * 128 + nh * 64;
    const int fr = lane & 15, kg = lane >> 4;

    f32x4 acc[4];
#pragma unroll
    for (int i = 0; i < 4; i++) acc[i] = (f32x4){0.f, 0.f, 0.f, 0.f};

#pragma unroll
    for (int step = 0; step < 2; step++) {
        short8 a = *reinterpret_cast<const short8*>(
            &dtin[(size_t)(m0 + mt * 16 + fr) * DTRANK + step * 32 + kg * 8]);
#pragma unroll
        for (int nt = 0; nt < 4; nt++) {
            short8 b = *reinterpret_cast<const short8*>(
                &WdtT[(size_t)(n0 + nt * 16 + fr) * DTRANK + step * 32 + kg * 8]);
            acc[nt] = __builtin_amdgcn_mfma_f32_16x16x32_bf16(a, b, acc[nt], 0, 0, 0);
        }
    }
    const int g4 = kg * 4;
#pragma unroll
    for (int nt = 0; nt < 4; nt++)
#pragma unroll
        for (int j = 0; j < 4; j++) {
            int m = m0 + mt * 16 + g4 + j;
            int n = n0 + nt * 16 + fr;
            dtout[(size_t)m * DINNER + n] = f2bf(softplus_f(acc[nt][j] + bias[n]));
        }
}

// ---- proj split-K MFMA: pp[kc][M][96] partial of xb_bf @ WxT^T ----
__global__ __launch_bounds__(256) void proj_splitk(
    const unsigned short* __restrict__ Abf,
    const unsigned short* __restrict__ WxT,
    float* __restrict__ pp) {
    const int lane = threadIdx.x & 63;
    const int wid = threadIdx.x >> 6;
    const int mt = wid >> 1;
    const int nh = wid & 1;
    const int m0 = blockIdx.x * 32;
    const int kc = blockIdx.y;
    const int fr = lane & 15;
    const int kg = lane >> 4;

    const size_t abase = (size_t)(m0 + mt * 16 + fr) * DINNER + kc * KCH + kg * 8;

    f32x4 acc[3];
#pragma unroll
    for (int i = 0; i < 3; i++) acc[i] = (f32x4){0.f, 0.f, 0.f, 0.f};

    for (int step = 0; step < KCH / 32; step++) {
        short8 a = *reinterpret_cast<const short8*>(&Abf[abase + step * 32]);
#pragma unroll
        for (int nt = 0; nt < 3; nt++) {
            int nrow = nh * 48 + nt * 16 + fr;
            short8 b = *reinterpret_cast<const short8*>(
                &WxT[(size_t)nrow * DINNER + kc * KCH + step * 32 + kg * 8]);
            acc[nt] = __builtin_amdgcn_mfma_f32_16x16x32_bf16(a, b, acc[nt], 0, 0, 0);
        }
    }
    const int g4 = (lane >> 4) * 4;
#pragma unroll
    for (int nt = 0; nt < 3; nt++)
#pragma unroll
        for (int j = 0; j < 4; j++) {
            int m = m0 + mt * 16 + g4 + j;
            int n = nh * 48 + nt * 16 + fr;
            pp[((size_t)kc * (BSZ * LSEQ) + m) * NPROJ + n] = acc[nt][j];
        }
}

// reduce split-K partials; emit fp32 proj + bf16 dt_in (cols < DTRANK)
__global__ __launch_bounds__(256) void proj_reduce(
    const float* __restrict__ pp, float* __restrict__ proj,
    unsigned short* __restrict__ dtin) {
    int i = blockIdx.x * 256 + threadIdx.x;
    if (i >= BSZ * LSEQ * NPROJ) return;
    float s = 0.f;
#pragma unroll
    for (int kc = 0; kc < KS; kc++)
        s += pp[(size_t)kc * BSZ * LSEQ * NPROJ + i];
    proj[i] = s;
    int m = i / NPROJ;
    int n = i - m * NPROJ;
    if (n < DTRANK) dtin[(size_t)m * DTRANK + n] = f2bf(s);
}

// ---- causal depthwise conv (k=4) + bias + silu — sliding window ----
__global__ __launch_bounds__(256) void conv_silu_kernel(
    const unsigned short* __restrict__ xin, const float* __restrict__ w,
    const float* __restrict__ bconv, unsigned short* __restrict__ xout) {
    const int tid = threadIdx.x;
    const int d0 = tid * 8;
    const int bt0 = blockIdx.x * TT;
    const int tloc = bt0 & (LSEQ - 1);

    float wk0[8], wk1[8], wk2[8], wk3[8], bb[8];
#pragma unroll
    for (int q = 0; q < 8; q++) {
        float4 wv = *reinterpret_cast<const float4*>(&w[(d0 + q) * 4]);
        wk0[q] = wv.x; wk1[q] = wv.y; wk2[q] = wv.z; wk3[q] = wv.w;
    }
    {
        float4 b0 = *reinterpret_cast<const float4*>(&bconv[d0]);
        float4 b1 = *reinterpret_cast<const float4*>(&bconv[d0 + 4]);
        bb[0] = b0.x; bb[1] = b0.y; bb[2] = b0.z; bb[3] = b0.w;
        bb[4] = b1.x; bb[5] = b1.y; bb[6] = b1.z; bb[7] = b1.w;
    }

    float xm3[8], xm2[8], xm1[8];
    if (tloc >= 3) {
        short8 v3 = *reinterpret_cast<const short8*>(&xin[(size_t)(bt0 - 3) * DINNER + d0]);
        short8 v2 = *reinterpret_cast<const short8*>(&xin[(size_t)(bt0 - 2) * DINNER + d0]);
        short8 v1 = *reinterpret_cast<const short8*>(&xin[(size_t)(bt0 - 1) * DINNER + d0]);
#pragma unroll
        for (int q = 0; q < 8; q++) {
            xm3[q] = bf2f((unsigned short)v3[q]);
            xm2[q] = bf2f((unsigned short)v2[q]);
            xm1[q] = bf2f((unsigned short)v1[q]);
        }
    } else {
#pragma unroll
        for (int q = 0; q < 8; q++) { xm3[q] = 0.f; xm2[q] = 0.f; xm1[q] = 0.f; }
    }

#pragma unroll
    for (int i = 0; i < TT; i++) {
        short8 vc = *reinterpret_cast<const short8*>(&xin[(size_t)(bt0 + i) * DINNER + d0]);
        float xc[8];
        short8 o;
#pragma unroll
        for (int q = 0; q < 8; q++) {
            xc[q] = bf2f((unsigned short)vc[q]);
            float a = bb[q];
            a = fmaf(wk0[q], xm3[q], a);
            a = fmaf(wk1[q], xm2[q], a);
            a = fmaf(wk2[q], xm1[q], a);
            a = fmaf(wk3[q], xc[q], a);
            o[q] = (short)f2bf(silu_f(a));
        }
        *reinterpret_cast<short8*>(&xout[(size_t)(bt0 + i) * DINNER + d0]) = o;
#pragma unroll
        for (int q = 0; q < 8; q++) { xm3[q] = xm2[q]; xm2[q] = xm1[q]; xm1[q] = xc[q]; }
    }
}

// ---- chunked selective scan (bf16 operands, fp32 state) ----
__global__ __launch_bounds__(256) void scan_pass1(
    const unsigned short* __restrict__ xb, const unsigned short* __restrict__ dt,
    const float* __restrict__ proj, const float* __restrict__ A_log,
    float* __restrict__ aprod, float* __restrict__ hend) {
    __shared__ float Bs[LC][DSTATE];
    const int tg = blockIdx.x * 256 + threadIdx.x;
    const int d = tg & (DINNER - 1);
    const int bc = tg >> 11;
    const int c = bc & (NC - 1);
    const int b = bc >> 5;

    for (int idx = threadIdx.x; idx < LC * DSTATE; idx += 256) {
        int ti = idx >> 4, j = idx & 15;
        Bs[ti][j] = proj[(size_t)(b * LSEQ + c * LC + ti) * NPROJ + DTRANK + j];
    }
    __syncthreads();

    float Av[DSTATE], h[DSTATE], ap[DSTATE];
#pragma unroll
    for (int s = 0; s < DSTATE; s++) {
        Av[s] = -expf(A_log[d * DSTATE + s]);
        h[s] = 0.f;
        ap[s] = 1.f;
    }

    for (int i = 0; i < LC; i++) {
        size_t base = (size_t)(b * LSEQ + c * LC + i) * DINNER + d;
        float dtv = bf2f(dt[base]);
        float xv = bf2f(xb[base]);
        float dx = dtv * xv;
#pragma unroll
        for (int s = 0; s < DSTATE; s++) {
            float dA = __expf(dtv * Av[s]);
            ap[s] *= dA;
            h[s] = fmaf(dA, h[s], dx * Bs[i][s]);
        }
    }

    size_t o = ((size_t)bc * DINNER + d) * DSTATE;
#pragma unroll
    for (int q = 0; q < 4; q++) {
        *reinterpret_cast<float4*>(&aprod[o + q * 4]) =
            make_float4(ap[4 * q], ap[4 * q + 1], ap[4 * q + 2], ap[4 * q + 3]);
        *reinterpret_cast<float4*>(&hend[o + q * 4]) =
            make_float4(h[4 * q], h[4 * q + 1], h[4 * q + 2], h[4 * q + 3]);
    }
}

__global__ __launch_bounds__(256) void scan_pass2(
    float* __restrict__ aprod, const float* __restrict__ hend) {
    const int tg = blockIdx.x * 256 + threadIdx.x;
    const int s = tg & (DSTATE - 1);
    const int d = (tg >> 4) & (DINNER - 1);
    const int b = tg >> 15;
    float h = 0.f;
    for (int c = 0; c < NC; c++) {
        size_t o = ((size_t)((b * NC + c) * DINNER) + d) * DSTATE + s;
        float a = aprod[o];
        float e = hend[o];
        aprod[o] = h;
        h = fmaf(a, h, e);
    }
}

__global__ __launch_bounds__(256) void scan_pass3(
    const unsigned short* __restrict__ xb, const unsigned short* __restrict__ dt,
    const float* __restrict__ proj, const float* __restrict__ hstart,
    const float* __restrict__ A_log, const float* __restrict__ Dp,
    const unsigned short* __restrict__ sz, unsigned short* __restrict__ ybf) {
    __shared__ float Bs[LC][DSTATE];
    __shared__ float Cs[LC][DSTATE];
    const int tg = blockIdx.x * 256 + threadIdx.x;
    const int d = tg & (DINNER - 1);
    const int bc = tg >> 11;
    const int c = bc & (NC - 1);
    const int b = bc >> 5;

    for (int idx = threadIdx.x; idx < LC * 2 * DSTATE; idx += 256) {
        int ti = idx >> 5, j = idx & 31;
        float v = proj[(size_t)(b * LSEQ + c * LC + ti) * NPROJ + DTRANK + j];
        if (j < DSTATE) Bs[ti][j] = v;
        else            Cs[ti][j - DSTATE] = v;
    }
    __syncthreads();

    float Av[DSTATE], h[DSTATE];
    size_t o = ((size_t)bc * DINNER + d) * DSTATE;
#pragma unroll
    for (int q = 0; q < 4; q++) {
        float4 hv = *reinterpret_cast<const float4*>(&hstart[o + q * 4]);
        h[4 * q] = hv.x; h[4 * q + 1] = hv.y; h[4 * q + 2] = hv.z; h[4 * q + 3] = hv.w;
    }
#pragma unroll
    for (int s = 0; s < DSTATE; s++)
        Av[s] = -expf(A_log[d * DSTATE + s]);
    const float Dd = Dp[d];

    for (int i = 0; i < LC; i++) {
        size_t base = (size_t)(b * LSEQ + c * LC + i) * DINNER + d;
        float dtv = bf2f(dt[base]);
        float xv = bf2f(xb[base]);
        float szv = bf2f(sz[base]);
        float dx = dtv * xv;
        float p = 0.f;
#pragma unroll
        for (int s = 0; s < DSTATE; s++) {
            float dA = __expf(dtv * Av[s]);
            h[s] = fmaf(dA, h[s], dx * Bs[i][s]);
            p = fmaf(h[s], Cs[i][s], p);
        }
        ybf[base] = f2bf((p + Dd * xv) * szv);
    }
}

extern "C" void kernel_launch(void* const* d_in, const int* in_sizes, int n_in,
                              void* d_out, int out_size, void* d_ws,
                              size_t ws_size, hipStream_t stream) {
    const float* x = (const float*)d_in[0];
    const float* W_in = (const float*)d_in[1];
    const float* conv_w = (const float*)d_in[2];
    const float* conv_b = (const float*)d_in[3];
    const float* W_xproj = (const float*)d_in[4];
    const float* W_dt = (const float*)d_in[5];
    const float* b_dt = (const float*)d_in[6];
    const float* A_log = (const float*)d_in[7];
    const float* Dp = (const float*)d_in[8];
    const float* W_out = (const float*)d_in[9];
    float* out = (float*)d_out;

    char* ws = (char*)d_ws;
    const size_t MB = 1u << 20;
    // [0,16M): pp (6.3M, KS=4) -> later aprod(8M)+hend(8M)
    float* pp    = (float*)(ws);
    float* aprod = (float*)(ws);
    float* hend  = (float*)(ws + 8 * MB);
    // [16,32M): xbpre_bf (dead after conv) -> ybf (16 MB)
    unsigned short* xbpre_bf = (unsigned short*)(ws + 16 * MB);  // 16 MB
    unsigned short* ybf      = (unsigned short*)(ws + 16 * MB);  // 16 MB (after conv)
    unsigned short* sz_bf    = (unsigned short*)(ws + 32 * MB);  // 16 MB
    unsigned short* xb_bf    = (unsigned short*)(ws + 48 * MB);  // 16 MB
    unsigned short* dt_bf    = (unsigned short*)(ws + 64 * MB);  // 16 MB
    float* projbuf           = (float*)(ws + 88 * MB);           // 1.5 MB
    unsigned short* dtin_bf  = (unsigned short*)(ws + 90 * MB);  // 0.5 MB
    unsigned short* xbf      = (unsigned short*)(ws + 91 * MB);  // 8 MB
    unsigned short* WinT     = (unsigned short*)(ws + 99 * MB);  // 8 MB
    unsigned short* WoutT    = (unsigned short*)(ws + 107 * MB); // 4 MB
    unsigned short* WxT      = (unsigned short*)(ws + 111 * MB); // 384 KB
    unsigned short* WdtT     = (unsigned short*)(ws + 112 * MB); // 256 KB

    const int M = BSZ * LSEQ; // 4096
    dim3 blk(256);

    // 0. fused prep: x->bf16 + 4 transposes (1 launch)
    prep_kernel<<<dim3(4096 + 4096 + 2048 + 192 + 128), blk, 0, stream>>>(
        x, W_in, W_out, W_xproj, W_dt, xbf, WinT, WoutT, WxT, WdtT);

    // 1. xz = x @ W_in — 256x256 4-phase BK=64 (128 KB dyn LDS)
    gemm256<1, unsigned short><<<dim3((2 * DINNER) / 256, M / 256), dim3(512),
                                 131072, stream>>>(
        xbf, WinT, xbpre_bf, sz_bf, M, 2 * DINNER, DMODEL);

    // 2. conv + silu (sliding window, TT=8); xbpre dead after this
    conv_silu_kernel<<<dim3(M / TT), blk, 0, stream>>>(
        xbpre_bf, conv_w, conv_b, xb_bf);

    // 3. proj (split-K = 4)
    proj_splitk<<<dim3(M / 32, KS), blk, 0, stream>>>(xb_bf, WxT, pp);
    proj_reduce<<<dim3((M * NPROJ) / 256), blk, 0, stream>>>(pp, projbuf, dtin_bf);

    // 4. dt = softplus(dt_in @ W_dt + b_dt) — LDS-free direct MFMA
    dt_gemm<<<dim3(M / 32, DINNER / 128), blk, 0, stream>>>(
        dtin_bf, WdtT, b_dt, dt_bf);

    // 5. scan
    const int nthreads1 = BSZ * NC * DINNER;
    scan_pass1<<<dim3(nthreads1 / 256), blk, 0, stream>>>(
        xb_bf, dt_bf, projbuf, A_log, aprod, hend);
    const int nthreads2 = BSZ * DINNER * DSTATE;
    scan_pass2<<<dim3(nthreads2 / 256), blk, 0, stream>>>(aprod, hend);
    scan_pass3<<<dim3(nthreads1 / 256), blk, 0, stream>>>(
        xb_bf, dt_bf, projbuf, aprod, A_log, Dp, sz_bf, ybf);

    // 6. out = y @ W_out (2-phase 128x128, XCD swizzle)
    gemm_mfma<0, float><<<dim3(DMODEL / 128, M / 128), blk, 0, stream>>>(
        ybf, WoutT, out, M, DMODEL, DINNER);
}

// Round 13
// 259.308 us; speedup vs baseline: 1.2680x; 1.0071x over previous
//
#include <hip/hip_runtime.h>
#include <hip/hip_bf16.h>
#include <math.h>

#define BSZ 2
#define LSEQ 2048
#define DMODEL 1024
#define DSTATE 16
#define DCONV 4
#define DINNER 2048
#define DTRANK 64
#define NPROJ (DTRANK + 2 * DSTATE) // 96
#define NC 32   // scan chunks
#define LC 64   // steps per chunk
#define KS 4    // proj split-K chunks
#define KCH (DINNER / KS) // 512
#define TT 8    // conv timesteps per thread

using short8 = __attribute__((ext_vector_type(8))) short;
using f32x4 = __attribute__((ext_vector_type(4))) float;
using u16x4 = __attribute__((ext_vector_type(4))) unsigned short;

__device__ __forceinline__ float silu_f(float v) {
    return v / (1.f + expf(-v));
}
__device__ __forceinline__ float softplus_f(float v) {
    return fmaxf(v, 0.f) + log1pf(expf(-fabsf(v)));
}
// fp32 -> bf16 bits, round-to-nearest-even
__device__ __forceinline__ unsigned short f2bf(float f) {
    unsigned u = __builtin_bit_cast(unsigned, f);
    u += 0x7fffu + ((u >> 16) & 1u);
    return (unsigned short)(u >> 16);
}
__device__ __forceinline__ float bf2f(unsigned short u) {
    unsigned x = ((unsigned)u) << 16;
    return __builtin_bit_cast(float, x);
}

__device__ __forceinline__ void gld_lds16(const unsigned short* g, unsigned short* l) {
    __builtin_amdgcn_global_load_lds(
        (const __attribute__((address_space(1))) unsigned int*)g,
        (__attribute__((address_space(3))) unsigned int*)l, 16, 0, 0);
}

// bijective XCD swizzle (requires nwg % 8 == 0)
__device__ __forceinline__ int xcd_swz(int wg, int nwg) {
    return (wg & 7) * (nwg >> 3) + (wg >> 3);
}

// ---- fused prep: x->bf16 + 4 weight transposes (fp32 [R][Cc] -> bf16 [Cc][R]) ----
__global__ __launch_bounds__(256) void prep_kernel(
    const float* __restrict__ x, const float* __restrict__ W_in,
    const float* __restrict__ W_out, const float* __restrict__ W_xproj,
    const float* __restrict__ W_dt,
    unsigned short* __restrict__ xbf, unsigned short* __restrict__ WinT,
    unsigned short* __restrict__ WoutT, unsigned short* __restrict__ WxT,
    unsigned short* __restrict__ WdtT) {
    int bid = blockIdx.x;
    if (bid < 4096) { // x -> bf16
        int i = bid * 256 + threadIdx.x;
        float4 v = reinterpret_cast<const float4*>(x)[i];
        u16x4 o = {f2bf(v.x), f2bf(v.y), f2bf(v.z), f2bf(v.w)};
        reinterpret_cast<u16x4*>(xbf)[i] = o;
        return;
    }
    bid -= 4096;
    const float* in;
    unsigned short* outp;
    int R, Cc, gx;
    if (bid < 4096) { in = W_in; outp = WinT; R = 1024; Cc = 4096; gx = 128; }
    else if ((bid -= 4096) < 2048) { in = W_out; outp = WoutT; R = 2048; Cc = 1024; gx = 32; }
    else if ((bid -= 2048) < 192) { in = W_xproj; outp = WxT; R = 2048; Cc = 96; gx = 3; }
    else { bid -= 192; in = W_dt; outp = WdtT; R = 64; Cc = 2048; gx = 64; }
    const int bx = bid % gx, by = bid / gx;
    __shared__ float t[32][33];
    const int tx = threadIdx.x & 31, ty = threadIdx.x >> 5;
    const int c0 = bx * 32, r0 = by * 32;
    for (int i = ty; i < 32; i += 8)
        t[i][tx] = in[(size_t)(r0 + i) * Cc + c0 + tx];
    __syncthreads();
    for (int i = ty; i < 32; i += 8)
        outp[(size_t)(c0 + i) * R + r0 + tx] = f2bf(t[tx][i]);
}

// ===== 256x128 8-wave 2-phase MFMA GEMM (xz) =====
// BM=256, BN=128, 512 thr (8 waves as 4m x 2n, per-wave 64x64), BK=32.
// LDS 48 KB static (2 buf x (A 16KB + B 8KB)) -> 2 blocks/CU at grid 512:
// co-resident block fills this block's barrier stalls (m102 co-residency lever).
// r6-proven 2-phase __syncthreads loop + chunk swizzle (2-way banks, free).
// EPI 1: nn<DINNER -> C, else silu -> C2 (both bf16, ldc=DINNER).
template <int EPI, typename CT>
__global__ __launch_bounds__(512, 4) void gemm_bm256(
    const unsigned short* __restrict__ A, const unsigned short* __restrict__ Bt,
    CT* __restrict__ C, CT* __restrict__ C2, int M, int N, int K) {
    __shared__ __align__(16) unsigned short As[2][8192]; // 256 rows x 32
    __shared__ __align__(16) unsigned short Bs[2][4096]; // 128 rows x 32
    const int tid = threadIdx.x;
    const int lane = tid & 63;
    const int w8 = tid >> 6;
    const int wm = w8 >> 1, wn = w8 & 1;
    const int nwg = gridDim.x * gridDim.y;
    const int wg = xcd_swz(blockIdx.y * gridDim.x + blockIdx.x, nwg);
    const int m0 = (wg / gridDim.x) * 256, n0 = (wg % gridDim.x) * 128;
    const int fr = lane & 15, kg = lane >> 4;
    const int kswz = ((kg ^ ((fr >> 1) & 3)) << 3);
    const int r0 = tid >> 2;              // 0..127 (4 thr/row)
    const int d0 = tid * 8;
    const int cs8 = (((tid & 3) ^ ((tid >> 3) & 3)) << 3);
    const int nt = K / 32;

    f32x4 acc[4][4];
#pragma unroll
    for (int m = 0; m < 4; m++)
#pragma unroll
        for (int n = 0; n < 4; n++) acc[m][n] = (f32x4){0.f, 0.f, 0.f, 0.f};

#define STAGE(buf, k0)                                                           \
    {                                                                            \
        gld_lds16(&A[(size_t)(m0 + r0) * K + (k0) + cs8], &As[buf][d0]);         \
        gld_lds16(&A[(size_t)(m0 + 128 + r0) * K + (k0) + cs8],                  \
                  &As[buf][d0 + 4096]);                                          \
        gld_lds16(&Bt[(size_t)(n0 + r0) * K + (k0) + cs8], &Bs[buf][d0]);        \
    }

    STAGE(0, 0);
    __syncthreads();

    int cur = 0;
    for (int t = 0; t < nt; t++) {
        if (t + 1 < nt) STAGE(cur ^ 1, (t + 1) * 32);
        short8 a[4], b[4];
#pragma unroll
        for (int m = 0; m < 4; m++)
            a[m] = *reinterpret_cast<const short8*>(
                &As[cur][(wm * 64 + m * 16 + fr) * 32 + kswz]);
#pragma unroll
        for (int n = 0; n < 4; n++)
            b[n] = *reinterpret_cast<const short8*>(
                &Bs[cur][(wn * 64 + n * 16 + fr) * 32 + kswz]);
#pragma unroll
        for (int m = 0; m < 4; m++)
#pragma unroll
            for (int n = 0; n < 4; n++)
                acc[m][n] = __builtin_amdgcn_mfma_f32_16x16x32_bf16(
                    a[m], b[n], acc[m][n], 0, 0, 0);
        __syncthreads(); // reads of cur done everywhere + prefetch landed
        cur ^= 1;
    }
#undef STAGE

    const int g4 = kg * 4;
#pragma unroll
    for (int m = 0; m < 4; m++)
#pragma unroll
        for (int n = 0; n < 4; n++)
#pragma unroll
            for (int j = 0; j < 4; j++) {
                int mm = m0 + wm * 64 + m * 16 + g4 + j;
                int nn = n0 + wn * 64 + n * 16 + fr;
                float v = acc[m][n][j];
                if (EPI == 1) {
                    if (nn < DINNER)
                        C[(size_t)mm * DINNER + nn] = f2bf(v);
                    else
                        C2[(size_t)mm * DINNER + (nn - DINNER)] = f2bf(silu_f(v));
                } else {
                    if constexpr (sizeof(CT) == 2)
                        C[(size_t)mm * N + nn] = f2bf(v);
                    else
                        C[(size_t)mm * N + nn] = v;
                }
            }
}

// ---- 128x128 2-phase MFMA GEMM (out) ----
template <int EPI, typename CT>
__global__ __launch_bounds__(256) void gemm_mfma(
    const unsigned short* __restrict__ A, const unsigned short* __restrict__ Bt,
    CT* __restrict__ C, int M, int N, int K) {
    __shared__ __align__(16) unsigned short As[2][4096];
    __shared__ __align__(16) unsigned short Bs[2][4096];
    const int tid = threadIdx.x;
    const int lane = tid & 63;
    const int wid = tid >> 6;
    const int wr = wid >> 1, wc = wid & 1;
    const int nwg = gridDim.x * gridDim.y;
    const int wg = xcd_swz(blockIdx.y * gridDim.x + blockIdx.x, nwg);
    const int m0 = (wg / gridDim.x) * 128, n0 = (wg % gridDim.x) * 128;

    const int r0 = tid >> 2;
    const int r1 = r0 + 64;
    const int d0 = tid * 8;
    const int d1 = d0 + 2048;
    const int cs8 = (((tid & 3) ^ ((tid >> 3) & 3)) << 3);

    f32x4 acc[4][4];
#pragma unroll
    for (int m = 0; m < 4; m++)
#pragma unroll
        for (int n = 0; n < 4; n++) acc[m][n] = (f32x4){0.f, 0.f, 0.f, 0.f};

    const int fr = lane & 15;
    const int kg = lane >> 4;
    const int kswz = ((kg ^ ((fr >> 1) & 3)) << 3);
    const int nt = K / 32;

    gld_lds16(&A[(size_t)(m0 + r0) * K + cs8], &As[0][d0]);
    gld_lds16(&A[(size_t)(m0 + r1) * K + cs8], &As[0][d1]);
    gld_lds16(&Bt[(size_t)(n0 + r0) * K + cs8], &Bs[0][d0]);
    gld_lds16(&Bt[(size_t)(n0 + r1) * K + cs8], &Bs[0][d1]);
    __syncthreads();

    int cur = 0;
    for (int t = 0; t < nt; t++) {
        if (t + 1 < nt) {
            const int k0 = (t + 1) * 32;
            gld_lds16(&A[(size_t)(m0 + r0) * K + k0 + cs8], &As[cur ^ 1][d0]);
            gld_lds16(&A[(size_t)(m0 + r1) * K + k0 + cs8], &As[cur ^ 1][d1]);
            gld_lds16(&Bt[(size_t)(n0 + r0) * K + k0 + cs8], &Bs[cur ^ 1][d0]);
            gld_lds16(&Bt[(size_t)(n0 + r1) * K + k0 + cs8], &Bs[cur ^ 1][d1]);
        }
        short8 a[4], b[4];
#pragma unroll
        for (int m = 0; m < 4; m++)
            a[m] = *reinterpret_cast<const short8*>(
                &As[cur][(wr * 64 + m * 16 + fr) * 32 + kswz]);
#pragma unroll
        for (int n = 0; n < 4; n++)
            b[n] = *reinterpret_cast<const short8*>(
                &Bs[cur][(wc * 64 + n * 16 + fr) * 32 + kswz]);
#pragma unroll
        for (int m = 0; m < 4; m++)
#pragma unroll
            for (int n = 0; n < 4; n++)
                acc[m][n] = __builtin_amdgcn_mfma_f32_16x16x32_bf16(
                    a[m], b[n], acc[m][n], 0, 0, 0);
        __syncthreads();
        cur ^= 1;
    }

    const int g4 = (lane >> 4) * 4;
#pragma unroll
    for (int m = 0; m < 4; m++)
#pragma unroll
        for (int n = 0; n < 4; n++)
#pragma unroll
            for (int j = 0; j < 4; j++) {
                int mm = m0 + wr * 64 + m * 16 + g4 + j;
                int nn = n0 + wc * 64 + n * 16 + fr;
                float v = acc[m][n][j];
                if constexpr (sizeof(CT) == 2)
                    C[(size_t)mm * N + nn] = f2bf(v);
                else
                    C[(size_t)mm * N + nn] = v;
            }
}

// ---- dt: LDS-free direct MFMA, K=64 ----
__global__ __launch_bounds__(256) void dt_gemm(
    const unsigned short* __restrict__ dtin,  // [M][64]
    const unsigned short* __restrict__ WdtT,  // [DINNER][64]
    const float* __restrict__ bias,
    unsigned short* __restrict__ dtout) {     // [M][DINNER]
    const int lane = threadIdx.x & 63;
    const int wid = threadIdx.x >> 6;
    const int mt = wid >> 1, nh = wid & 1;
    const int m0 = blockIdx.x * 32;
    const int n0 = blockIdx.y * 128 + nh * 64;
    const int fr = lane & 15, kg = lane >> 4;

    f32x4 acc[4];
#pragma unroll
    for (int i = 0; i < 4; i++) acc[i] = (f32x4){0.f, 0.f, 0.f, 0.f};

#pragma unroll
    for (int step = 0; step < 2; step++) {
        short8 a = *reinterpret_cast<const short8*>(
            &dtin[(size_t)(m0 + mt * 16 + fr) * DTRANK + step * 32 + kg * 8]);
#pragma unroll
        for (int nt = 0; nt < 4; nt++) {
            short8 b = *reinterpret_cast<const short8*>(
                &WdtT[(size_t)(n0 + nt * 16 + fr) * DTRANK + step * 32 + kg * 8]);
            acc[nt] = __builtin_amdgcn_mfma_f32_16x16x32_bf16(a, b, acc[nt], 0, 0, 0);
        }
    }
    const int g4 = kg * 4;
#pragma unroll
    for (int nt = 0; nt < 4; nt++)
#pragma unroll
        for (int j = 0; j < 4; j++) {
            int m = m0 + mt * 16 + g4 + j;
            int n = n0 + nt * 16 + fr;
            dtout[(size_t)m * DINNER + n] = f2bf(softplus_f(acc[nt][j] + bias[n]));
        }
}

// ---- proj split-K MFMA: pp[kc][M][96] partial of xb_bf @ WxT^T ----
__global__ __launch_bounds__(256) void proj_splitk(
    const unsigned short* __restrict__ Abf,
    const unsigned short* __restrict__ WxT,
    float* __restrict__ pp) {
    const int lane = threadIdx.x & 63;
    const int wid = threadIdx.x >> 6;
    const int mt = wid >> 1;
    const int nh = wid & 1;
    const int m0 = blockIdx.x * 32;
    const int kc = blockIdx.y;
    const int fr = lane & 15;
    const int kg = lane >> 4;

    const size_t abase = (size_t)(m0 + mt * 16 + fr) * DINNER + kc * KCH + kg * 8;

    f32x4 acc[3];
#pragma unroll
    for (int i = 0; i < 3; i++) acc[i] = (f32x4){0.f, 0.f, 0.f, 0.f};

    for (int step = 0; step < KCH / 32; step++) {
        short8 a = *reinterpret_cast<const short8*>(&Abf[abase + step * 32]);
#pragma unroll
        for (int nt = 0; nt < 3; nt++) {
            int nrow = nh * 48 + nt * 16 + fr;
            short8 b = *reinterpret_cast<const short8*>(
                &WxT[(size_t)nrow * DINNER + kc * KCH + step * 32 + kg * 8]);
            acc[nt] = __builtin_amdgcn_mfma_f32_16x16x32_bf16(a, b, acc[nt], 0, 0, 0);
        }
    }
    const int g4 = (lane >> 4) * 4;
#pragma unroll
    for (int nt = 0; nt < 3; nt++)
#pragma unroll
        for (int j = 0; j < 4; j++) {
            int m = m0 + mt * 16 + g4 + j;
            int n = nh * 48 + nt * 16 + fr;
            pp[((size_t)kc * (BSZ * LSEQ) + m) * NPROJ + n] = acc[nt][j];
        }
}

// reduce split-K partials; emit fp32 proj + bf16 dt_in (cols < DTRANK)
__global__ __launch_bounds__(256) void proj_reduce(
    const float* __restrict__ pp, float* __restrict__ proj,
    unsigned short* __restrict__ dtin) {
    int i = blockIdx.x * 256 + threadIdx.x;
    if (i >= BSZ * LSEQ * NPROJ) return;
    float s = 0.f;
#pragma unroll
    for (int kc = 0; kc < KS; kc++)
        s += pp[(size_t)kc * BSZ * LSEQ * NPROJ + i];
    proj[i] = s;
    int m = i / NPROJ;
    int n = i - m * NPROJ;
    if (n < DTRANK) dtin[(size_t)m * DTRANK + n] = f2bf(s);
}

// ---- causal depthwise conv (k=4) + bias + silu — sliding window ----
__global__ __launch_bounds__(256) void conv_silu_kernel(
    const unsigned short* __restrict__ xin, const float* __restrict__ w,
    const float* __restrict__ bconv, unsigned short* __restrict__ xout) {
    const int tid = threadIdx.x;
    const int d0 = tid * 8;
    const int bt0 = blockIdx.x * TT;
    const int tloc = bt0 & (LSEQ - 1);

    float wk0[8], wk1[8], wk2[8], wk3[8], bb[8];
#pragma unroll
    for (int q = 0; q < 8; q++) {
        float4 wv = *reinterpret_cast<const float4*>(&w[(d0 + q) * 4]);
        wk0[q] = wv.x; wk1[q] = wv.y; wk2[q] = wv.z; wk3[q] = wv.w;
    }
    {
        float4 b0 = *reinterpret_cast<const float4*>(&bconv[d0]);
        float4 b1 = *reinterpret_cast<const float4*>(&bconv[d0 + 4]);
        bb[0] = b0.x; bb[1] = b0.y; bb[2] = b0.z; bb[3] = b0.w;
        bb[4] = b1.x; bb[5] = b1.y; bb[6] = b1.z; bb[7] = b1.w;
    }

    float xm3[8], xm2[8], xm1[8];
    if (tloc >= 3) {
        short8 v3 = *reinterpret_cast<const short8*>(&xin[(size_t)(bt0 - 3) * DINNER + d0]);
        short8 v2 = *reinterpret_cast<const short8*>(&xin[(size_t)(bt0 - 2) * DINNER + d0]);
        short8 v1 = *reinterpret_cast<const short8*>(&xin[(size_t)(bt0 - 1) * DINNER + d0]);
#pragma unroll
        for (int q = 0; q < 8; q++) {
            xm3[q] = bf2f((unsigned short)v3[q]);
            xm2[q] = bf2f((unsigned short)v2[q]);
            xm1[q] = bf2f((unsigned short)v1[q]);
        }
    } else {
#pragma unroll
        for (int q = 0; q < 8; q++) { xm3[q] = 0.f; xm2[q] = 0.f; xm1[q] = 0.f; }
    }

#pragma unroll
    for (int i = 0; i < TT; i++) {
        short8 vc = *reinterpret_cast<const short8*>(&xin[(size_t)(bt0 + i) * DINNER + d0]);
        float xc[8];
        short8 o;
#pragma unroll
        for (int q = 0; q < 8; q++) {
            xc[q] = bf2f((unsigned short)vc[q]);
            float a = bb[q];
            a = fmaf(wk0[q], xm3[q], a);
            a = fmaf(wk1[q], xm2[q], a);
            a = fmaf(wk2[q], xm1[q], a);
            a = fmaf(wk3[q], xc[q], a);
            o[q] = (short)f2bf(silu_f(a));
        }
        *reinterpret_cast<short8*>(&xout[(size_t)(bt0 + i) * DINNER + d0]) = o;
#pragma unroll
        for (int q = 0; q < 8; q++) { xm3[q] = xm2[q]; xm2[q] = xm1[q]; xm1[q] = xc[q]; }
    }
}

// ---- chunked selective scan (bf16 operands, fp32 state) ----
// B/C rows pulled from LDS per step as float4 quads into registers
// (static-indexed after unroll) -> 4x ds_read_b128 broadcast, not 16x b32.
__global__ __launch_bounds__(256) void scan_pass1(
    const unsigned short* __restrict__ xb, const unsigned short* __restrict__ dt,
    const float* __restrict__ proj, const float* __restrict__ A_log,
    float* __restrict__ aprod, float* __restrict__ hend) {
    __shared__ __align__(16) float Bsh[LC][DSTATE];
    const int tg = blockIdx.x * 256 + threadIdx.x;
    const int d = tg & (DINNER - 1);
    const int bc = tg >> 11;
    const int c = bc & (NC - 1);
    const int b = bc >> 5;

    for (int idx = threadIdx.x; idx < LC * DSTATE; idx += 256) {
        int ti = idx >> 4, j = idx & 15;
        Bsh[ti][j] = proj[(size_t)(b * LSEQ + c * LC + ti) * NPROJ + DTRANK + j];
    }
    __syncthreads();

    float Av[DSTATE], h[DSTATE], ap[DSTATE];
#pragma unroll
    for (int s = 0; s < DSTATE; s++) {
        Av[s] = -expf(A_log[d * DSTATE + s]);
        h[s] = 0.f;
        ap[s] = 1.f;
    }

    for (int i = 0; i < LC; i++) {
        size_t base = (size_t)(b * LSEQ + c * LC + i) * DINNER + d;
        float dtv = bf2f(dt[base]);
        float xv = bf2f(xb[base]);
        float dx = dtv * xv;
        float Bv[DSTATE];
        *reinterpret_cast<float4*>(&Bv[0])  = *reinterpret_cast<const float4*>(&Bsh[i][0]);
        *reinterpret_cast<float4*>(&Bv[4])  = *reinterpret_cast<const float4*>(&Bsh[i][4]);
        *reinterpret_cast<float4*>(&Bv[8])  = *reinterpret_cast<const float4*>(&Bsh[i][8]);
        *reinterpret_cast<float4*>(&Bv[12]) = *reinterpret_cast<const float4*>(&Bsh[i][12]);
#pragma unroll
        for (int s = 0; s < DSTATE; s++) {
            float dA = __expf(dtv * Av[s]);
            ap[s] *= dA;
            h[s] = fmaf(dA, h[s], dx * Bv[s]);
        }
    }

    size_t o = ((size_t)bc * DINNER + d) * DSTATE;
#pragma unroll
    for (int q = 0; q < 4; q++) {
        *reinterpret_cast<float4*>(&aprod[o + q * 4]) =
            make_float4(ap[4 * q], ap[4 * q + 1], ap[4 * q + 2], ap[4 * q + 3]);
        *reinterpret_cast<float4*>(&hend[o + q * 4]) =
            make_float4(h[4 * q], h[4 * q + 1], h[4 * q + 2], h[4 * q + 3]);
    }
}

__global__ __launch_bounds__(256) void scan_pass2(
    float* __restrict__ aprod, const float* __restrict__ hend) {
    const int tg = blockIdx.x * 256 + threadIdx.x;
    const int s = tg & (DSTATE - 1);
    const int d = (tg >> 4) & (DINNER - 1);
    const int b = tg >> 15;
    float h = 0.f;
    for (int c = 0; c < NC; c++) {
        size_t o = ((size_t)((b * NC + c) * DINNER) + d) * DSTATE + s;
        float a = aprod[o];
        float e = hend[o];
        aprod[o] = h;
        h = fmaf(a, h, e);
    }
}

__global__ __launch_bounds__(256) void scan_pass3(
    const unsigned short* __restrict__ xb, const unsigned short* __restrict__ dt,
    const float* __restrict__ proj, const float* __restrict__ hstart,
    const float* __restrict__ A_log, const float* __restrict__ Dp,
    const unsigned short* __restrict__ sz, unsigned short* __restrict__ ybf) {
    __shared__ __align__(16) float Bsh[LC][DSTATE];
    __shared__ __align__(16) float Csh[LC][DSTATE];
    const int tg = blockIdx.x * 256 + threadIdx.x;
    const int d = tg & (DINNER - 1);
    const int bc = tg >> 11;
    const int c = bc & (NC - 1);
    const int b = bc >> 5;

    for (int idx = threadIdx.x; idx < LC * 2 * DSTATE; idx += 256) {
        int ti = idx >> 5, j = idx & 31;
        float v = proj[(size_t)(b * LSEQ + c * LC + ti) * NPROJ + DTRANK + j];
        if (j < DSTATE) Bsh[ti][j] = v;
        else            Csh[ti][j - DSTATE] = v;
    }
    __syncthreads();

    float Av[DSTATE], h[DSTATE];
    size_t o = ((size_t)bc * DINNER + d) * DSTATE;
#pragma unroll
    for (int q = 0; q < 4; q++) {
        float4 hv = *reinterpret_cast<const float4*>(&hstart[o + q * 4]);
        h[4 * q] = hv.x; h[4 * q + 1] = hv.y; h[4 * q + 2] = hv.z; h[4 * q + 3] = hv.w;
    }
#pragma unroll
    for (int s = 0; s < DSTATE; s++)
        Av[s] = -expf(A_log[d * DSTATE + s]);
    const float Dd = Dp[d];

    for (int i = 0; i < LC; i++) {
        size_t base = (size_t)(b * LSEQ + c * LC + i) * DINNER + d;
        float dtv = bf2f(dt[base]);
        float xv = bf2f(xb[base]);
        float szv = bf2f(sz[base]);
        float dx = dtv * xv;
        float Bv[DSTATE], Cv[DSTATE];
        *reinterpret_cast<float4*>(&Bv[0])  = *reinterpret_cast<const float4*>(&Bsh[i][0]);
        *reinterpret_cast<float4*>(&Bv[4])  = *reinterpret_cast<const float4*>(&Bsh[i][4]);
        *reinterpret_cast<float4*>(&Bv[8])  = *reinterpret_cast<const float4*>(&Bsh[i][8]);
        *reinterpret_cast<float4*>(&Bv[12]) = *reinterpret_cast<const float4*>(&Bsh[i][12]);
        *reinterpret_cast<float4*>(&Cv[0])  = *reinterpret_cast<const float4*>(&Csh[i][0]);
        *reinterpret_cast<float4*>(&Cv[4])  = *reinterpret_cast<const float4*>(&Csh[i][4]);
        *reinterpret_cast<float4*>(&Cv[8])  = *reinterpret_cast<const float4*>(&Csh[i][8]);
        *reinterpret_cast<float4*>(&Cv[12]) = *reinterpret_cast<const float4*>(&Csh[i][12]);
        float p = 0.f;
#pragma unroll
        for (int s = 0; s < DSTATE; s++) {
            float dA = __expf(dtv * Av[s]);
            h[s] = fmaf(dA, h[s], dx * Bv[s]);
            p = fmaf(h[s], Cv[s], p);
        }
        ybf[base] = f2bf((p + Dd * xv) * szv);
    }
}

extern "C" void kernel_launch(void* const* d_in, const int* in_sizes, int n_in,
                              void* d_out, int out_size, void* d_ws,
                              size_t ws_size, hipStream_t stream) {
    const float* x = (const float*)d_in[0];
    const float* W_in = (const float*)d_in[1];
    const float* conv_w = (const float*)d_in[2];
    const float* conv_b = (const float*)d_in[3];
    const float* W_xproj = (const float*)d_in[4];
    const float* W_dt = (const float*)d_in[5];
    const float* b_dt = (const float*)d_in[6];
    const float* A_log = (const float*)d_in[7];
    const float* Dp = (const float*)d_in[8];
    const float* W_out = (const float*)d_in[9];
    float* out = (float*)d_out;

    char* ws = (char*)d_ws;
    const size_t MB = 1u << 20;
    // [0,16M): pp (6.3M, KS=4) -> later aprod(8M)+hend(8M)
    float* pp    = (float*)(ws);
    float* aprod = (float*)(ws);
    float* hend  = (float*)(ws + 8 * MB);
    // [16,32M): xbpre_bf (dead after conv) -> ybf (16 MB)
    unsigned short* xbpre_bf = (unsigned short*)(ws + 16 * MB);  // 16 MB
    unsigned short* ybf      = (unsigned short*)(ws + 16 * MB);  // 16 MB (after conv)
    unsigned short* sz_bf    = (unsigned short*)(ws + 32 * MB);  // 16 MB
    unsigned short* xb_bf    = (unsigned short*)(ws + 48 * MB);  // 16 MB
    unsigned short* dt_bf    = (unsigned short*)(ws + 64 * MB);  // 16 MB
    float* projbuf           = (float*)(ws + 88 * MB);           // 1.5 MB
    unsigned short* dtin_bf  = (unsigned short*)(ws + 90 * MB);  // 0.5 MB
    unsigned short* xbf      = (unsigned short*)(ws + 91 * MB);  // 8 MB
    unsigned short* WinT     = (unsigned short*)(ws + 99 * MB);  // 8 MB
    unsigned short* WoutT    = (unsigned short*)(ws + 107 * MB); // 4 MB
    unsigned short* WxT      = (unsigned short*)(ws + 111 * MB); // 384 KB
    unsigned short* WdtT     = (unsigned short*)(ws + 112 * MB); // 256 KB

    const int M = BSZ * LSEQ; // 4096
    dim3 blk(256);

    // 0. fused prep: x->bf16 + 4 transposes (1 launch)
    prep_kernel<<<dim3(4096 + 4096 + 2048 + 192 + 128), blk, 0, stream>>>(
        x, W_in, W_out, W_xproj, W_dt, xbf, WinT, WoutT, WxT, WdtT);

    // 1. xz = x @ W_in — 256x128 tile, 512 blocks -> 2 blocks/CU
    gemm_bm256<1, unsigned short><<<dim3((2 * DINNER) / 128, M / 256), dim3(512),
                                    0, stream>>>(
        xbf, WinT, xbpre_bf, sz_bf, M, 2 * DINNER, DMODEL);

    // 2. conv + silu (sliding window, TT=8); xbpre dead after this
    conv_silu_kernel<<<dim3(M / TT), blk, 0, stream>>>(
        xbpre_bf, conv_w, conv_b, xb_bf);

    // 3. proj (split-K = 4)
    proj_splitk<<<dim3(M / 32, KS), blk, 0, stream>>>(xb_bf, WxT, pp);
    proj_reduce<<<dim3((M * NPROJ) / 256), blk, 0, stream>>>(pp, projbuf, dtin_bf);

    // 4. dt = softplus(dt_in @ W_dt + b_dt) — LDS-free direct MFMA
    dt_gemm<<<dim3(M / 32, DINNER / 128), blk, 0, stream>>>(
        dtin_bf, WdtT, b_dt, dt_bf);

    // 5. scan
    const int nthreads1 = BSZ * NC * DINNER;
    scan_pass1<<<dim3(nthreads1 / 256), blk, 0, stream>>>(
        xb_bf, dt_bf, projbuf, A_log, aprod, hend);
    const int nthreads2 = BSZ * DINNER * DSTATE;
    scan_pass2<<<dim3(nthreads2 / 256), blk, 0, stream>>>(aprod, hend);
    scan_pass3<<<dim3(nthreads1 / 256), blk, 0, stream>>>(
        xb_bf, dt_bf, projbuf, aprod, A_log, Dp, sz_bf, ybf);

    // 6. out = y @ W_out (2-phase 128x128, XCD swizzle)
    gemm_mfma<0, float><<<dim3(DMODEL / 128, M / 128), blk, 0, stream>>>(
        ybf, WoutT, out, M, DMODEL, DINNER);
}

// Round 14
// 253.156 us; speedup vs baseline: 1.2989x; 1.0243x over previous
//
#include <hip/hip_runtime.h>
#include <hip/hip_bf16.h>
#include <math.h>

#define BSZ 2
#define LSEQ 2048
#define DMODEL 1024
#define DSTATE 16
#define DCONV 4
#define DINNER 2048
#define DTRANK 64
#define NPROJ (DTRANK + 2 * DSTATE) // 96
#define NC 32   // scan chunks
#define LC 64   // steps per chunk
#define KS 4    // proj split-K chunks
#define KCH (DINNER / KS) // 512
#define TT 8    // conv timesteps per thread

using short8 = __attribute__((ext_vector_type(8))) short;
using f32x4 = __attribute__((ext_vector_type(4))) float;
using u16x4 = __attribute__((ext_vector_type(4))) unsigned short;

__device__ __forceinline__ float silu_f(float v) {
    return v / (1.f + expf(-v));
}
__device__ __forceinline__ float softplus_f(float v) {
    return fmaxf(v, 0.f) + log1pf(expf(-fabsf(v)));
}
// fp32 -> bf16 bits, round-to-nearest-even
__device__ __forceinline__ unsigned short f2bf(float f) {
    unsigned u = __builtin_bit_cast(unsigned, f);
    u += 0x7fffu + ((u >> 16) & 1u);
    return (unsigned short)(u >> 16);
}
__device__ __forceinline__ float bf2f(unsigned short u) {
    unsigned x = ((unsigned)u) << 16;
    return __builtin_bit_cast(float, x);
}

__device__ __forceinline__ void gld_lds16(const unsigned short* g, unsigned short* l) {
    __builtin_amdgcn_global_load_lds(
        (const __attribute__((address_space(1))) unsigned int*)g,
        (__attribute__((address_space(3))) unsigned int*)l, 16, 0, 0);
}

// bijective XCD swizzle (requires nwg % 8 == 0)
__device__ __forceinline__ int xcd_swz(int wg, int nwg) {
    return (wg & 7) * (nwg >> 3) + (wg >> 3);
}

// ---- fused prep: x->bf16 + weight transposes ----
// W_in / W_out use 64x64 tiles (128B write segments); W_xproj / W_dt 32x32.
__global__ __launch_bounds__(256) void prep_kernel(
    const float* __restrict__ x, const float* __restrict__ W_in,
    const float* __restrict__ W_out, const float* __restrict__ W_xproj,
    const float* __restrict__ W_dt,
    unsigned short* __restrict__ xbf, unsigned short* __restrict__ WinT,
    unsigned short* __restrict__ WoutT, unsigned short* __restrict__ WxT,
    unsigned short* __restrict__ WdtT) {
    int bid = blockIdx.x;
    if (bid < 4096) { // x -> bf16
        int i = bid * 256 + threadIdx.x;
        float4 v = reinterpret_cast<const float4*>(x)[i];
        u16x4 o = {f2bf(v.x), f2bf(v.y), f2bf(v.z), f2bf(v.w)};
        reinterpret_cast<u16x4*>(xbf)[i] = o;
        return;
    }
    bid -= 4096;
    if (bid < 1024 + 512) { // 64x64 transposes: W_in (1024 blocks), W_out (512)
        const float* in;
        unsigned short* outp;
        int R, Cc, gx;
        if (bid < 1024) { in = W_in; outp = WinT; R = 1024; Cc = 4096; gx = 64; }
        else { bid -= 1024; in = W_out; outp = WoutT; R = 2048; Cc = 1024; gx = 16; }
        const int bx = bid % gx, by = bid / gx;
        __shared__ float t64[64][65];
        const int tx = threadIdx.x & 63, ty = threadIdx.x >> 6; // 64 x 4
        const int c0 = bx * 64, r0 = by * 64;
#pragma unroll
        for (int i = 0; i < 16; i++)
            t64[ty + 4 * i][tx] = in[(size_t)(r0 + ty + 4 * i) * Cc + c0 + tx];
        __syncthreads();
#pragma unroll
        for (int i = 0; i < 16; i++) {
            int rr = ty + 4 * i;
            outp[(size_t)(c0 + rr) * R + r0 + tx] = f2bf(t64[tx][rr]);
        }
        return;
    }
    bid -= 1536;
    const float* in;
    unsigned short* outp;
    int R, Cc, gx;
    if (bid < 192) { in = W_xproj; outp = WxT; R = 2048; Cc = 96; gx = 3; }
    else { bid -= 192; in = W_dt; outp = WdtT; R = 64; Cc = 2048; gx = 64; }
    const int bx = bid % gx, by = bid / gx;
    __shared__ float t[32][33];
    const int tx = threadIdx.x & 31, ty = threadIdx.x >> 5;
    const int c0 = bx * 32, r0 = by * 32;
    for (int i = ty; i < 32; i += 8)
        t[i][tx] = in[(size_t)(r0 + i) * Cc + c0 + tx];
    __syncthreads();
    for (int i = ty; i < 32; i += 8)
        outp[(size_t)(c0 + i) * R + r0 + tx] = f2bf(t[tx][i]);
}

// ===== 256x128 8-wave 2-phase MFMA GEMM (xz) — r13-proven =====
template <int EPI, typename CT>
__global__ __launch_bounds__(512, 4) void gemm_bm256(
    const unsigned short* __restrict__ A, const unsigned short* __restrict__ Bt,
    CT* __restrict__ C, CT* __restrict__ C2, int M, int N, int K) {
    __shared__ __align__(16) unsigned short As[2][8192]; // 256 rows x 32
    __shared__ __align__(16) unsigned short Bs[2][4096]; // 128 rows x 32
    const int tid = threadIdx.x;
    const int lane = tid & 63;
    const int w8 = tid >> 6;
    const int wm = w8 >> 1, wn = w8 & 1;
    const int nwg = gridDim.x * gridDim.y;
    const int wg = xcd_swz(blockIdx.y * gridDim.x + blockIdx.x, nwg);
    const int m0 = (wg / gridDim.x) * 256, n0 = (wg % gridDim.x) * 128;
    const int fr = lane & 15, kg = lane >> 4;
    const int kswz = ((kg ^ ((fr >> 1) & 3)) << 3);
    const int r0 = tid >> 2;
    const int d0 = tid * 8;
    const int cs8 = (((tid & 3) ^ ((tid >> 3) & 3)) << 3);
    const int nt = K / 32;

    f32x4 acc[4][4];
#pragma unroll
    for (int m = 0; m < 4; m++)
#pragma unroll
        for (int n = 0; n < 4; n++) acc[m][n] = (f32x4){0.f, 0.f, 0.f, 0.f};

#define STAGE(buf, k0)                                                           \
    {                                                                            \
        gld_lds16(&A[(size_t)(m0 + r0) * K + (k0) + cs8], &As[buf][d0]);         \
        gld_lds16(&A[(size_t)(m0 + 128 + r0) * K + (k0) + cs8],                  \
                  &As[buf][d0 + 4096]);                                          \
        gld_lds16(&Bt[(size_t)(n0 + r0) * K + (k0) + cs8], &Bs[buf][d0]);        \
    }

    STAGE(0, 0);
    __syncthreads();

    int cur = 0;
    for (int t = 0; t < nt; t++) {
        if (t + 1 < nt) STAGE(cur ^ 1, (t + 1) * 32);
        short8 a[4], b[4];
#pragma unroll
        for (int m = 0; m < 4; m++)
            a[m] = *reinterpret_cast<const short8*>(
                &As[cur][(wm * 64 + m * 16 + fr) * 32 + kswz]);
#pragma unroll
        for (int n = 0; n < 4; n++)
            b[n] = *reinterpret_cast<const short8*>(
                &Bs[cur][(wn * 64 + n * 16 + fr) * 32 + kswz]);
#pragma unroll
        for (int m = 0; m < 4; m++)
#pragma unroll
            for (int n = 0; n < 4; n++)
                acc[m][n] = __builtin_amdgcn_mfma_f32_16x16x32_bf16(
                    a[m], b[n], acc[m][n], 0, 0, 0);
        __syncthreads();
        cur ^= 1;
    }
#undef STAGE

    const int g4 = kg * 4;
#pragma unroll
    for (int m = 0; m < 4; m++)
#pragma unroll
        for (int n = 0; n < 4; n++)
#pragma unroll
            for (int j = 0; j < 4; j++) {
                int mm = m0 + wm * 64 + m * 16 + g4 + j;
                int nn = n0 + wn * 64 + n * 16 + fr;
                float v = acc[m][n][j];
                if (EPI == 1) {
                    if (nn < DINNER)
                        C[(size_t)mm * DINNER + nn] = f2bf(v);
                    else
                        C2[(size_t)mm * DINNER + (nn - DINNER)] = f2bf(silu_f(v));
                } else {
                    if constexpr (sizeof(CT) == 2)
                        C[(size_t)mm * N + nn] = f2bf(v);
                    else
                        C[(size_t)mm * N + nn] = v;
                }
            }
}

// ---- 128xBN 2-phase MFMA GEMM (out; BN=64 -> 512 blocks, 2/CU) ----
template <int BN, typename CT>
__global__ __launch_bounds__(256) void gemm_mfma(
    const unsigned short* __restrict__ A, const unsigned short* __restrict__ Bt,
    CT* __restrict__ C, int M, int N, int K) {
    constexpr int NF = BN / 32;
    __shared__ __align__(16) unsigned short As[2][4096];
    __shared__ __align__(16) unsigned short Bs[2][BN * 32];
    const int tid = threadIdx.x;
    const int lane = tid & 63;
    const int wid = tid >> 6;
    const int wr = wid >> 1, wc = wid & 1;
    const int nwg = gridDim.x * gridDim.y;
    const int wg = xcd_swz(blockIdx.y * gridDim.x + blockIdx.x, nwg);
    const int m0 = (wg / gridDim.x) * 128, n0 = (wg % gridDim.x) * BN;

    const int r0 = tid >> 2;
    const int r1 = r0 + 64;
    const int d0 = tid * 8;
    const int d1 = d0 + 2048;
    const int cs8 = (((tid & 3) ^ ((tid >> 3) & 3)) << 3);

    f32x4 acc[4][NF];
#pragma unroll
    for (int m = 0; m < 4; m++)
#pragma unroll
        for (int n = 0; n < NF; n++) acc[m][n] = (f32x4){0.f, 0.f, 0.f, 0.f};

    const int fr = lane & 15;
    const int kg = lane >> 4;
    const int kswz = ((kg ^ ((fr >> 1) & 3)) << 3);
    const int nt = K / 32;

    gld_lds16(&A[(size_t)(m0 + r0) * K + cs8], &As[0][d0]);
    gld_lds16(&A[(size_t)(m0 + r1) * K + cs8], &As[0][d1]);
    gld_lds16(&Bt[(size_t)(n0 + r0) * K + cs8], &Bs[0][d0]);
    if constexpr (BN == 128)
        gld_lds16(&Bt[(size_t)(n0 + r1) * K + cs8], &Bs[0][d1]);
    __syncthreads();

    int cur = 0;
    for (int t = 0; t < nt; t++) {
        if (t + 1 < nt) {
            const int k0 = (t + 1) * 32;
            gld_lds16(&A[(size_t)(m0 + r0) * K + k0 + cs8], &As[cur ^ 1][d0]);
            gld_lds16(&A[(size_t)(m0 + r1) * K + k0 + cs8], &As[cur ^ 1][d1]);
            gld_lds16(&Bt[(size_t)(n0 + r0) * K + k0 + cs8], &Bs[cur ^ 1][d0]);
            if constexpr (BN == 128)
                gld_lds16(&Bt[(size_t)(n0 + r1) * K + k0 + cs8], &Bs[cur ^ 1][d1]);
        }
        short8 a[4], b[NF];
#pragma unroll
        for (int m = 0; m < 4; m++)
            a[m] = *reinterpret_cast<const short8*>(
                &As[cur][(wr * 64 + m * 16 + fr) * 32 + kswz]);
#pragma unroll
        for (int n = 0; n < NF; n++)
            b[n] = *reinterpret_cast<const short8*>(
                &Bs[cur][(wc * (BN / 2) + n * 16 + fr) * 32 + kswz]);
#pragma unroll
        for (int m = 0; m < 4; m++)
#pragma unroll
            for (int n = 0; n < NF; n++)
                acc[m][n] = __builtin_amdgcn_mfma_f32_16x16x32_bf16(
                    a[m], b[n], acc[m][n], 0, 0, 0);
        __syncthreads();
        cur ^= 1;
    }

    const int g4 = (lane >> 4) * 4;
#pragma unroll
    for (int m = 0; m < 4; m++)
#pragma unroll
        for (int n = 0; n < NF; n++)
#pragma unroll
            for (int j = 0; j < 4; j++) {
                int mm = m0 + wr * 64 + m * 16 + g4 + j;
                int nn = n0 + wc * (BN / 2) + n * 16 + fr;
                float v = acc[m][n][j];
                if constexpr (sizeof(CT) == 2)
                    C[(size_t)mm * N + nn] = f2bf(v);
                else
                    C[(size_t)mm * N + nn] = v;
            }
}

// ---- dt: LDS-free direct MFMA, K=64 ----
__global__ __launch_bounds__(256) void dt_gemm(
    const unsigned short* __restrict__ dtin,  // [M][64]
    const unsigned short* __restrict__ WdtT,  // [DINNER][64]
    const float* __restrict__ bias,
    unsigned short* __restrict__ dtout) {     // [M][DINNER]
    const int lane = threadIdx.x & 63;
    const int wid = threadIdx.x >> 6;
    const int mt = wid >> 1, nh = wid & 1;
    const int m0 = blockIdx.x * 32;
    const int n0 = blockIdx.y * 128 + nh * 64;
    const int fr = lane & 15, kg = lane >> 4;

    f32x4 acc[4];
#pragma unroll
    for (int i = 0; i < 4; i++) acc[i] = (f32x4){0.f, 0.f, 0.f, 0.f};

#pragma unroll
    for (int step = 0; step < 2; step++) {
        short8 a = *reinterpret_cast<const short8*>(
            &dtin[(size_t)(m0 + mt * 16 + fr) * DTRANK + step * 32 + kg * 8]);
#pragma unroll
        for (int nt = 0; nt < 4; nt++) {
            short8 b = *reinterpret_cast<const short8*>(
                &WdtT[(size_t)(n0 + nt * 16 + fr) * DTRANK + step * 32 + kg * 8]);
            acc[nt] = __builtin_amdgcn_mfma_f32_16x16x32_bf16(a, b, acc[nt], 0, 0, 0);
        }
    }
    const int g4 = kg * 4;
#pragma unroll
    for (int nt = 0; nt < 4; nt++)
#pragma unroll
        for (int j = 0; j < 4; j++) {
            int m = m0 + mt * 16 + g4 + j;
            int n = n0 + nt * 16 + fr;
            dtout[(size_t)m * DINNER + n] = f2bf(softplus_f(acc[nt][j] + bias[n]));
        }
}

// ---- proj split-K MFMA: pp[kc][M][96] partial of xb_bf @ WxT^T ----
__global__ __launch_bounds__(256) void proj_splitk(
    const unsigned short* __restrict__ Abf,
    const unsigned short* __restrict__ WxT,
    float* __restrict__ pp) {
    const int lane = threadIdx.x & 63;
    const int wid = threadIdx.x >> 6;
    const int mt = wid >> 1;
    const int nh = wid & 1;
    const int m0 = blockIdx.x * 32;
    const int kc = blockIdx.y;
    const int fr = lane & 15;
    const int kg = lane >> 4;

    const size_t abase = (size_t)(m0 + mt * 16 + fr) * DINNER + kc * KCH + kg * 8;

    f32x4 acc[3];
#pragma unroll
    for (int i = 0; i < 3; i++) acc[i] = (f32x4){0.f, 0.f, 0.f, 0.f};

    for (int step = 0; step < KCH / 32; step++) {
        short8 a = *reinterpret_cast<const short8*>(&Abf[abase + step * 32]);
#pragma unroll
        for (int nt = 0; nt < 3; nt++) {
            int nrow = nh * 48 + nt * 16 + fr;
            short8 b = *reinterpret_cast<const short8*>(
                &WxT[(size_t)nrow * DINNER + kc * KCH + step * 32 + kg * 8]);
            acc[nt] = __builtin_amdgcn_mfma_f32_16x16x32_bf16(a, b, acc[nt], 0, 0, 0);
        }
    }
    const int g4 = (lane >> 4) * 4;
#pragma unroll
    for (int nt = 0; nt < 3; nt++)
#pragma unroll
        for (int j = 0; j < 4; j++) {
            int m = m0 + mt * 16 + g4 + j;
            int n = nh * 48 + nt * 16 + fr;
            pp[((size_t)kc * (BSZ * LSEQ) + m) * NPROJ + n] = acc[nt][j];
        }
}

// reduce split-K partials; emit fp32 proj + bf16 dt_in (cols < DTRANK)
__global__ __launch_bounds__(256) void proj_reduce(
    const float* __restrict__ pp, float* __restrict__ proj,
    unsigned short* __restrict__ dtin) {
    int i = blockIdx.x * 256 + threadIdx.x;
    if (i >= BSZ * LSEQ * NPROJ) return;
    float s = 0.f;
#pragma unroll
    for (int kc = 0; kc < KS; kc++)
        s += pp[(size_t)kc * BSZ * LSEQ * NPROJ + i];
    proj[i] = s;
    int m = i / NPROJ;
    int n = i - m * NPROJ;
    if (n < DTRANK) dtin[(size_t)m * DTRANK + n] = f2bf(s);
}

// ---- causal depthwise conv (k=4) + bias + silu — sliding window ----
__global__ __launch_bounds__(256) void conv_silu_kernel(
    const unsigned short* __restrict__ xin, const float* __restrict__ w,
    const float* __restrict__ bconv, unsigned short* __restrict__ xout) {
    const int tid = threadIdx.x;
    const int d0 = tid * 8;
    const int bt0 = blockIdx.x * TT;
    const int tloc = bt0 & (LSEQ - 1);

    float wk0[8], wk1[8], wk2[8], wk3[8], bb[8];
#pragma unroll
    for (int q = 0; q < 8; q++) {
        float4 wv = *reinterpret_cast<const float4*>(&w[(d0 + q) * 4]);
        wk0[q] = wv.x; wk1[q] = wv.y; wk2[q] = wv.z; wk3[q] = wv.w;
    }
    {
        float4 b0 = *reinterpret_cast<const float4*>(&bconv[d0]);
        float4 b1 = *reinterpret_cast<const float4*>(&bconv[d0 + 4]);
        bb[0] = b0.x; bb[1] = b0.y; bb[2] = b0.z; bb[3] = b0.w;
        bb[4] = b1.x; bb[5] = b1.y; bb[6] = b1.z; bb[7] = b1.w;
    }

    float xm3[8], xm2[8], xm1[8];
    if (tloc >= 3) {
        short8 v3 = *reinterpret_cast<const short8*>(&xin[(size_t)(bt0 - 3) * DINNER + d0]);
        short8 v2 = *reinterpret_cast<const short8*>(&xin[(size_t)(bt0 - 2) * DINNER + d0]);
        short8 v1 = *reinterpret_cast<const short8*>(&xin[(size_t)(bt0 - 1) * DINNER + d0]);
#pragma unroll
        for (int q = 0; q < 8; q++) {
            xm3[q] = bf2f((unsigned short)v3[q]);
            xm2[q] = bf2f((unsigned short)v2[q]);
            xm1[q] = bf2f((unsigned short)v1[q]);
        }
    } else {
#pragma unroll
        for (int q = 0; q < 8; q++) { xm3[q] = 0.f; xm2[q] = 0.f; xm1[q] = 0.f; }
    }

#pragma unroll
    for (int i = 0; i < TT; i++) {
        short8 vc = *reinterpret_cast<const short8*>(&xin[(size_t)(bt0 + i) * DINNER + d0]);
        float xc[8];
        short8 o;
#pragma unroll
        for (int q = 0; q < 8; q++) {
            xc[q] = bf2f((unsigned short)vc[q]);
            float a = bb[q];
            a = fmaf(wk0[q], xm3[q], a);
            a = fmaf(wk1[q], xm2[q], a);
            a = fmaf(wk2[q], xm1[q], a);
            a = fmaf(wk3[q], xc[q], a);
            o[q] = (short)f2bf(silu_f(a));
        }
        *reinterpret_cast<short8*>(&xout[(size_t)(bt0 + i) * DINNER + d0]) = o;
#pragma unroll
        for (int q = 0; q < 8; q++) { xm3[q] = xm2[q]; xm2[q] = xm1[q]; xm1[q] = xc[q]; }
    }
}

// ---- chunked selective scan (bf16 operands, fp32 state) ----
__global__ __launch_bounds__(256) void scan_pass1(
    const unsigned short* __restrict__ xb, const unsigned short* __restrict__ dt,
    const float* __restrict__ proj, const float* __restrict__ A_log,
    float* __restrict__ aprod, float* __restrict__ hend) {
    __shared__ __align__(16) float Bsh[LC][DSTATE];
    const int tg = blockIdx.x * 256 + threadIdx.x;
    const int d = tg & (DINNER - 1);
    const int bc = tg >> 11;
    const int c = bc & (NC - 1);
    const int b = bc >> 5;

    for (int idx = threadIdx.x; idx < LC * DSTATE; idx += 256) {
        int ti = idx >> 4, j = idx & 15;
        Bsh[ti][j] = proj[(size_t)(b * LSEQ + c * LC + ti) * NPROJ + DTRANK + j];
    }
    __syncthreads();

    float Av[DSTATE], h[DSTATE], ap[DSTATE];
#pragma unroll
    for (int s = 0; s < DSTATE; s++) {
        Av[s] = -expf(A_log[d * DSTATE + s]);
        h[s] = 0.f;
        ap[s] = 1.f;
    }

    for (int i = 0; i < LC; i++) {
        size_t base = (size_t)(b * LSEQ + c * LC + i) * DINNER + d;
        float dtv = bf2f(dt[base]);
        float xv = bf2f(xb[base]);
        float dx = dtv * xv;
        float Bv[DSTATE];
        *reinterpret_cast<float4*>(&Bv[0])  = *reinterpret_cast<const float4*>(&Bsh[i][0]);
        *reinterpret_cast<float4*>(&Bv[4])  = *reinterpret_cast<const float4*>(&Bsh[i][4]);
        *reinterpret_cast<float4*>(&Bv[8])  = *reinterpret_cast<const float4*>(&Bsh[i][8]);
        *reinterpret_cast<float4*>(&Bv[12]) = *reinterpret_cast<const float4*>(&Bsh[i][12]);
#pragma unroll
        for (int s = 0; s < DSTATE; s++) {
            float dA = __expf(dtv * Av[s]);
            ap[s] *= dA;
            h[s] = fmaf(dA, h[s], dx * Bv[s]);
        }
    }

    size_t o = ((size_t)bc * DINNER + d) * DSTATE;
#pragma unroll
    for (int q = 0; q < 4; q++) {
        *reinterpret_cast<float4*>(&aprod[o + q * 4]) =
            make_float4(ap[4 * q], ap[4 * q + 1], ap[4 * q + 2], ap[4 * q + 3]);
        *reinterpret_cast<float4*>(&hend[o + q * 4]) =
            make_float4(h[4 * q], h[4 * q + 1], h[4 * q + 2], h[4 * q + 3]);
    }
}

__global__ __launch_bounds__(256) void scan_pass2(
    float* __restrict__ aprod, const float* __restrict__ hend) {
    const int tg = blockIdx.x * 256 + threadIdx.x;
    const int s = tg & (DSTATE - 1);
    const int d = (tg >> 4) & (DINNER - 1);
    const int b = tg >> 15;
    float h = 0.f;
    for (int c = 0; c < NC; c++) {
        size_t o = ((size_t)((b * NC + c) * DINNER) + d) * DSTATE + s;
        float a = aprod[o];
        float e = hend[o];
        aprod[o] = h;
        h = fmaf(a, h, e);
    }
}

__global__ __launch_bounds__(256) void scan_pass3(
    const unsigned short* __restrict__ xb, const unsigned short* __restrict__ dt,
    const float* __restrict__ proj, const float* __restrict__ hstart,
    const float* __restrict__ A_log, const float* __restrict__ Dp,
    const unsigned short* __restrict__ sz, unsigned short* __restrict__ ybf) {
    __shared__ __align__(16) float Bsh[LC][DSTATE];
    __shared__ __align__(16) float Csh[LC][DSTATE];
    const int tg = blockIdx.x * 256 + threadIdx.x;
    const int d = tg & (DINNER - 1);
    const int bc = tg >> 11;
    const int c = bc & (NC - 1);
    const int b = bc >> 5;

    for (int idx = threadIdx.x; idx < LC * 2 * DSTATE; idx += 256) {
        int ti = idx >> 5, j = idx & 31;
        float v = proj[(size_t)(b * LSEQ + c * LC + ti) * NPROJ + DTRANK + j];
        if (j < DSTATE) Bsh[ti][j] = v;
        else            Csh[ti][j - DSTATE] = v;
    }
    __syncthreads();

    float Av[DSTATE], h[DSTATE];
    size_t o = ((size_t)bc * DINNER + d) * DSTATE;
#pragma unroll
    for (int q = 0; q < 4; q++) {
        float4 hv = *reinterpret_cast<const float4*>(&hstart[o + q * 4]);
        h[4 * q] = hv.x; h[4 * q + 1] = hv.y; h[4 * q + 2] = hv.z; h[4 * q + 3] = hv.w;
    }
#pragma unroll
    for (int s = 0; s < DSTATE; s++)
        Av[s] = -expf(A_log[d * DSTATE + s]);
    const float Dd = Dp[d];

    for (int i = 0; i < LC; i++) {
        size_t base = (size_t)(b * LSEQ + c * LC + i) * DINNER + d;
        float dtv = bf2f(dt[base]);
        float xv = bf2f(xb[base]);
        float szv = bf2f(sz[base]);
        float dx = dtv * xv;
        float Bv[DSTATE], Cv[DSTATE];
        *reinterpret_cast<float4*>(&Bv[0])  = *reinterpret_cast<const float4*>(&Bsh[i][0]);
        *reinterpret_cast<float4*>(&Bv[4])  = *reinterpret_cast<const float4*>(&Bsh[i][4]);
        *reinterpret_cast<float4*>(&Bv[8])  = *reinterpret_cast<const float4*>(&Bsh[i][8]);
        *reinterpret_cast<float4*>(&Bv[12]) = *reinterpret_cast<const float4*>(&Bsh[i][12]);
        *reinterpret_cast<float4*>(&Cv[0])  = *reinterpret_cast<const float4*>(&Csh[i][0]);
        *reinterpret_cast<float4*>(&Cv[4])  = *reinterpret_cast<const float4*>(&Csh[i][4]);
        *reinterpret_cast<float4*>(&Cv[8])  = *reinterpret_cast<const float4*>(&Csh[i][8]);
        *reinterpret_cast<float4*>(&Cv[12]) = *reinterpret_cast<const float4*>(&Csh[i][12]);
        float p = 0.f;
#pragma unroll
        for (int s = 0; s < DSTATE; s++) {
            float dA = __expf(dtv * Av[s]);
            h[s] = fmaf(dA, h[s], dx * Bv[s]);
            p = fmaf(h[s], Cv[s], p);
        }
        ybf[base] = f2bf((p + Dd * xv) * szv);
    }
}

extern "C" void kernel_launch(void* const* d_in, const int* in_sizes, int n_in,
                              void* d_out, int out_size, void* d_ws,
                              size_t ws_size, hipStream_t stream) {
    const float* x = (const float*)d_in[0];
    const float* W_in = (const float*)d_in[1];
    const float* conv_w = (const float*)d_in[2];
    const float* conv_b = (const float*)d_in[3];
    const float* W_xproj = (const float*)d_in[4];
    const float* W_dt = (const float*)d_in[5];
    const float* b_dt = (const float*)d_in[6];
    const float* A_log = (const float*)d_in[7];
    const float* Dp = (const float*)d_in[8];
    const float* W_out = (const float*)d_in[9];
    float* out = (float*)d_out;

    char* ws = (char*)d_ws;
    const size_t MB = 1u << 20;
    float* pp    = (float*)(ws);
    float* aprod = (float*)(ws);
    float* hend  = (float*)(ws + 8 * MB);
    unsigned short* xbpre_bf = (unsigned short*)(ws + 16 * MB);  // 16 MB
    unsigned short* ybf      = (unsigned short*)(ws + 16 * MB);  // 16 MB (after conv)
    unsigned short* sz_bf    = (unsigned short*)(ws + 32 * MB);  // 16 MB
    unsigned short* xb_bf    = (unsigned short*)(ws + 48 * MB);  // 16 MB
    unsigned short* dt_bf    = (unsigned short*)(ws + 64 * MB);  // 16 MB
    float* projbuf           = (float*)(ws + 88 * MB);           // 1.5 MB
    unsigned short* dtin_bf  = (unsigned short*)(ws + 90 * MB);  // 0.5 MB
    unsigned short* xbf      = (unsigned short*)(ws + 91 * MB);  // 8 MB
    unsigned short* WinT     = (unsigned short*)(ws + 99 * MB);  // 8 MB
    unsigned short* WoutT    = (unsigned short*)(ws + 107 * MB); // 4 MB
    unsigned short* WxT      = (unsigned short*)(ws + 111 * MB); // 384 KB
    unsigned short* WdtT     = (unsigned short*)(ws + 112 * MB); // 256 KB

    const int M = BSZ * LSEQ; // 4096
    dim3 blk(256);

    // 0. fused prep: x->bf16 + transposes (64x64 tiles for W_in/W_out)
    prep_kernel<<<dim3(4096 + 1024 + 512 + 192 + 128), blk, 0, stream>>>(
        x, W_in, W_out, W_xproj, W_dt, xbf, WinT, WoutT, WxT, WdtT);

    // 1. xz = x @ W_in — 256x128 tile, 512 blocks -> 2 blocks/CU
    gemm_bm256<1, unsigned short><<<dim3((2 * DINNER) / 128, M / 256), dim3(512),
                                    0, stream>>>(
        xbf, WinT, xbpre_bf, sz_bf, M, 2 * DINNER, DMODEL);

    // 2. conv + silu (sliding window, TT=8); xbpre dead after this
    conv_silu_kernel<<<dim3(M / TT), blk, 0, stream>>>(
        xbpre_bf, conv_w, conv_b, xb_bf);

    // 3. proj (split-K = 4)
    proj_splitk<<<dim3(M / 32, KS), blk, 0, stream>>>(xb_bf, WxT, pp);
    proj_reduce<<<dim3((M * NPROJ) / 256), blk, 0, stream>>>(pp, projbuf, dtin_bf);

    // 4. dt = softplus(dt_in @ W_dt + b_dt) — LDS-free direct MFMA
    dt_gemm<<<dim3(M / 32, DINNER / 128), blk, 0, stream>>>(
        dtin_bf, WdtT, b_dt, dt_bf);

    // 5. scan
    const int nthreads1 = BSZ * NC * DINNER;
    scan_pass1<<<dim3(nthreads1 / 256), blk, 0, stream>>>(
        xb_bf, dt_bf, projbuf, A_log, aprod, hend);
    const int nthreads2 = BSZ * DINNER * DSTATE;
    scan_pass2<<<dim3(nthreads2 / 256), blk, 0, stream>>>(aprod, hend);
    scan_pass3<<<dim3(nthreads1 / 256), blk, 0, stream>>>(
        xb_bf, dt_bf, projbuf, aprod, A_log, Dp, sz_bf, ybf);

    // 6. out = y @ W_out (2-phase 128x64 -> 512 blocks, 2/CU)
    gemm_mfma<64, float><<<dim3(DMODEL / 64, M / 128), blk, 0, stream>>>(
        ybf, WoutT, out, M, DMODEL, DINNER);
}

// Round 15
// 249.312 us; speedup vs baseline: 1.3189x; 1.0154x over previous
//
#include <hip/hip_runtime.h>
#include <hip/hip_bf16.h>
#include <math.h>

#define BSZ 2
#define LSEQ 2048
#define DMODEL 1024
#define DSTATE 16
#define DCONV 4
#define DINNER 2048
#define DTRANK 64
#define NPROJ (DTRANK + 2 * DSTATE) // 96
#define NC 32   // scan chunks
#define LC 64   // steps per chunk
#define KS 4    // proj split-K chunks
#define KCH (DINNER / KS) // 512

using short8 = __attribute__((ext_vector_type(8))) short;
using f32x4 = __attribute__((ext_vector_type(4))) float;
using u16x4 = __attribute__((ext_vector_type(4))) unsigned short;

__device__ __forceinline__ float silu_f(float v) {
    return v / (1.f + expf(-v));
}
__device__ __forceinline__ float softplus_f(float v) {
    return fmaxf(v, 0.f) + log1pf(expf(-fabsf(v)));
}
// fp32 -> bf16 bits, round-to-nearest-even
__device__ __forceinline__ unsigned short f2bf(float f) {
    unsigned u = __builtin_bit_cast(unsigned, f);
    u += 0x7fffu + ((u >> 16) & 1u);
    return (unsigned short)(u >> 16);
}
__device__ __forceinline__ float bf2f(unsigned short u) {
    unsigned x = ((unsigned)u) << 16;
    return __builtin_bit_cast(float, x);
}

__device__ __forceinline__ void gld_lds16(const unsigned short* g, unsigned short* l) {
    __builtin_amdgcn_global_load_lds(
        (const __attribute__((address_space(1))) unsigned int*)g,
        (__attribute__((address_space(3))) unsigned int*)l, 16, 0, 0);
}

// bijective XCD swizzle (requires nwg % 8 == 0)
__device__ __forceinline__ int xcd_swz(int wg, int nwg) {
    return (wg & 7) * (nwg >> 3) + (wg >> 3);
}

// ---- fused prep: x->bf16 + weight transposes ----
__global__ __launch_bounds__(256) void prep_kernel(
    const float* __restrict__ x, const float* __restrict__ W_in,
    const float* __restrict__ W_out, const float* __restrict__ W_xproj,
    const float* __restrict__ W_dt,
    unsigned short* __restrict__ xbf, unsigned short* __restrict__ WinT,
    unsigned short* __restrict__ WoutT, unsigned short* __restrict__ WxT,
    unsigned short* __restrict__ WdtT) {
    int bid = blockIdx.x;
    if (bid < 4096) { // x -> bf16
        int i = bid * 256 + threadIdx.x;
        float4 v = reinterpret_cast<const float4*>(x)[i];
        u16x4 o = {f2bf(v.x), f2bf(v.y), f2bf(v.z), f2bf(v.w)};
        reinterpret_cast<u16x4*>(xbf)[i] = o;
        return;
    }
    bid -= 4096;
    if (bid < 1024 + 512) { // 64x64 transposes: W_in, W_out
        const float* in;
        unsigned short* outp;
        int R, Cc, gx;
        if (bid < 1024) { in = W_in; outp = WinT; R = 1024; Cc = 4096; gx = 64; }
        else { bid -= 1024; in = W_out; outp = WoutT; R = 2048; Cc = 1024; gx = 16; }
        const int bx = bid % gx, by = bid / gx;
        __shared__ float t64[64][65];
        const int tx = threadIdx.x & 63, ty = threadIdx.x >> 6; // 64 x 4
        const int c0 = bx * 64, r0 = by * 64;
#pragma unroll
        for (int i = 0; i < 16; i++)
            t64[ty + 4 * i][tx] = in[(size_t)(r0 + ty + 4 * i) * Cc + c0 + tx];
        __syncthreads();
#pragma unroll
        for (int i = 0; i < 16; i++) {
            int rr = ty + 4 * i;
            outp[(size_t)(c0 + rr) * R + r0 + tx] = f2bf(t64[tx][rr]);
        }
        return;
    }
    bid -= 1536;
    const float* in;
    unsigned short* outp;
    int R, Cc, gx;
    if (bid < 192) { in = W_xproj; outp = WxT; R = 2048; Cc = 96; gx = 3; }
    else { bid -= 192; in = W_dt; outp = WdtT; R = 64; Cc = 2048; gx = 64; }
    const int bx = bid % gx, by = bid / gx;
    __shared__ float t[32][33];
    const int tx = threadIdx.x & 31, ty = threadIdx.x >> 5;
    const int c0 = bx * 32, r0 = by * 32;
    for (int i = ty; i < 32; i += 8)
        t[i][tx] = in[(size_t)(r0 + i) * Cc + c0 + tx];
    __syncthreads();
    for (int i = ty; i < 32; i += 8)
        outp[(size_t)(c0 + i) * R + r0 + tx] = f2bf(t[tx][i]);
}

// ===== 256x128 8-wave 2-phase MFMA GEMM (xz) — r13-proven =====
template <int EPI, typename CT>
__global__ __launch_bounds__(512, 4) void gemm_bm256(
    const unsigned short* __restrict__ A, const unsigned short* __restrict__ Bt,
    CT* __restrict__ C, CT* __restrict__ C2, int M, int N, int K) {
    __shared__ __align__(16) unsigned short As[2][8192];
    __shared__ __align__(16) unsigned short Bs[2][4096];
    const int tid = threadIdx.x;
    const int lane = tid & 63;
    const int w8 = tid >> 6;
    const int wm = w8 >> 1, wn = w8 & 1;
    const int nwg = gridDim.x * gridDim.y;
    const int wg = xcd_swz(blockIdx.y * gridDim.x + blockIdx.x, nwg);
    const int m0 = (wg / gridDim.x) * 256, n0 = (wg % gridDim.x) * 128;
    const int fr = lane & 15, kg = lane >> 4;
    const int kswz = ((kg ^ ((fr >> 1) & 3)) << 3);
    const int r0 = tid >> 2;
    const int d0 = tid * 8;
    const int cs8 = (((tid & 3) ^ ((tid >> 3) & 3)) << 3);
    const int nt = K / 32;

    f32x4 acc[4][4];
#pragma unroll
    for (int m = 0; m < 4; m++)
#pragma unroll
        for (int n = 0; n < 4; n++) acc[m][n] = (f32x4){0.f, 0.f, 0.f, 0.f};

#define STAGE(buf, k0)                                                           \
    {                                                                            \
        gld_lds16(&A[(size_t)(m0 + r0) * K + (k0) + cs8], &As[buf][d0]);         \
        gld_lds16(&A[(size_t)(m0 + 128 + r0) * K + (k0) + cs8],                  \
                  &As[buf][d0 + 4096]);                                          \
        gld_lds16(&Bt[(size_t)(n0 + r0) * K + (k0) + cs8], &Bs[buf][d0]);        \
    }

    STAGE(0, 0);
    __syncthreads();

    int cur = 0;
    for (int t = 0; t < nt; t++) {
        if (t + 1 < nt) STAGE(cur ^ 1, (t + 1) * 32);
        short8 a[4], b[4];
#pragma unroll
        for (int m = 0; m < 4; m++)
            a[m] = *reinterpret_cast<const short8*>(
                &As[cur][(wm * 64 + m * 16 + fr) * 32 + kswz]);
#pragma unroll
        for (int n = 0; n < 4; n++)
            b[n] = *reinterpret_cast<const short8*>(
                &Bs[cur][(wn * 64 + n * 16 + fr) * 32 + kswz]);
#pragma unroll
        for (int m = 0; m < 4; m++)
#pragma unroll
            for (int n = 0; n < 4; n++)
                acc[m][n] = __builtin_amdgcn_mfma_f32_16x16x32_bf16(
                    a[m], b[n], acc[m][n], 0, 0, 0);
        __syncthreads();
        cur ^= 1;
    }
#undef STAGE

    const int g4 = kg * 4;
#pragma unroll
    for (int m = 0; m < 4; m++)
#pragma unroll
        for (int n = 0; n < 4; n++)
#pragma unroll
            for (int j = 0; j < 4; j++) {
                int mm = m0 + wm * 64 + m * 16 + g4 + j;
                int nn = n0 + wn * 64 + n * 16 + fr;
                float v = acc[m][n][j];
                if (EPI == 1) {
                    if (nn < DINNER)
                        C[(size_t)mm * DINNER + nn] = f2bf(v);
                    else
                        C2[(size_t)mm * DINNER + (nn - DINNER)] = f2bf(silu_f(v));
                } else {
                    if constexpr (sizeof(CT) == 2)
                        C[(size_t)mm * N + nn] = f2bf(v);
                    else
                        C[(size_t)mm * N + nn] = v;
                }
            }
}

// ---- 128xBN 2-phase MFMA GEMM (out; BN=64 -> 512 blocks) ----
template <int BN, typename CT>
__global__ __launch_bounds__(256) void gemm_mfma(
    const unsigned short* __restrict__ A, const unsigned short* __restrict__ Bt,
    CT* __restrict__ C, int M, int N, int K) {
    constexpr int NF = BN / 32;
    __shared__ __align__(16) unsigned short As[2][4096];
    __shared__ __align__(16) unsigned short Bs[2][BN * 32];
    const int tid = threadIdx.x;
    const int lane = tid & 63;
    const int wid = tid >> 6;
    const int wr = wid >> 1, wc = wid & 1;
    const int nwg = gridDim.x * gridDim.y;
    const int wg = xcd_swz(blockIdx.y * gridDim.x + blockIdx.x, nwg);
    const int m0 = (wg / gridDim.x) * 128, n0 = (wg % gridDim.x) * BN;

    const int r0 = tid >> 2;
    const int r1 = r0 + 64;
    const int d0 = tid * 8;
    const int d1 = d0 + 2048;
    const int cs8 = (((tid & 3) ^ ((tid >> 3) & 3)) << 3);

    f32x4 acc[4][NF];
#pragma unroll
    for (int m = 0; m < 4; m++)
#pragma unroll
        for (int n = 0; n < NF; n++) acc[m][n] = (f32x4){0.f, 0.f, 0.f, 0.f};

    const int fr = lane & 15;
    const int kg = lane >> 4;
    const int kswz = ((kg ^ ((fr >> 1) & 3)) << 3);
    const int nt = K / 32;

    gld_lds16(&A[(size_t)(m0 + r0) * K + cs8], &As[0][d0]);
    gld_lds16(&A[(size_t)(m0 + r1) * K + cs8], &As[0][d1]);
    gld_lds16(&Bt[(size_t)(n0 + r0) * K + cs8], &Bs[0][d0]);
    if constexpr (BN == 128)
        gld_lds16(&Bt[(size_t)(n0 + r1) * K + cs8], &Bs[0][d1]);
    __syncthreads();

    int cur = 0;
    for (int t = 0; t < nt; t++) {
        if (t + 1 < nt) {
            const int k0 = (t + 1) * 32;
            gld_lds16(&A[(size_t)(m0 + r0) * K + k0 + cs8], &As[cur ^ 1][d0]);
            gld_lds16(&A[(size_t)(m0 + r1) * K + k0 + cs8], &As[cur ^ 1][d1]);
            gld_lds16(&Bt[(size_t)(n0 + r0) * K + k0 + cs8], &Bs[cur ^ 1][d0]);
            if constexpr (BN == 128)
                gld_lds16(&Bt[(size_t)(n0 + r1) * K + k0 + cs8], &Bs[cur ^ 1][d1]);
        }
        short8 a[4], b[NF];
#pragma unroll
        for (int m = 0; m < 4; m++)
            a[m] = *reinterpret_cast<const short8*>(
                &As[cur][(wr * 64 + m * 16 + fr) * 32 + kswz]);
#pragma unroll
        for (int n = 0; n < NF; n++)
            b[n] = *reinterpret_cast<const short8*>(
                &Bs[cur][(wc * (BN / 2) + n * 16 + fr) * 32 + kswz]);
#pragma unroll
        for (int m = 0; m < 4; m++)
#pragma unroll
            for (int n = 0; n < NF; n++)
                acc[m][n] = __builtin_amdgcn_mfma_f32_16x16x32_bf16(
                    a[m], b[n], acc[m][n], 0, 0, 0);
        __syncthreads();
        cur ^= 1;
    }

    const int g4 = (lane >> 4) * 4;
#pragma unroll
    for (int m = 0; m < 4; m++)
#pragma unroll
        for (int n = 0; n < NF; n++)
#pragma unroll
            for (int j = 0; j < 4; j++) {
                int mm = m0 + wr * 64 + m * 16 + g4 + j;
                int nn = n0 + wc * (BN / 2) + n * 16 + fr;
                float v = acc[m][n][j];
                if constexpr (sizeof(CT) == 2)
                    C[(size_t)mm * N + nn] = f2bf(v);
                else
                    C[(size_t)mm * N + nn] = v;
            }
}

// ---- dt: LDS-free direct MFMA, K=64 ----
__global__ __launch_bounds__(256) void dt_gemm(
    const unsigned short* __restrict__ dtin,  // [M][64]
    const unsigned short* __restrict__ WdtT,  // [DINNER][64]
    const float* __restrict__ bias,
    unsigned short* __restrict__ dtout) {     // [M][DINNER]
    const int lane = threadIdx.x & 63;
    const int wid = threadIdx.x >> 6;
    const int mt = wid >> 1, nh = wid & 1;
    const int m0 = blockIdx.x * 32;
    const int n0 = blockIdx.y * 128 + nh * 64;
    const int fr = lane & 15, kg = lane >> 4;

    f32x4 acc[4];
#pragma unroll
    for (int i = 0; i < 4; i++) acc[i] = (f32x4){0.f, 0.f, 0.f, 0.f};

#pragma unroll
    for (int step = 0; step < 2; step++) {
        short8 a = *reinterpret_cast<const short8*>(
            &dtin[(size_t)(m0 + mt * 16 + fr) * DTRANK + step * 32 + kg * 8]);
#pragma unroll
        for (int nt = 0; nt < 4; nt++) {
            short8 b = *reinterpret_cast<const short8*>(
                &WdtT[(size_t)(n0 + nt * 16 + fr) * DTRANK + step * 32 + kg * 8]);
            acc[nt] = __builtin_amdgcn_mfma_f32_16x16x32_bf16(a, b, acc[nt], 0, 0, 0);
        }
    }
    const int g4 = kg * 4;
#pragma unroll
    for (int nt = 0; nt < 4; nt++)
#pragma unroll
        for (int j = 0; j < 4; j++) {
            int m = m0 + mt * 16 + g4 + j;
            int n = n0 + nt * 16 + fr;
            dtout[(size_t)m * DINNER + n] = f2bf(softplus_f(acc[nt][j] + bias[n]));
        }
}

// ---- FUSED conv+proj: block (mb, kc) owns rows mb*32..+31, d kc*512..+511 ----
// Phase 1 (conv): each thread computes 8 rows x 8 d of conv+silu (sliding
// window, weights in regs), writes bf16 to LDS tile [32][520] AND to global xb.
// Phase 2 (MFMA): proj partial pp[kc] with A-fragments from the LDS tile.
// Covers each (row, d) exactly once across the grid.
__global__ __launch_bounds__(256) void proj_conv(
    const unsigned short* __restrict__ xbpre, const float* __restrict__ w,
    const float* __restrict__ bconv, const unsigned short* __restrict__ WxT,
    unsigned short* __restrict__ xb_out, float* __restrict__ pp) {
    __shared__ __align__(16) unsigned short xbs[32][520]; // +8 pad: bank rotate
    const int mb = blockIdx.x, kc = blockIdx.y;
    const int m0 = mb * 32;
    const int D0 = kc * KCH;

    // ---- conv phase ----
    {
        const int tcol = threadIdx.x & 63;  // d-octet
        const int trow = threadIdx.x >> 6;  // 0..3 -> rows trow*8..+7
        const int dd = D0 + tcol * 8;
        float wk0[8], wk1[8], wk2[8], wk3[8], bb[8];
#pragma unroll
        for (int q = 0; q < 8; q++) {
            float4 wv = *reinterpret_cast<const float4*>(&w[(dd + q) * 4]);
            wk0[q] = wv.x; wk1[q] = wv.y; wk2[q] = wv.z; wk3[q] = wv.w;
        }
        {
            float4 b0 = *reinterpret_cast<const float4*>(&bconv[dd]);
            float4 b1 = *reinterpret_cast<const float4*>(&bconv[dd + 4]);
            bb[0] = b0.x; bb[1] = b0.y; bb[2] = b0.z; bb[3] = b0.w;
            bb[4] = b1.x; bb[5] = b1.y; bb[6] = b1.z; bb[7] = b1.w;
        }
        const int rbase = m0 + trow * 8;
        const int tloc0 = rbase & (LSEQ - 1);
        float xm3[8], xm2[8], xm1[8];
        if (tloc0 >= 3) {
            short8 v3 = *reinterpret_cast<const short8*>(&xbpre[(size_t)(rbase - 3) * DINNER + dd]);
            short8 v2 = *reinterpret_cast<const short8*>(&xbpre[(size_t)(rbase - 2) * DINNER + dd]);
            short8 v1 = *reinterpret_cast<const short8*>(&xbpre[(size_t)(rbase - 1) * DINNER + dd]);
#pragma unroll
            for (int q = 0; q < 8; q++) {
                xm3[q] = bf2f((unsigned short)v3[q]);
                xm2[q] = bf2f((unsigned short)v2[q]);
                xm1[q] = bf2f((unsigned short)v1[q]);
            }
        } else { // batch start (tloc0 == 0)
#pragma unroll
            for (int q = 0; q < 8; q++) { xm3[q] = 0.f; xm2[q] = 0.f; xm1[q] = 0.f; }
        }
#pragma unroll
        for (int rr = 0; rr < 8; rr++) {
            short8 vc = *reinterpret_cast<const short8*>(
                &xbpre[(size_t)(rbase + rr) * DINNER + dd]);
            float xc[8];
            short8 o;
#pragma unroll
            for (int q = 0; q < 8; q++) {
                xc[q] = bf2f((unsigned short)vc[q]);
                float a = bb[q];
                a = fmaf(wk0[q], xm3[q], a);
                a = fmaf(wk1[q], xm2[q], a);
                a = fmaf(wk2[q], xm1[q], a);
                a = fmaf(wk3[q], xc[q], a);
                o[q] = (short)f2bf(silu_f(a));
            }
            *reinterpret_cast<short8*>(&xbs[trow * 8 + rr][tcol * 8]) = o;
            *reinterpret_cast<short8*>(
                &xb_out[(size_t)(rbase + rr) * DINNER + dd]) = o;
#pragma unroll
            for (int q = 0; q < 8; q++) { xm3[q] = xm2[q]; xm2[q] = xm1[q]; xm1[q] = xc[q]; }
        }
    }
    __syncthreads();

    // ---- MFMA phase (proj partial) ----
    const int lane = threadIdx.x & 63;
    const int wid = threadIdx.x >> 6;
    const int mt = wid >> 1;
    const int nh = wid & 1;
    const int fr = lane & 15;
    const int kg = lane >> 4;

    f32x4 acc[3];
#pragma unroll
    for (int i = 0; i < 3; i++) acc[i] = (f32x4){0.f, 0.f, 0.f, 0.f};

    for (int step = 0; step < KCH / 32; step++) {
        short8 a = *reinterpret_cast<const short8*>(
            &xbs[mt * 16 + fr][step * 32 + kg * 8]);
#pragma unroll
        for (int nt = 0; nt < 3; nt++) {
            int nrow = nh * 48 + nt * 16 + fr;
            short8 b = *reinterpret_cast<const short8*>(
                &WxT[(size_t)nrow * DINNER + D0 + step * 32 + kg * 8]);
            acc[nt] = __builtin_amdgcn_mfma_f32_16x16x32_bf16(a, b, acc[nt], 0, 0, 0);
        }
    }
    const int g4 = kg * 4;
#pragma unroll
    for (int nt = 0; nt < 3; nt++)
#pragma unroll
        for (int j = 0; j < 4; j++) {
            int m = m0 + mt * 16 + g4 + j;
            int n = nh * 48 + nt * 16 + fr;
            pp[((size_t)kc * (BSZ * LSEQ) + m) * NPROJ + n] = acc[nt][j];
        }
}

// reduce split-K partials; emit fp32 proj + bf16 dt_in (cols < DTRANK)
__global__ __launch_bounds__(256) void proj_reduce(
    const float* __restrict__ pp, float* __restrict__ proj,
    unsigned short* __restrict__ dtin) {
    int i = blockIdx.x * 256 + threadIdx.x;
    if (i >= BSZ * LSEQ * NPROJ) return;
    float s = 0.f;
#pragma unroll
    for (int kc = 0; kc < KS; kc++)
        s += pp[(size_t)kc * BSZ * LSEQ * NPROJ + i];
    proj[i] = s;
    int m = i / NPROJ;
    int n = i - m * NPROJ;
    if (n < DTRANK) dtin[(size_t)m * DTRANK + n] = f2bf(s);
}

// ---- chunked selective scan (bf16 operands, fp32 state) ----
__global__ __launch_bounds__(256) void scan_pass1(
    const unsigned short* __restrict__ xb, const unsigned short* __restrict__ dt,
    const float* __restrict__ proj, const float* __restrict__ A_log,
    float* __restrict__ aprod, float* __restrict__ hend) {
    __shared__ __align__(16) float Bsh[LC][DSTATE];
    const int tg = blockIdx.x * 256 + threadIdx.x;
    const int d = tg & (DINNER - 1);
    const int bc = tg >> 11;
    const int c = bc & (NC - 1);
    const int b = bc >> 5;

    for (int idx = threadIdx.x; idx < LC * DSTATE; idx += 256) {
        int ti = idx >> 4, j = idx & 15;
        Bsh[ti][j] = proj[(size_t)(b * LSEQ + c * LC + ti) * NPROJ + DTRANK + j];
    }
    __syncthreads();

    float Av[DSTATE], h[DSTATE], ap[DSTATE];
#pragma unroll
    for (int s = 0; s < DSTATE; s++) {
        Av[s] = -expf(A_log[d * DSTATE + s]);
        h[s] = 0.f;
        ap[s] = 1.f;
    }

    for (int i = 0; i < LC; i++) {
        size_t base = (size_t)(b * LSEQ + c * LC + i) * DINNER + d;
        float dtv = bf2f(dt[base]);
        float xv = bf2f(xb[base]);
        float dx = dtv * xv;
        float Bv[DSTATE];
        *reinterpret_cast<float4*>(&Bv[0])  = *reinterpret_cast<const float4*>(&Bsh[i][0]);
        *reinterpret_cast<float4*>(&Bv[4])  = *reinterpret_cast<const float4*>(&Bsh[i][4]);
        *reinterpret_cast<float4*>(&Bv[8])  = *reinterpret_cast<const float4*>(&Bsh[i][8]);
        *reinterpret_cast<float4*>(&Bv[12]) = *reinterpret_cast<const float4*>(&Bsh[i][12]);
#pragma unroll
        for (int s = 0; s < DSTATE; s++) {
            float dA = __expf(dtv * Av[s]);
            ap[s] *= dA;
            h[s] = fmaf(dA, h[s], dx * Bv[s]);
        }
    }

    size_t o = ((size_t)bc * DINNER + d) * DSTATE;
#pragma unroll
    for (int q = 0; q < 4; q++) {
        *reinterpret_cast<float4*>(&aprod[o + q * 4]) =
            make_float4(ap[4 * q], ap[4 * q + 1], ap[4 * q + 2], ap[4 * q + 3]);
        *reinterpret_cast<float4*>(&hend[o + q * 4]) =
            make_float4(h[4 * q], h[4 * q + 1], h[4 * q + 2], h[4 * q + 3]);
    }
}

__global__ __launch_bounds__(256) void scan_pass2(
    float* __restrict__ aprod, const float* __restrict__ hend) {
    const int tg = blockIdx.x * 256 + threadIdx.x;
    const int s = tg & (DSTATE - 1);
    const int d = (tg >> 4) & (DINNER - 1);
    const int b = tg >> 15;
    float h = 0.f;
    for (int c = 0; c < NC; c++) {
        size_t o = ((size_t)((b * NC + c) * DINNER) + d) * DSTATE + s;
        float a = aprod[o];
        float e = hend[o];
        aprod[o] = h;
        h = fmaf(a, h, e);
    }
}

__global__ __launch_bounds__(256) void scan_pass3(
    const unsigned short* __restrict__ xb, const unsigned short* __restrict__ dt,
    const float* __restrict__ proj, const float* __restrict__ hstart,
    const float* __restrict__ A_log, const float* __restrict__ Dp,
    const unsigned short* __restrict__ sz, unsigned short* __restrict__ ybf) {
    __shared__ __align__(16) float Bsh[LC][DSTATE];
    __shared__ __align__(16) float Csh[LC][DSTATE];
    const int tg = blockIdx.x * 256 + threadIdx.x;
    const int d = tg & (DINNER - 1);
    const int bc = tg >> 11;
    const int c = bc & (NC - 1);
    const int b = bc >> 5;

    for (int idx = threadIdx.x; idx < LC * 2 * DSTATE; idx += 256) {
        int ti = idx >> 5, j = idx & 31;
        float v = proj[(size_t)(b * LSEQ + c * LC + ti) * NPROJ + DTRANK + j];
        if (j < DSTATE) Bsh[ti][j] = v;
        else            Csh[ti][j - DSTATE] = v;
    }
    __syncthreads();

    float Av[DSTATE], h[DSTATE];
    size_t o = ((size_t)bc * DINNER + d) * DSTATE;
#pragma unroll
    for (int q = 0; q < 4; q++) {
        float4 hv = *reinterpret_cast<const float4*>(&hstart[o + q * 4]);
        h[4 * q] = hv.x; h[4 * q + 1] = hv.y; h[4 * q + 2] = hv.z; h[4 * q + 3] = hv.w;
    }
#pragma unroll
    for (int s = 0; s < DSTATE; s++)
        Av[s] = -expf(A_log[d * DSTATE + s]);
    const float Dd = Dp[d];

    for (int i = 0; i < LC; i++) {
        size_t base = (size_t)(b * LSEQ + c * LC + i) * DINNER + d;
        float dtv = bf2f(dt[base]);
        float xv = bf2f(xb[base]);
        float szv = bf2f(sz[base]);
        float dx = dtv * xv;
        float Bv[DSTATE], Cv[DSTATE];
        *reinterpret_cast<float4*>(&Bv[0])  = *reinterpret_cast<const float4*>(&Bsh[i][0]);
        *reinterpret_cast<float4*>(&Bv[4])  = *reinterpret_cast<const float4*>(&Bsh[i][4]);
        *reinterpret_cast<float4*>(&Bv[8])  = *reinterpret_cast<const float4*>(&Bsh[i][8]);
        *reinterpret_cast<float4*>(&Bv[12]) = *reinterpret_cast<const float4*>(&Bsh[i][12]);
        *reinterpret_cast<float4*>(&Cv[0])  = *reinterpret_cast<const float4*>(&Csh[i][0]);
        *reinterpret_cast<float4*>(&Cv[4])  = *reinterpret_cast<const float4*>(&Csh[i][4]);
        *reinterpret_cast<float4*>(&Cv[8])  = *reinterpret_cast<const float4*>(&Csh[i][8]);
        *reinterpret_cast<float4*>(&Cv[12]) = *reinterpret_cast<const float4*>(&Csh[i][12]);
        float p = 0.f;
#pragma unroll
        for (int s = 0; s < DSTATE; s++) {
            float dA = __expf(dtv * Av[s]);
            h[s] = fmaf(dA, h[s], dx * Bv[s]);
            p = fmaf(h[s], Cv[s], p);
        }
        ybf[base] = f2bf((p + Dd * xv) * szv);
    }
}

extern "C" void kernel_launch(void* const* d_in, const int* in_sizes, int n_in,
                              void* d_out, int out_size, void* d_ws,
                              size_t ws_size, hipStream_t stream) {
    const float* x = (const float*)d_in[0];
    const float* W_in = (const float*)d_in[1];
    const float* conv_w = (const float*)d_in[2];
    const float* conv_b = (const float*)d_in[3];
    const float* W_xproj = (const float*)d_in[4];
    const float* W_dt = (const float*)d_in[5];
    const float* b_dt = (const float*)d_in[6];
    const float* A_log = (const float*)d_in[7];
    const float* Dp = (const float*)d_in[8];
    const float* W_out = (const float*)d_in[9];
    float* out = (float*)d_out;

    char* ws = (char*)d_ws;
    const size_t MB = 1u << 20;
    float* pp    = (float*)(ws);
    float* aprod = (float*)(ws);
    float* hend  = (float*)(ws + 8 * MB);
    unsigned short* xbpre_bf = (unsigned short*)(ws + 16 * MB);  // 16 MB
    unsigned short* ybf      = (unsigned short*)(ws + 16 * MB);  // 16 MB (after proj_conv)
    unsigned short* sz_bf    = (unsigned short*)(ws + 32 * MB);  // 16 MB
    unsigned short* xb_bf    = (unsigned short*)(ws + 48 * MB);  // 16 MB
    unsigned short* dt_bf    = (unsigned short*)(ws + 64 * MB);  // 16 MB
    float* projbuf           = (float*)(ws + 88 * MB);           // 1.5 MB
    unsigned short* dtin_bf  = (unsigned short*)(ws + 90 * MB);  // 0.5 MB
    unsigned short* xbf      = (unsigned short*)(ws + 91 * MB);  // 8 MB
    unsigned short* WinT     = (unsigned short*)(ws + 99 * MB);  // 8 MB
    unsigned short* WoutT    = (unsigned short*)(ws + 107 * MB); // 4 MB
    unsigned short* WxT      = (unsigned short*)(ws + 111 * MB); // 384 KB
    unsigned short* WdtT     = (unsigned short*)(ws + 112 * MB); // 256 KB

    const int M = BSZ * LSEQ; // 4096
    dim3 blk(256);

    // 0. fused prep
    prep_kernel<<<dim3(4096 + 1024 + 512 + 192 + 128), blk, 0, stream>>>(
        x, W_in, W_out, W_xproj, W_dt, xbf, WinT, WoutT, WxT, WdtT);

    // 1. xz = x @ W_in — 256x128 tile, 512 blocks
    gemm_bm256<1, unsigned short><<<dim3((2 * DINNER) / 128, M / 256), dim3(512),
                                    0, stream>>>(
        xbf, WinT, xbpre_bf, sz_bf, M, 2 * DINNER, DMODEL);

    // 2+3. fused conv + proj split-K (writes xb_bf + pp); xbpre dead after
    proj_conv<<<dim3(M / 32, KS), blk, 0, stream>>>(
        xbpre_bf, conv_w, conv_b, WxT, xb_bf, pp);
    proj_reduce<<<dim3((M * NPROJ) / 256), blk, 0, stream>>>(pp, projbuf, dtin_bf);

    // 4. dt = softplus(dt_in @ W_dt + b_dt)
    dt_gemm<<<dim3(M / 32, DINNER / 128), blk, 0, stream>>>(
        dtin_bf, WdtT, b_dt, dt_bf);

    // 5. scan
    const int nthreads1 = BSZ * NC * DINNER;
    scan_pass1<<<dim3(nthreads1 / 256), blk, 0, stream>>>(
        xb_bf, dt_bf, projbuf, A_log, aprod, hend);
    const int nthreads2 = BSZ * DINNER * DSTATE;
    scan_pass2<<<dim3(nthreads2 / 256), blk, 0, stream>>>(aprod, hend);
    scan_pass3<<<dim3(nthreads1 / 256), blk, 0, stream>>>(
        xb_bf, dt_bf, projbuf, aprod, A_log, Dp, sz_bf, ybf);

    // 6. out = y @ W_out (2-phase 128x64)
    gemm_mfma<64, float><<<dim3(DMODEL / 64, M / 128), blk, 0, stream>>>(
        ybf, WoutT, out, M, DMODEL, DINNER);
}